// Round 1
// baseline (3984.431 us; speedup 1.0000x reference)
//
#include <hip/hip_runtime.h>
#include <hip/hip_bf16.h>

// RtNet25DDualRENet forward, fp32, correctness-first baseline.
// B=64, C=960, H=W=7. Workspace requirement: ~32.7M floats (~131 MB).

#define BNINV 0.9999950000374997f  // 1/sqrt(1+1e-5)

// ---------------- workspace layout (float offsets) ----------------
#define OFF_XN      0u            // (b,960,49)  branch-reused
#define OFF_Y1      3010560u      // (b,96,49,25)
#define OFF_Y2      10536960u     // (b,49,96,9)
#define OFF_T       13246464u     // (b,49,96)
#define OFF_XPN     13547520u     // 2 x (b,49,960)
#define OFF_SQ      19568640u     // 2 x (b,49,96)
#define OFF_CORR    20170752u     // (b,49,49)
#define OFF_S0Y1    20324416u
#define OFF_S0Y2    20478080u
#define OFF_S0P     20631744u     // (b,16,49,49)
#define OFF_S1Y1    23090368u
#define OFF_S1Y2    25548992u
#define OFF_C4F     28007616u     // (b,49,49)
#define OFF_ATT     28161280u     // attn_s[64*49], attn_q[64*49]
#define OFF_EPI     28167552u     // ep[64*1920], ei[64*1920]
#define OFF_H1      28413312u     // 2 x (64,1920)
#define OFF_EM3     28659072u     // 2 x (64,960)
#define OFF_PM      28781952u     // 2 x (8,960)
#define OFF_H2      28797312u     // 2 x (8,1920)
#define OFF_WOUTT   28828032u     // w_out^T [96][960]
#define OFF_CCAT    28920192u     // cca1x1_w^T [960][96]
#define OFF_MCLST   29012352u     // mcls_w1^T [960][1920]
#define OFF_ECLST   30855552u     // ecls_w1^T [960][1920]

// ---------------- generic transpose: in[R][C] -> out[C][R] ----------------
__global__ void k_transpose(const float* __restrict__ in, float* __restrict__ out,
                            int R, int C) {
  int i = blockIdx.x * 256 + threadIdx.x;
  if (i < R * C) {
    int r = i / C, c = i % C;
    out[c * R + r] = in[i];
  }
}

// ---------------- K1: relu + l2-normalize over C per (b,p) ----------------
__global__ __launch_bounds__(256) void k_l2n(const float* __restrict__ x,
                                             float* __restrict__ xn) {
  int b = blockIdx.x, t = threadIdx.x;
  __shared__ float red[256];
  __shared__ float inv[49];
  const float* xb = x + b * 47040;
  float* ob = xn + b * 47040;
  int p = t & 63, sl = t >> 6;
  float s = 0.f;
  if (p < 49) {
    for (int c = sl * 240; c < sl * 240 + 240; ++c) {
      float v = xb[c * 49 + p];
      if (v > 0.f) s += v * v;
    }
  }
  red[t] = s;
  __syncthreads();
  if (t < 49) {
    float q = red[t] + red[t + 64] + red[t + 128] + red[t + 192];
    inv[t] = 1.f / fmaxf(sqrtf(q), 1e-12f);
  }
  __syncthreads();
  for (int i = t; i < 47040; i += 256) {
    float v = xb[i];
    ob[i] = v > 0.f ? v * inv[i % 49] : 0.f;
  }
}

// ------- K2: fused self-corr x scr_w_in einsum + BN + relu -------
// y1[b,o,p,uv] = relu(BN(sum_c W[o,c]*xn[b,c,p]*xn_pad[b,c,nb(p,uv)]))
// grid (7 h-rows, 64 b), block 256 = (16 tx, 16 ty); tile: 96 o x 175 cols.
__global__ __launch_bounds__(256) void k_scr_in(
    const float* __restrict__ xn, const float* __restrict__ w_in,
    const float* __restrict__ bn, float* __restrict__ y1) {
  const int h = blockIdx.x, b = blockIdx.y, t = threadIdx.x;
  const int tx = t & 15, ty = t >> 4;
  __shared__ __align__(16) float xc[32 * 60];    // [kk][r*12+wc]
  __shared__ __align__(16) float Wt[32 * 100];   // [kk][o], stride 100
  __shared__ __align__(16) float P[32 * 192];    // [kk][col], stride 192
  float acc[6][12];
#pragma unroll
  for (int m = 0; m < 6; ++m)
#pragma unroll
    for (int j = 0; j < 12; ++j) acc[m][j] = 0.f;
  const float* xb = xn + b * 47040;
  for (int k0 = 0; k0 < 960; k0 += 32) {
    __syncthreads();
    for (int i = t; i < 32 * 60; i += 256) {
      int kk = i / 60, j = i % 60;
      int r = j / 12, wc = j % 12;
      int row = h + r - 2, w = wc - 2;
      float v = 0.f;
      if (row >= 0 && row < 7 && w >= 0 && w < 7)
        v = xb[(k0 + kk) * 49 + row * 7 + w];
      xc[kk * 60 + j] = v;
    }
    for (int i = t; i < 96 * 32; i += 256) {
      int o = i >> 5, kk = i & 31;
      Wt[kk * 100 + o] = w_in[o * 960 + k0 + kk];
    }
    __syncthreads();
    for (int i = t; i < 32 * 192; i += 256) {
      int kk = i / 192, col = i % 192;
      int c = col < 175 ? col : 174;
      int wp = c / 25, uv = c - wp * 25;
      int du = uv / 5, dv = uv - du * 5;
      P[kk * 192 + col] = xc[kk * 60 + 26 + wp] * xc[kk * 60 + du * 12 + wp + dv];
    }
    __syncthreads();
#pragma unroll 4
    for (int kk = 0; kk < 32; ++kk) {
      float wv[6], pv[12];
      *(float2*)&wv[0] = *(const float2*)&Wt[kk * 100 + ty * 6];
      *(float2*)&wv[2] = *(const float2*)&Wt[kk * 100 + ty * 6 + 2];
      *(float2*)&wv[4] = *(const float2*)&Wt[kk * 100 + ty * 6 + 4];
      *(float4*)&pv[0] = *(const float4*)&P[kk * 192 + tx * 12];
      *(float4*)&pv[4] = *(const float4*)&P[kk * 192 + tx * 12 + 4];
      *(float4*)&pv[8] = *(const float4*)&P[kk * 192 + tx * 12 + 8];
#pragma unroll
      for (int m = 0; m < 6; ++m)
#pragma unroll
        for (int j = 0; j < 12; ++j) acc[m][j] += wv[m] * pv[j];
    }
  }
#pragma unroll
  for (int m = 0; m < 6; ++m) {
    int o = ty * 6 + m;
    float g = BNINV * bn[o], bt = bn[96 + o];
#pragma unroll
    for (int j = 0; j < 12; ++j) {
      int col = tx * 12 + j;
      if (col < 175) {
        int wp = col / 25, uv = col - wp * 25;
        y1[((b * 96 + o) * 49 + h * 7 + wp) * 25 + uv] =
            fmaxf(acc[m][j] * g + bt, 0.f);
      }
    }
  }
}

// ---------------- K3: SCR conv1 (1,3,3) 5x5->3x3, BN, relu ----------------
// grid (13 p-tiles of 4, 64 b), block 128 = (32 og x 4 q); thread: 3 o x 9 out
__global__ __launch_bounds__(128) void k_conv1(
    const float* __restrict__ y1, const float* __restrict__ w1,
    const float* __restrict__ bn1, float* __restrict__ y2g) {
  int pb = blockIdx.x * 4, b = blockIdx.y, t = threadIdx.x;
  int PQ = 49 - pb; if (PQ > 4) PQ = 4;
  int og = t >> 2, q = t & 3;
  __shared__ __align__(16) float Yl[4 * 96 * 28];
  __shared__ __align__(16) float wc[96 * 52];
  for (int i = t; i < 4 * 96 * 28; i += 128) Yl[i] = 0.f;
  __syncthreads();
  for (int i = t; i < 4 * 96 * 25; i += 128) {
    int q2 = i / 2400, r = i % 2400, o = r / 25, uv = r % 25;
    if (q2 < PQ)
      Yl[(q2 * 96 + o) * 28 + uv] = y1[b * 117600 + o * 1225 + (pb + q2) * 25 + uv];
  }
  float acc[3][9];
#pragma unroll
  for (int a = 0; a < 3; ++a)
#pragma unroll
    for (int d = 0; d < 9; ++d) acc[a][d] = 0.f;
  for (int ch = 0; ch < 24; ++ch) {
    __syncthreads();
    for (int i = t; i < 96 * 48; i += 128) {
      int o = i / 48, r = i % 48, icc = r / 12, d = r % 12;
      wc[o * 52 + r] = (d < 9) ? w1[(o * 96 + ch * 4 + icc) * 9 + d] : 0.f;
    }
    __syncthreads();
#pragma unroll
    for (int icc = 0; icc < 4; ++icc) {
      int ic = ch * 4 + icc;
      float yv[28];
      const float* yb = &Yl[(q * 96 + ic) * 28];
#pragma unroll
      for (int v4 = 0; v4 < 7; ++v4) *(float4*)&yv[v4 * 4] = *(const float4*)&yb[v4 * 4];
#pragma unroll
      for (int jo = 0; jo < 3; ++jo) {
        float wv[12];
        const float* wb = &wc[(og * 3 + jo) * 52 + icc * 12];
        *(float4*)&wv[0] = *(const float4*)&wb[0];
        *(float4*)&wv[4] = *(const float4*)&wb[4];
        *(float4*)&wv[8] = *(const float4*)&wb[8];
#pragma unroll
        for (int i2 = 0; i2 < 3; ++i2)
#pragma unroll
          for (int j2 = 0; j2 < 3; ++j2) {
            float s = acc[jo][i2 * 3 + j2];
#pragma unroll
            for (int di = 0; di < 3; ++di)
#pragma unroll
              for (int dj = 0; dj < 3; ++dj)
                s += wv[di * 3 + dj] * yv[(i2 + di) * 5 + (j2 + dj)];
            acc[jo][i2 * 3 + j2] = s;
          }
      }
    }
  }
  if (q < PQ) {
#pragma unroll
    for (int jo = 0; jo < 3; ++jo) {
      int o = og * 3 + jo;
      float g = BNINV * bn1[o], bt = bn1[96 + o];
#pragma unroll
      for (int d = 0; d < 9; ++d)
        y2g[((b * 49 + pb + q) * 96 + o) * 9 + d] = fmaxf(acc[jo][d] * g + bt, 0.f);
    }
  }
}

// ---------------- K4: SCR conv2 (1,3,3) 3x3->1, BN, relu ----------------
// grid (7, 64), block 128; out T[(b,p,96)]
__global__ __launch_bounds__(128) void k_conv2(
    const float* __restrict__ y2g, const float* __restrict__ w2,
    const float* __restrict__ bn2, float* __restrict__ tout) {
  int pr = blockIdx.x, b = blockIdx.y, t = threadIdx.x;
  __shared__ __align__(16) float yl[7 * 96 * 12];
  __shared__ __align__(16) float wc[96 * 52];
  for (int i = t; i < 7 * 96 * 12; i += 128) yl[i] = 0.f;
  __syncthreads();
  for (int i = t; i < 7 * 96 * 9; i += 128) {
    int q = i / 864, r = i % 864, ic = r / 9, d = r % 9;
    yl[(q * 96 + ic) * 12 + d] = y2g[((b * 49 + pr * 7 + q) * 96 + ic) * 9 + d];
  }
  float acc[6] = {0.f, 0.f, 0.f, 0.f, 0.f, 0.f};
  for (int ch = 0; ch < 24; ++ch) {
    __syncthreads();
    for (int i = t; i < 96 * 48; i += 128) {
      int o = i / 48, r = i % 48, icc = r / 12, d = r % 12;
      wc[o * 52 + r] = (d < 9) ? w2[(o * 96 + ch * 4 + icc) * 9 + d] : 0.f;
    }
    __syncthreads();
    for (int n = 0; n < 6; ++n) {
      int it = t + n * 128;
      if (it < 672) {
        int o2 = it % 96, q = it / 96;
#pragma unroll
        for (int icc = 0; icc < 4; ++icc) {
          int ic = ch * 4 + icc;
          float yv[12], wv[12];
          const float* yb = &yl[(q * 96 + ic) * 12];
          *(float4*)&yv[0] = *(const float4*)&yb[0];
          *(float4*)&yv[4] = *(const float4*)&yb[4];
          *(float4*)&yv[8] = *(const float4*)&yb[8];
          const float* wb = &wc[o2 * 52 + icc * 12];
          *(float4*)&wv[0] = *(const float4*)&wb[0];
          *(float4*)&wv[4] = *(const float4*)&wb[4];
          *(float4*)&wv[8] = *(const float4*)&wb[8];
          float s = acc[n];
#pragma unroll
          for (int d = 0; d < 9; ++d) s += wv[d] * yv[d];
          acc[n] = s;
        }
      }
    }
  }
  for (int n = 0; n < 6; ++n) {
    int it = t + n * 128;
    if (it < 672) {
      int o2 = it % 96, q = it / 96;
      tout[(b * 49 + pr * 7 + q) * 96 + o2] =
          fmaxf(acc[n] * (BNINV * bn2[o2]) + bn2[96 + o2], 0.f);
    }
  }
}

// ------- K5: w_out GEMM + BN + residual relu + channel-mean subtract -------
// grid (7, 64), block 256. out xpn layout (b,p,960)
__global__ __launch_bounds__(256) void k_scr_out(
    const float* __restrict__ tin, const float* __restrict__ wouT,
    const float* __restrict__ bno, const float* __restrict__ x,
    float* __restrict__ xpn) {
  int pr = blockIdx.x, b = blockIdx.y, t = threadIdx.x;
  __shared__ __align__(16) float tl2[96 * 8];
  __shared__ float xr[7 * 960];
  __shared__ float xl[7 * 960];
  __shared__ float red[7 * 32];
  __shared__ float mean[7];
  for (int i = t; i < 672; i += 256) {
    int pl = i / 96, ic = i % 96;
    tl2[ic * 8 + pl] = tin[(b * 49 + pr * 7 + pl) * 96 + ic];
  }
  for (int i = t; i < 672; i += 256) tl2[(i % 96) * 8 + 7] = 0.f;
  for (int i = t; i < 6720; i += 256) {
    int o = i / 7, pl = i % 7;
    xl[pl * 960 + o] = x[(b * 960 + o) * 49 + pr * 7 + pl];
  }
  __syncthreads();
  for (int o = t; o < 960; o += 256) {
    float acc[7] = {0.f, 0.f, 0.f, 0.f, 0.f, 0.f, 0.f};
#pragma unroll 4
    for (int ic = 0; ic < 96; ++ic) {
      float w = wouT[ic * 960 + o];
      float tv[8];
      *(float4*)&tv[0] = *(const float4*)&tl2[ic * 8];
      *(float4*)&tv[4] = *(const float4*)&tl2[ic * 8 + 4];
#pragma unroll
      for (int pl = 0; pl < 7; ++pl) acc[pl] += w * tv[pl];
    }
    float g = BNINV * bno[o], bt = bno[960 + o];
#pragma unroll
    for (int pl = 0; pl < 7; ++pl)
      xr[pl * 960 + o] = fmaxf(xl[pl * 960 + o] + acc[pl] * g + bt, 0.f);
  }
  __syncthreads();
  if (t < 224) {
    int pl = t >> 5, ln = t & 31;
    float s = 0.f;
    for (int o = ln; o < 960; o += 32) s += xr[pl * 960 + o];
    red[pl * 32 + ln] = s;
  }
  __syncthreads();
  if (t < 7) {
    float s = 0.f;
    for (int i = 0; i < 32; ++i) s += red[t * 32 + i];
    mean[t] = s * (1.f / 960.f);
  }
  __syncthreads();
  for (int i = t; i < 6720; i += 256) {
    int pl = i / 960, o = i % 960;
    xpn[(b * 49 + pr * 7 + pl) * 960 + o] = xr[pl * 960 + o] - mean[pl];
  }
}

// ------- K6: cca1 1x1 + BN + relu + l2-normalize(96, eps 1e-8) -------
// grid (7, 64), block 128. out sq layout (b,p,96)
__global__ __launch_bounds__(128) void k_cca1(
    const float* __restrict__ xpn, const float* __restrict__ ccaT,
    const float* __restrict__ bnc, float* __restrict__ sq) {
  int pr = blockIdx.x, b = blockIdx.y, t = threadIdx.x;
  __shared__ __align__(16) float xl2[960 * 8];
  __shared__ float sv[7 * 96];
  __shared__ float red[7 * 16];
  __shared__ float inv[7];
  for (int i = t; i < 6720; i += 128) {
    int pl = i / 960, c = i % 960;
    xl2[c * 8 + pl] = xpn[(b * 49 + pr * 7 + pl) * 960 + c];
  }
  for (int c = t; c < 960; c += 128) xl2[c * 8 + 7] = 0.f;
  __syncthreads();
  if (t < 96) {
    float acc[7] = {0.f, 0.f, 0.f, 0.f, 0.f, 0.f, 0.f};
#pragma unroll 4
    for (int c = 0; c < 960; ++c) {
      float w = ccaT[c * 96 + t];
      float tv[8];
      *(float4*)&tv[0] = *(const float4*)&xl2[c * 8];
      *(float4*)&tv[4] = *(const float4*)&xl2[c * 8 + 4];
#pragma unroll
      for (int pl = 0; pl < 7; ++pl) acc[pl] += w * tv[pl];
    }
    float g = BNINV * bnc[t], bt = bnc[96 + t];
#pragma unroll
    for (int pl = 0; pl < 7; ++pl)
      sv[pl * 96 + t] = fmaxf(acc[pl] * g + bt, 0.f);
  }
  __syncthreads();
  if (t < 112) {
    int pl = t >> 4, ln = t & 15;
    float s = 0.f;
    for (int o = ln; o < 96; o += 16) { float v = sv[pl * 96 + o]; s += v * v; }
    red[pl * 16 + ln] = s;
  }
  __syncthreads();
  if (t < 7) {
    float s = 0.f;
    for (int i = 0; i < 16; ++i) s += red[t * 16 + i];
    inv[t] = 1.f / fmaxf(sqrtf(s), 1e-8f);
  }
  __syncthreads();
  for (int i = t; i < 672; i += 128) {
    int pl = i / 96, o = i % 96;
    sq[(b * 49 + pr * 7 + pl) * 96 + o] = sv[pl * 96 + o] * inv[pl];
  }
}

// ---------------- K7: corr[b,ij,kl] = sum_c spt[c,ij]*qry[c,kl] ----------------
__global__ __launch_bounds__(256) void k_corr(const float* __restrict__ sq0,
                                              const float* __restrict__ sq1,
                                              float* __restrict__ corr) {
  int b = blockIdx.x, t = threadIdx.x;
  __shared__ float sL[49 * 97];
  __shared__ float qL[49 * 97];
  for (int i = t; i < 4704; i += 256) {
    int p = i / 96, c = i % 96;
    sL[p * 97 + c] = sq0[b * 4704 + i];
    qL[p * 97 + c] = sq1[b * 4704 + i];
  }
  __syncthreads();
  for (int i = t; i < 2401; i += 256) {
    int ij = i / 49, kl = i % 49;
    float a = 0.f;
#pragma unroll 4
    for (int c = 0; c < 96; ++c) a += sL[ij * 97 + c] * qL[kl * 97 + c];
    corr[b * 2401 + i] = a;
  }
}

// ---------------- sep4d #0: 1-channel 3x3 convs ----------------
__global__ void k_sep0(const float* __restrict__ in, const float* __restrict__ w9,
                       const float* __restrict__ bnp, float* __restrict__ out,
                       int overUV, int doRelu) {
  int b = blockIdx.x, t = threadIdx.x;
  __shared__ float c[2401];
  for (int i = t; i < 2401; i += 256) c[i] = in[b * 2401 + i];
  float w[9];
#pragma unroll
  for (int d = 0; d < 9; ++d) w[d] = w9[d];
  float g = BNINV * bnp[0], bt = bnp[1];
  __syncthreads();
  for (int i = t; i < 2401; i += 256) {
    int ij = i / 49, kl = i % 49;
    float a = 0.f;
    if (overUV) {
      int u = ij / 7, v = ij % 7;
      for (int du = 0; du < 3; ++du)
        for (int dv = 0; dv < 3; ++dv) {
          int uu = u + du - 1, vv = v + dv - 1;
          if (uu >= 0 && uu < 7 && vv >= 0 && vv < 7)
            a += w[du * 3 + dv] * c[(uu * 7 + vv) * 49 + kl];
        }
    } else {
      int kk = kl / 7, ll = kl % 7;
      for (int dh = 0; dh < 3; ++dh)
        for (int dw = 0; dw < 3; ++dw) {
          int k2 = kk + dh - 1, l2 = ll + dw - 1;
          if (k2 >= 0 && k2 < 7 && l2 >= 0 && l2 < 7)
            a += w[dh * 3 + dw] * c[ij * 49 + k2 * 7 + l2];
        }
    }
    a = a * g + bt;
    out[b * 2401 + i] = doRelu ? fmaxf(a, 0.f) : a;
  }
}

__global__ void k_sep0p(const float* __restrict__ in, const float* __restrict__ pw,
                        const float* __restrict__ pbn, float* __restrict__ out) {
  int b = blockIdx.x, o = blockIdx.y, t = threadIdx.x;
  float sc = pw[o] * BNINV * pbn[o], bt = pbn[16 + o];
  for (int i = t; i < 2401; i += 256)
    out[(b * 16 + o) * 2401 + i] = fmaxf(in[b * 2401 + i] * sc + bt, 0.f);
}

// ---------------- sep4d #1: 16-channel convs ----------------
__global__ __launch_bounds__(256) void k_sep1a(
    const float* __restrict__ in, const float* __restrict__ w,
    const float* __restrict__ bnp, float* __restrict__ out) {
  int kc = blockIdx.x, b = blockIdx.y, t = threadIdx.x;
  __shared__ float inL[16 * 343];
  __shared__ float wL[2304];
  for (int i = t; i < 2304; i += 256) wL[i] = w[i];
  for (int i = t; i < 5488; i += 256) {
    int ic = i / 343, r = i % 343;
    int ij = r / 7, s = r % 7;
    inL[ic * 343 + r] = in[(b * 16 + ic) * 2401 + ij * 49 + kc * 7 + s];
  }
  __syncthreads();
  for (int i = t; i < 5488; i += 256) {
    int o = i / 343, r = i % 343;
    int ij = r / 7, s = r % 7;
    int u = ij / 7, v = ij % 7;
    float a = 0.f;
    for (int ic = 0; ic < 16; ++ic)
#pragma unroll
      for (int du = 0; du < 3; ++du) {
        int uu = u + du - 1;
        if (uu < 0 || uu > 6) continue;
#pragma unroll
        for (int dv = 0; dv < 3; ++dv) {
          int vv = v + dv - 1;
          if (vv < 0 || vv > 6) continue;
          a += wL[((o * 16 + ic) * 3 + du) * 3 + dv] * inL[ic * 343 + (uu * 7 + vv) * 7 + s];
        }
      }
    float g = BNINV * bnp[o], bt = bnp[16 + o];
    out[(b * 16 + o) * 2401 + ij * 49 + kc * 7 + s] = fmaxf(a * g + bt, 0.f);
  }
}

__global__ __launch_bounds__(256) void k_sep1b(
    const float* __restrict__ in, const float* __restrict__ w,
    const float* __restrict__ bnp, float* __restrict__ out) {
  int ir = blockIdx.x, b = blockIdx.y, t = threadIdx.x;
  __shared__ float inL[16 * 343];
  __shared__ float wL[2304];
  for (int i = t; i < 2304; i += 256) wL[i] = w[i];
  for (int i = t; i < 5488; i += 256) {
    int ic = i / 343, r = i % 343;
    inL[ic * 343 + r] = in[(b * 16 + ic) * 2401 + ir * 343 + r];
  }
  __syncthreads();
  for (int i = t; i < 5488; i += 256) {
    int o = i / 343, r = i % 343;
    int jj = r / 49, kl = r % 49;
    int k = kl / 7, l = kl % 7;
    float a = 0.f;
    for (int ic = 0; ic < 16; ++ic)
#pragma unroll
      for (int dh = 0; dh < 3; ++dh) {
        int k2 = k + dh - 1;
        if (k2 < 0 || k2 > 6) continue;
#pragma unroll
        for (int dw = 0; dw < 3; ++dw) {
          int l2 = l + dw - 1;
          if (l2 < 0 || l2 > 6) continue;
          a += wL[((o * 16 + ic) * 3 + dh) * 3 + dw] * inL[ic * 343 + jj * 49 + k2 * 7 + l2];
        }
      }
    float g = BNINV * bnp[o], bt = bnp[16 + o];
    out[(b * 16 + o) * 2401 + ir * 343 + r] = a * g + bt;  // no relu
  }
}

__global__ void k_sep1p(const float* __restrict__ in, const float* __restrict__ pw,
                        const float* __restrict__ pbn, float* __restrict__ out) {
  int b = blockIdx.x, t = threadIdx.x;
  float g = BNINV * pbn[0], bt = pbn[1];
  __shared__ float pl[16];
  if (t < 16) pl[t] = pw[t];
  __syncthreads();
  for (int i = t; i < 2401; i += 256) {
    float a = 0.f;
#pragma unroll
    for (int ic = 0; ic < 16; ++ic) a += pl[ic] * in[(b * 16 + ic) * 2401 + i];
    out[b * 2401 + i] = a * g + bt;
  }
}

// ------- K10: gauss-normalize + softmax + attention sums -------
__global__ __launch_bounds__(64) void k_attn(const float* __restrict__ c4,
                                             float* __restrict__ attn_s,
                                             float* __restrict__ attn_q) {
  int b = blockIdx.x, t = threadIdx.x;
  __shared__ float c[2401];
  __shared__ float n[2401];
  for (int i = t; i < 2401; i += 64) c[i] = c4[b * 2401 + i];
  __syncthreads();
  // phase A: per kl, stats + softmax over ij
  if (t < 49) {
    float m = 0.f;
    for (int ij = 0; ij < 49; ++ij) m += c[ij * 49 + t];
    m *= (1.f / 49.f);
    float v = 0.f;
    for (int ij = 0; ij < 49; ++ij) { float d = c[ij * 49 + t] - m; v += d * d; }
    v *= (1.f / 48.f);
    float inv = 1.f / sqrtf(v + 1e-5f);
    float mx = -1e30f;
    for (int ij = 0; ij < 49; ++ij) mx = fmaxf(mx, (c[ij * 49 + t] - m) * inv);
    float s = 0.f;
    for (int ij = 0; ij < 49; ++ij) {
      float e = expf((c[ij * 49 + t] - m) * inv - mx);
      n[ij * 49 + t] = e; s += e;
    }
    float r = 1.f / s;
    for (int ij = 0; ij < 49; ++ij) n[ij * 49 + t] *= r;
  }
  __syncthreads();
  if (t < 49) {
    float s = 0.f;
    for (int kl = 0; kl < 49; ++kl) s += n[t * 49 + kl];
    attn_s[b * 49 + t] = s;
  }
  __syncthreads();
  // phase B: per ij, stats + softmax over kl
  if (t < 49) {
    float m = 0.f;
    for (int kl = 0; kl < 49; ++kl) m += c[t * 49 + kl];
    m *= (1.f / 49.f);
    float v = 0.f;
    for (int kl = 0; kl < 49; ++kl) { float d = c[t * 49 + kl] - m; v += d * d; }
    v *= (1.f / 48.f);
    float inv = 1.f / sqrtf(v + 1e-5f);
    float mx = -1e30f;
    for (int kl = 0; kl < 49; ++kl) mx = fmaxf(mx, (c[t * 49 + kl] - m) * inv);
    float s = 0.f;
    for (int kl = 0; kl < 49; ++kl) {
      float e = expf((c[t * 49 + kl] - m) * inv - mx);
      n[t * 49 + kl] = e; s += e;
    }
    float r = 1.f / s;
    for (int kl = 0; kl < 49; ++kl) n[t * 49 + kl] *= r;
  }
  __syncthreads();
  if (t < 49) {
    float s = 0.f;
    for (int ij = 0; ij < 49; ++ij) s += n[ij * 49 + t];
    attn_q[b * 49 + t] = s;
  }
}

// ------- K11: attention-weighted mean/max pooling -------
__global__ __launch_bounds__(256) void k_pool(const float* __restrict__ xpn,
                                              const float* __restrict__ attn,
                                              float* __restrict__ ep) {
  int b = blockIdx.x, br = blockIdx.y, t = threadIdx.x;
  const float* xb = xpn + br * 3010560 + b * 47040;  // (p,c)
  const float* a = attn + br * 3136 + b * 49;
  __shared__ float al[49];
  if (t < 49) al[t] = a[t];
  __syncthreads();
  float* eb = ep + br * 122880 + b * 1920;
  for (int c = t; c < 960; c += 256) {
    float s = 0.f, mx = -1e30f;
    for (int hw = 0; hw < 49; ++hw) {
      float v = al[hw] * xb[hw * 960 + c];
      s += v; mx = fmaxf(mx, v);
    }
    eb[c] = s * (1.f / 49.f);
    eb[960 + c] = mx;
  }
}

// ------- M=64 GEMM, split-K with atomicAdd: C[b,o] += sum_k A[b,k]*W[o,k] -------
__global__ __launch_bounds__(256) void k_gemm64(
    const float* __restrict__ A0, const float* __restrict__ A1, int asplit,
    int reluA, const float* __restrict__ W, int K, int Kslice,
    float* __restrict__ C, int N) {
  int otile = blockIdx.x, ks = blockIdx.y;
  int t = threadIdx.x, bt = t >> 4, ot = t & 15;
  __shared__ __align__(16) float eT[48 * 68];
  __shared__ __align__(16) float wT[48 * 68];
  float acc[4][4];
#pragma unroll
  for (int i = 0; i < 4; ++i)
#pragma unroll
    for (int j = 0; j < 4; ++j) acc[i][j] = 0.f;
  int kbeg = ks * Kslice, kend = kbeg + Kslice;
  for (int k0 = kbeg; k0 < kend; k0 += 48) {
    __syncthreads();
    for (int i = t; i < 768; i += 256) {
      int b = i / 12, kg = i % 12;
      int k = k0 + kg * 4;
      float4 v;
      if (asplit) {
        v = (k < asplit) ? *(const float4*)&A0[b * 1920 + k]
                         : *(const float4*)&A1[b * 1920 + k - asplit];
      } else {
        v = *(const float4*)&A0[b * K + k];
      }
      if (reluA) {
        v.x = fmaxf(v.x, 0.f); v.y = fmaxf(v.y, 0.f);
        v.z = fmaxf(v.z, 0.f); v.w = fmaxf(v.w, 0.f);
      }
      eT[(kg * 4 + 0) * 68 + b] = v.x; eT[(kg * 4 + 1) * 68 + b] = v.y;
      eT[(kg * 4 + 2) * 68 + b] = v.z; eT[(kg * 4 + 3) * 68 + b] = v.w;
    }
    for (int i = t; i < 768; i += 256) {
      int o = i / 12, kg = i % 12;
      float4 v = *(const float4*)&W[(otile * 64 + o) * K + k0 + kg * 4];
      wT[(kg * 4 + 0) * 68 + o] = v.x; wT[(kg * 4 + 1) * 68 + o] = v.y;
      wT[(kg * 4 + 2) * 68 + o] = v.z; wT[(kg * 4 + 3) * 68 + o] = v.w;
    }
    __syncthreads();
#pragma unroll 4
    for (int kk = 0; kk < 48; ++kk) {
      float av[4], wv[4];
      *(float4*)av = *(const float4*)&eT[kk * 68 + bt * 4];
      *(float4*)wv = *(const float4*)&wT[kk * 68 + ot * 4];
#pragma unroll
      for (int i = 0; i < 4; ++i)
#pragma unroll
        for (int j = 0; j < 4; ++j) acc[i][j] += av[i] * wv[j];
    }
  }
#pragma unroll
  for (int i = 0; i < 4; ++i)
#pragma unroll
    for (int j = 0; j < 4; ++j)
      atomicAdd(&C[(bt * 4 + i) * N + otile * 64 + ot * 4 + j], acc[i][j]);
}

// ------- group pooling over 2.5D groups (+ deferred bias from mlp2) -------
__global__ void k_poolg(const float* __restrict__ em3m, const float* __restrict__ em3e,
                        const float* __restrict__ b2m, const float* __restrict__ b2e,
                        float* __restrict__ pm) {
  int g = blockIdx.x, which = blockIdx.y, t = threadIdx.x;
  const float* em = which ? em3e : em3m;
  const float* b2 = which ? b2e : b2m;
  for (int d = t; d < 960; d += 256) {
    float s = 0.f;
    for (int r = 0; r < 8; ++r) s += em[(g * 8 + r) * 960 + d];
    pm[which * 7680 + g * 960 + d] = s * 0.125f + b2[d];
  }
}

// ------- classifier layer 1: hardswish(pm @ W1^T + b1) -------
__global__ __launch_bounds__(256) void k_cls1(
    const float* __restrict__ pmbase, const float* __restrict__ w1mT,
    const float* __restrict__ b1m, const float* __restrict__ w1eT,
    const float* __restrict__ b1e, float* __restrict__ h2) {
  int which = blockIdx.y, t = threadIdx.x;
  const float* pmw = pmbase + which * 7680;
  const float* WT = which ? w1eT : w1mT;
  const float* b1 = which ? b1e : b1m;
  __shared__ float pl[7680];
  for (int i = t; i < 7680; i += 256) pl[i] = pmw[i];
  __syncthreads();
  int o = blockIdx.x * 256 + t;
  if (o >= 1920) return;
  float acc[8] = {0.f, 0.f, 0.f, 0.f, 0.f, 0.f, 0.f, 0.f};
#pragma unroll 4
  for (int k = 0; k < 960; ++k) {
    float w = WT[k * 1920 + o];
#pragma unroll
    for (int g = 0; g < 8; ++g) acc[g] += w * pl[g * 960 + k];
  }
  float bb = b1[o];
#pragma unroll
  for (int g = 0; g < 8; ++g) {
    float z = acc[g] + bb;
    h2[which * 15360 + g * 1920 + o] = z * fminf(fmaxf(z + 3.f, 0.f), 6.f) * (1.f / 6.f);
  }
}

// ------- classifier layer 2 + final concat -------
__global__ __launch_bounds__(256) void k_cls2(
    const float* __restrict__ h2, const float* __restrict__ w2m,
    const float* __restrict__ b2m, const float* __restrict__ w2e,
    const float* __restrict__ b2e, float* __restrict__ out) {
  int which = blockIdx.x, t = threadIdx.x;
  const float* h = h2 + which * 15360;
  const float* W = which ? w2e : w2m;
  const float* bb = which ? b2e : b2m;
  __shared__ float red[256];
  for (int gj = 0; gj < 16; ++gj) {
    int g = gj >> 1, j = gj & 1;
    float s = 0.f;
    for (int k = t; k < 1920; k += 256) s += h[g * 1920 + k] * W[j * 1920 + k];
    red[t] = s;
    __syncthreads();
    for (int off = 128; off >= 1; off >>= 1) {
      if (t < off) red[t] += red[t + off];
      __syncthreads();
    }
    if (t == 0) out[g * 4 + which * 2 + j] = red[0] + bb[j];
    __syncthreads();
  }
}

// =======================================================================
extern "C" void kernel_launch(void* const* d_in, const int* in_sizes, int n_in,
                              void* d_out, int out_size, void* d_ws, size_t ws_size,
                              hipStream_t stream) {
  const float* x_p = (const float*)d_in[0];
  const float* x_i = (const float*)d_in[1];
  const float* scr_w_in = (const float*)d_in[2];
  const float* scr_bn_in = (const float*)d_in[3];
  const float* scr_w1 = (const float*)d_in[4];
  const float* scr_bn1 = (const float*)d_in[5];
  const float* scr_w2 = (const float*)d_in[6];
  const float* scr_bn2 = (const float*)d_in[7];
  const float* scr_w_out = (const float*)d_in[8];
  const float* scr_bn_out = (const float*)d_in[9];
  const float* cca1x1_w = (const float*)d_in[10];
  const float* cca1x1_bn = (const float*)d_in[11];
  const float* cca0_c2_w = (const float*)d_in[12];
  const float* cca0_c2_bn = (const float*)d_in[13];
  const float* cca0_c1_w = (const float*)d_in[14];
  const float* cca0_c1_bn = (const float*)d_in[15];
  const float* cca0_p_w = (const float*)d_in[16];
  const float* cca0_p_bn = (const float*)d_in[17];
  const float* cca1_c2_w = (const float*)d_in[18];
  const float* cca1_c2_bn = (const float*)d_in[19];
  const float* cca1_c1_w = (const float*)d_in[20];
  const float* cca1_c1_bn = (const float*)d_in[21];
  const float* cca1_p_w = (const float*)d_in[22];
  const float* cca1_p_bn = (const float*)d_in[23];
  const float* meta_w1 = (const float*)d_in[24];
  const float* meta_w2 = (const float*)d_in[25];
  const float* meta_b2 = (const float*)d_in[26];
  const float* ene_w1 = (const float*)d_in[27];
  const float* ene_w2 = (const float*)d_in[28];
  const float* ene_b2 = (const float*)d_in[29];
  const float* mcls_w1 = (const float*)d_in[30];
  const float* mcls_b1 = (const float*)d_in[31];
  const float* mcls_w2 = (const float*)d_in[32];
  const float* mcls_b2 = (const float*)d_in[33];
  const float* ecls_w1 = (const float*)d_in[34];
  const float* ecls_b1 = (const float*)d_in[35];
  const float* ecls_w2 = (const float*)d_in[36];
  const float* ecls_b2 = (const float*)d_in[37];

  float* ws = (float*)d_ws;
  float* XN = ws + OFF_XN;
  float* Y1 = ws + OFF_Y1;
  float* Y2 = ws + OFF_Y2;
  float* T = ws + OFF_T;
  float* XPN = ws + OFF_XPN;
  float* SQ = ws + OFF_SQ;
  float* CORR = ws + OFF_CORR;
  float* S0Y1 = ws + OFF_S0Y1;
  float* S0Y2 = ws + OFF_S0Y2;
  float* S0P = ws + OFF_S0P;
  float* S1Y1 = ws + OFF_S1Y1;
  float* S1Y2 = ws + OFF_S1Y2;
  float* C4F = ws + OFF_C4F;
  float* ATT = ws + OFF_ATT;
  float* EPI = ws + OFF_EPI;
  float* H1 = ws + OFF_H1;
  float* EM3 = ws + OFF_EM3;
  float* PM = ws + OFF_PM;
  float* H2 = ws + OFF_H2;
  float* WOUTT = ws + OFF_WOUTT;
  float* CCAT = ws + OFF_CCAT;
  float* MCLST = ws + OFF_MCLST;
  float* ECLST = ws + OFF_ECLST;

  // weight transposes (small, every call)
  k_transpose<<<(960 * 96 + 255) / 256, 256, 0, stream>>>(scr_w_out, WOUTT, 960, 96);
  k_transpose<<<(96 * 960 + 255) / 256, 256, 0, stream>>>(cca1x1_w, CCAT, 96, 960);
  k_transpose<<<(1920 * 960 + 255) / 256, 256, 0, stream>>>(mcls_w1, MCLST, 1920, 960);
  k_transpose<<<(1920 * 960 + 255) / 256, 256, 0, stream>>>(ecls_w1, ECLST, 1920, 960);

  for (int br = 0; br < 2; ++br) {
    const float* x = br ? x_i : x_p;
    k_l2n<<<64, 256, 0, stream>>>(x, XN);
    k_scr_in<<<dim3(7, 64), 256, 0, stream>>>(XN, scr_w_in, scr_bn_in, Y1);
    k_conv1<<<dim3(13, 64), 128, 0, stream>>>(Y1, scr_w1, scr_bn1, Y2);
    k_conv2<<<dim3(7, 64), 128, 0, stream>>>(Y2, scr_w2, scr_bn2, T);
    k_scr_out<<<dim3(7, 64), 256, 0, stream>>>(T, WOUTT, scr_bn_out, x,
                                               XPN + br * 3010560);
    k_cca1<<<dim3(7, 64), 128, 0, stream>>>(XPN + br * 3010560, CCAT, cca1x1_bn,
                                            SQ + br * 301056);
  }
  k_corr<<<64, 256, 0, stream>>>(SQ, SQ + 301056, CORR);
  k_sep0<<<64, 256, 0, stream>>>(CORR, cca0_c2_w, cca0_c2_bn, S0Y1, 1, 1);
  k_sep0<<<64, 256, 0, stream>>>(S0Y1, cca0_c1_w, cca0_c1_bn, S0Y2, 0, 0);
  k_sep0p<<<dim3(64, 16), 256, 0, stream>>>(S0Y2, cca0_p_w, cca0_p_bn, S0P);
  k_sep1a<<<dim3(7, 64), 256, 0, stream>>>(S0P, cca1_c2_w, cca1_c2_bn, S1Y1);
  k_sep1b<<<dim3(7, 64), 256, 0, stream>>>(S1Y1, cca1_c1_w, cca1_c1_bn, S1Y2);
  k_sep1p<<<64, 256, 0, stream>>>(S1Y2, cca1_p_w, cca1_p_bn, C4F);
  k_attn<<<64, 64, 0, stream>>>(C4F, ATT, ATT + 3136);
  k_pool<<<dim3(64, 2), 256, 0, stream>>>(XPN, ATT, EPI);

  hipMemsetAsync(H1, 0, (245760u + 122880u) * sizeof(float), stream);
  // mlp1: em/ee @ w1^T (relu deferred to mlp2 input)
  k_gemm64<<<dim3(30, 8), 256, 0, stream>>>(EPI, EPI + 122880, 960, 0, meta_w1,
                                            1920, 240, H1, 1920);
  k_gemm64<<<dim3(30, 8), 256, 0, stream>>>(EPI + 960, EPI + 122880 + 960, 960, 0,
                                            ene_w1, 1920, 240, H1 + 122880, 1920);
  // mlp2: relu(h) @ w2^T (bias deferred to poolg)
  k_gemm64<<<dim3(15, 8), 256, 0, stream>>>(H1, nullptr, 0, 1, meta_w2, 1920, 240,
                                            EM3, 960);
  k_gemm64<<<dim3(15, 8), 256, 0, stream>>>(H1 + 122880, nullptr, 0, 1, ene_w2,
                                            1920, 240, EM3 + 61440, 960);
  k_poolg<<<dim3(8, 2), 256, 0, stream>>>(EM3, EM3 + 61440, meta_b2, ene_b2, PM);
  k_cls1<<<dim3(8, 2), 256, 0, stream>>>(PM, MCLST, mcls_b1, ECLST, ecls_b1, H2);
  k_cls2<<<2, 256, 0, stream>>>(H2, mcls_w2, mcls_b2, ecls_w2, ecls_b2,
                                (float*)d_out);
}

// Round 2
// 2370.573 us; speedup vs baseline: 1.6808x; 1.6808x over previous
//
#include <hip/hip_runtime.h>
#include <hip/hip_bf16.h>

// RtNet25DDualRENet forward, fp32. Round 2: conv1/conv2 rewritten as
// register-tiled GEMM-style kernels (old versions were occupancy/bank-conflict
// bound: 700us each, VALUBusy 17%, 2e7 bank conflicts).
// B=64, C=960, H=W=7. Workspace requirement: ~32.7M floats (~131 MB).

#define BNINV 0.9999950000374997f  // 1/sqrt(1+1e-5)

// ---------------- workspace layout (float offsets) ----------------
#define OFF_XN      0u            // (b,960,49)  branch-reused
#define OFF_Y1      3010560u      // (b,96,49,25)
#define OFF_Y2      10536960u     // (b,49,96,9)
#define OFF_T       13246464u     // (b,49,96)
#define OFF_XPN     13547520u     // 2 x (b,49,960)
#define OFF_SQ      19568640u     // 2 x (b,49,96)
#define OFF_CORR    20170752u     // (b,49,49)
#define OFF_S0Y1    20324416u
#define OFF_S0Y2    20478080u
#define OFF_S0P     20631744u     // (b,16,49,49) -- ALSO reused early for W1T/W2T
#define OFF_S1Y1    23090368u
#define OFF_S1Y2    25548992u
#define OFF_C4F     28007616u     // (b,49,49)
#define OFF_ATT     28161280u     // attn_s[64*49], attn_q[64*49]
#define OFF_EPI     28167552u     // ep[64*1920], ei[64*1920]
#define OFF_H1      28413312u     // 2 x (64,1920)
#define OFF_EM3     28659072u     // 2 x (64,960)
#define OFF_PM      28781952u     // 2 x (8,960)
#define OFF_H2      28797312u     // 2 x (8,1920)
#define OFF_WOUTT   28828032u     // w_out^T [96][960]
#define OFF_CCAT    28920192u     // cca1x1_w^T [960][96]
#define OFF_MCLST   29012352u     // mcls_w1^T [960][1920]
#define OFF_ECLST   30855552u     // ecls_w1^T [960][1920]
// W1T/W2T live in the S0P region (only needed during branch loop, S0P written later)
#define OFF_W1T     OFF_S0P
#define OFF_W2T     (OFF_S0P + 110592u)

// ---------------- generic transpose: in[R][C] -> out[C][R] ----------------
__global__ void k_transpose(const float* __restrict__ in, float* __restrict__ out,
                            int R, int C) {
  int i = blockIdx.x * 256 + threadIdx.x;
  if (i < R * C) {
    int r = i / C, c = i % C;
    out[c * R + r] = in[i];
  }
}

// ---- prep: w[o][ic][9] -> WT[ic][o][12] (taps padded with 0) ----
__global__ void k_prepw(const float* __restrict__ w1, const float* __restrict__ w2,
                        float* __restrict__ W1T, float* __restrict__ W2T) {
  int i = blockIdx.x * 256 + threadIdx.x;  // over 96*96*12
  if (i >= 110592) return;
  int tap = i % 12, rest = i / 12, o = rest % 96, ic = rest / 96;
  const float* w = blockIdx.y ? w2 : w1;
  float v = (tap < 9) ? w[(o * 96 + ic) * 9 + tap] : 0.f;
  (blockIdx.y ? W2T : W1T)[i] = v;
}

// ---------------- K1: relu + l2-normalize over C per (b,p) ----------------
__global__ __launch_bounds__(256) void k_l2n(const float* __restrict__ x,
                                             float* __restrict__ xn) {
  int b = blockIdx.x, t = threadIdx.x;
  __shared__ float red[256];
  __shared__ float inv[49];
  const float* xb = x + b * 47040;
  float* ob = xn + b * 47040;
  int p = t & 63, sl = t >> 6;
  float s = 0.f;
  if (p < 49) {
    for (int c = sl * 240; c < sl * 240 + 240; ++c) {
      float v = xb[c * 49 + p];
      if (v > 0.f) s += v * v;
    }
  }
  red[t] = s;
  __syncthreads();
  if (t < 49) {
    float q = red[t] + red[t + 64] + red[t + 128] + red[t + 192];
    inv[t] = 1.f / fmaxf(sqrtf(q), 1e-12f);
  }
  __syncthreads();
  for (int i = t; i < 47040; i += 256) {
    float v = xb[i];
    ob[i] = v > 0.f ? v * inv[i % 49] : 0.f;
  }
}

// ------- K2: fused self-corr x scr_w_in einsum + BN + relu -------
__global__ __launch_bounds__(256) void k_scr_in(
    const float* __restrict__ xn, const float* __restrict__ w_in,
    const float* __restrict__ bn, float* __restrict__ y1) {
  const int h = blockIdx.x, b = blockIdx.y, t = threadIdx.x;
  const int tx = t & 15, ty = t >> 4;
  __shared__ __align__(16) float xc[32 * 60];    // [kk][r*12+wc]
  __shared__ __align__(16) float Wt[32 * 100];   // [kk][o], stride 100
  __shared__ __align__(16) float P[32 * 192];    // [kk][col], stride 192
  float acc[6][12];
#pragma unroll
  for (int m = 0; m < 6; ++m)
#pragma unroll
    for (int j = 0; j < 12; ++j) acc[m][j] = 0.f;
  const float* xb = xn + b * 47040;
  for (int k0 = 0; k0 < 960; k0 += 32) {
    __syncthreads();
    for (int i = t; i < 32 * 60; i += 256) {
      int kk = i / 60, j = i % 60;
      int r = j / 12, wc = j % 12;
      int row = h + r - 2, w = wc - 2;
      float v = 0.f;
      if (row >= 0 && row < 7 && w >= 0 && w < 7)
        v = xb[(k0 + kk) * 49 + row * 7 + w];
      xc[kk * 60 + j] = v;
    }
    for (int i = t; i < 96 * 32; i += 256) {
      int o = i >> 5, kk = i & 31;
      Wt[kk * 100 + o] = w_in[o * 960 + k0 + kk];
    }
    __syncthreads();
    for (int i = t; i < 32 * 192; i += 256) {
      int kk = i / 192, col = i % 192;
      int c = col < 175 ? col : 174;
      int wp = c / 25, uv = c - wp * 25;
      int du = uv / 5, dv = uv - du * 5;
      P[kk * 192 + col] = xc[kk * 60 + 26 + wp] * xc[kk * 60 + du * 12 + wp + dv];
    }
    __syncthreads();
#pragma unroll 4
    for (int kk = 0; kk < 32; ++kk) {
      float wv[6], pv[12];
      *(float2*)&wv[0] = *(const float2*)&Wt[kk * 100 + ty * 6];
      *(float2*)&wv[2] = *(const float2*)&Wt[kk * 100 + ty * 6 + 2];
      *(float2*)&wv[4] = *(const float2*)&Wt[kk * 100 + ty * 6 + 4];
      *(float4*)&pv[0] = *(const float4*)&P[kk * 192 + tx * 12];
      *(float4*)&pv[4] = *(const float4*)&P[kk * 192 + tx * 12 + 4];
      *(float4*)&pv[8] = *(const float4*)&P[kk * 192 + tx * 12 + 8];
#pragma unroll
      for (int m = 0; m < 6; ++m)
#pragma unroll
        for (int j = 0; j < 12; ++j) acc[m][j] += wv[m] * pv[j];
    }
  }
#pragma unroll
  for (int m = 0; m < 6; ++m) {
    int o = ty * 6 + m;
    float g = BNINV * bn[o], bt = bn[96 + o];
#pragma unroll
    for (int j = 0; j < 12; ++j) {
      int col = tx * 12 + j;
      if (col < 175) {
        int wp = col / 25, uv = col - wp * 25;
        y1[((b * 96 + o) * 49 + h * 7 + wp) * 25 + uv] =
            fmaxf(acc[m][j] * g + bt, 0.f);
      }
    }
  }
}

// ---------------- K3: SCR conv1 (1,3,3) 5x5->3x3, BN, relu (v2) ----------------
// grid 392 (8 (b,p)-pairs each), block 256 = 8 tx(pair) x 32 ty(o-trio).
// Thread: 3 o x 9 outputs. K chunked by 8 input channels.
__global__ __launch_bounds__(256) void k_conv1(
    const float* __restrict__ y1, const float* __restrict__ W1T,
    const float* __restrict__ bn1, float* __restrict__ y2g) {
  const int t = threadIdx.x;
  const int tx = t & 7;    // pair slot
  const int ty = t >> 3;   // 0..31 -> o-trio
  const int pairBase = blockIdx.x * 8;
  __shared__ __align__(16) float Wc[9216];      // [8 ic][96 o][12 tap-pad]
  __shared__ __align__(16) float Raw[8 * 228];  // [pair][8 ic * 28-pad]
  float acc[3][9];
#pragma unroll
  for (int m = 0; m < 3; ++m)
#pragma unroll
    for (int d = 0; d < 9; ++d) acc[m][d] = 0.f;
  const int pair = pairBase + tx;
  for (int ch = 0; ch < 12; ++ch) {
    __syncthreads();
    {
      const float4* src = (const float4*)(W1T + ch * 9216);
      float4* dst = (float4*)Wc;
      for (int i = t; i < 2304; i += 256) dst[i] = src[i];
    }
    for (int i = t; i < 1600; i += 256) {
      int pr = i / 200, r = i - pr * 200, ic = r / 25, uv = r - ic * 25;
      int pp = pairBase + pr, bb = pp / 49, pq = pp - bb * 49;
      Raw[pr * 228 + ic * 28 + uv] =
          y1[((bb * 96 + ch * 8 + ic) * 49 + pq) * 25 + uv];
    }
    __syncthreads();
#pragma unroll
    for (int ic = 0; ic < 8; ++ic) {
      float r[25];
      const float* rb = &Raw[tx * 228 + ic * 28];
      *(float4*)&r[0]  = *(const float4*)&rb[0];
      *(float4*)&r[4]  = *(const float4*)&rb[4];
      *(float4*)&r[8]  = *(const float4*)&rb[8];
      *(float4*)&r[12] = *(const float4*)&rb[12];
      *(float4*)&r[16] = *(const float4*)&rb[16];
      *(float4*)&r[20] = *(const float4*)&rb[20];
      r[24] = rb[24];
#pragma unroll
      for (int m = 0; m < 3; ++m) {
        float w[12];
        const float* wb = &Wc[(ic * 96 + ty * 3 + m) * 12];
        *(float4*)&w[0] = *(const float4*)&wb[0];
        *(float4*)&w[4] = *(const float4*)&wb[4];
        *(float4*)&w[8] = *(const float4*)&wb[8];
#pragma unroll
        for (int i2 = 0; i2 < 3; ++i2)
#pragma unroll
          for (int j2 = 0; j2 < 3; ++j2) {
            float s = acc[m][i2 * 3 + j2];
#pragma unroll
            for (int di = 0; di < 3; ++di)
#pragma unroll
              for (int dj = 0; dj < 3; ++dj)
                s += w[di * 3 + dj] * r[(i2 + di) * 5 + (j2 + dj)];
            acc[m][i2 * 3 + j2] = s;
          }
      }
    }
  }
#pragma unroll
  for (int m = 0; m < 3; ++m) {
    int o = ty * 3 + m;
    float g = BNINV * bn1[o], bt = bn1[96 + o];
#pragma unroll
    for (int d = 0; d < 9; ++d)
      y2g[(pair * 96 + o) * 9 + d] = fmaxf(acc[m][d] * g + bt, 0.f);
  }
}

// ---------------- K4: SCR conv2 (1,3,3) 3x3->1, BN, relu (v2) ----------------
// grid 392 (8 pairs), block 128 = 8 tx(pair) x 16 ty(o-sextet).
__global__ __launch_bounds__(128) void k_conv2(
    const float* __restrict__ y2g, const float* __restrict__ W2T,
    const float* __restrict__ bn2, float* __restrict__ tout) {
  const int t = threadIdx.x;
  const int tx = t & 7;    // pair
  const int ty = t >> 3;   // 0..15 -> o = ty*6 + j
  const int pairBase = blockIdx.x * 8;
  __shared__ __align__(16) float Wc[9216];      // [8 ic][96 o][12]
  __shared__ __align__(16) float Yl[8 * 100];   // [pair][8 ic * 12-pad]
  float acc[6] = {0.f, 0.f, 0.f, 0.f, 0.f, 0.f};
  const int pair = pairBase + tx;
  for (int ch = 0; ch < 12; ++ch) {
    __syncthreads();
    {
      const float4* src = (const float4*)(W2T + ch * 9216);
      float4* dst = (float4*)Wc;
      for (int i = t; i < 2304; i += 128) dst[i] = src[i];
    }
    for (int i = t; i < 576; i += 128) {
      int pr = i / 72, k = i - pr * 72, ic = k / 9, tap = k - ic * 9;
      Yl[pr * 100 + ic * 12 + tap] = y2g[(pairBase + pr) * 864 + ch * 72 + k];
    }
    __syncthreads();
#pragma unroll
    for (int ic = 0; ic < 8; ++ic) {
      float y[9];
      const float* yb = &Yl[tx * 100 + ic * 12];
      *(float4*)&y[0] = *(const float4*)&yb[0];
      *(float4*)&y[4] = *(const float4*)&yb[4];
      y[8] = yb[8];
#pragma unroll
      for (int j = 0; j < 6; ++j) {
        float w[12];
        const float* wb = &Wc[(ic * 96 + ty * 6 + j) * 12];
        *(float4*)&w[0] = *(const float4*)&wb[0];
        *(float4*)&w[4] = *(const float4*)&wb[4];
        *(float4*)&w[8] = *(const float4*)&wb[8];
        float s = acc[j];
#pragma unroll
        for (int d = 0; d < 9; ++d) s += w[d] * y[d];
        acc[j] = s;
      }
    }
  }
#pragma unroll
  for (int j = 0; j < 6; ++j) {
    int o = ty * 6 + j;
    tout[pair * 96 + o] =
        fmaxf(acc[j] * (BNINV * bn2[o]) + bn2[96 + o], 0.f);
  }
}

// ------- K5: w_out GEMM + BN + residual relu + channel-mean subtract -------
__global__ __launch_bounds__(256) void k_scr_out(
    const float* __restrict__ tin, const float* __restrict__ wouT,
    const float* __restrict__ bno, const float* __restrict__ x,
    float* __restrict__ xpn) {
  int pr = blockIdx.x, b = blockIdx.y, t = threadIdx.x;
  __shared__ __align__(16) float tl2[96 * 8];
  __shared__ float xr[7 * 960];
  __shared__ float xl[7 * 960];
  __shared__ float red[7 * 32];
  __shared__ float mean[7];
  for (int i = t; i < 672; i += 256) {
    int pl = i / 96, ic = i % 96;
    tl2[ic * 8 + pl] = tin[(b * 49 + pr * 7 + pl) * 96 + ic];
  }
  for (int i = t; i < 672; i += 256) tl2[(i % 96) * 8 + 7] = 0.f;
  for (int i = t; i < 6720; i += 256) {
    int o = i / 7, pl = i % 7;
    xl[pl * 960 + o] = x[(b * 960 + o) * 49 + pr * 7 + pl];
  }
  __syncthreads();
  for (int o = t; o < 960; o += 256) {
    float acc[7] = {0.f, 0.f, 0.f, 0.f, 0.f, 0.f, 0.f};
#pragma unroll 4
    for (int ic = 0; ic < 96; ++ic) {
      float w = wouT[ic * 960 + o];
      float tv[8];
      *(float4*)&tv[0] = *(const float4*)&tl2[ic * 8];
      *(float4*)&tv[4] = *(const float4*)&tl2[ic * 8 + 4];
#pragma unroll
      for (int pl = 0; pl < 7; ++pl) acc[pl] += w * tv[pl];
    }
    float g = BNINV * bno[o], bt = bno[960 + o];
#pragma unroll
    for (int pl = 0; pl < 7; ++pl)
      xr[pl * 960 + o] = fmaxf(xl[pl * 960 + o] + acc[pl] * g + bt, 0.f);
  }
  __syncthreads();
  if (t < 224) {
    int pl = t >> 5, ln = t & 31;
    float s = 0.f;
    for (int o = ln; o < 960; o += 32) s += xr[pl * 960 + o];
    red[pl * 32 + ln] = s;
  }
  __syncthreads();
  if (t < 7) {
    float s = 0.f;
    for (int i = 0; i < 32; ++i) s += red[t * 32 + i];
    mean[t] = s * (1.f / 960.f);
  }
  __syncthreads();
  for (int i = t; i < 6720; i += 256) {
    int pl = i / 960, o = i % 960;
    xpn[(b * 49 + pr * 7 + pl) * 960 + o] = xr[pl * 960 + o] - mean[pl];
  }
}

// ------- K6: cca1 1x1 + BN + relu + l2-normalize(96, eps 1e-8) -------
__global__ __launch_bounds__(128) void k_cca1(
    const float* __restrict__ xpn, const float* __restrict__ ccaT,
    const float* __restrict__ bnc, float* __restrict__ sq) {
  int pr = blockIdx.x, b = blockIdx.y, t = threadIdx.x;
  __shared__ __align__(16) float xl2[960 * 8];
  __shared__ float sv[7 * 96];
  __shared__ float red[7 * 16];
  __shared__ float inv[7];
  for (int i = t; i < 6720; i += 128) {
    int pl = i / 960, c = i % 960;
    xl2[c * 8 + pl] = xpn[(b * 49 + pr * 7 + pl) * 960 + c];
  }
  for (int c = t; c < 960; c += 128) xl2[c * 8 + 7] = 0.f;
  __syncthreads();
  if (t < 96) {
    float acc[7] = {0.f, 0.f, 0.f, 0.f, 0.f, 0.f, 0.f};
#pragma unroll 4
    for (int c = 0; c < 960; ++c) {
      float w = ccaT[c * 96 + t];
      float tv[8];
      *(float4*)&tv[0] = *(const float4*)&xl2[c * 8];
      *(float4*)&tv[4] = *(const float4*)&xl2[c * 8 + 4];
#pragma unroll
      for (int pl = 0; pl < 7; ++pl) acc[pl] += w * tv[pl];
    }
    float g = BNINV * bnc[t], bt = bnc[96 + t];
#pragma unroll
    for (int pl = 0; pl < 7; ++pl)
      sv[pl * 96 + t] = fmaxf(acc[pl] * g + bt, 0.f);
  }
  __syncthreads();
  if (t < 112) {
    int pl = t >> 4, ln = t & 15;
    float s = 0.f;
    for (int o = ln; o < 96; o += 16) { float v = sv[pl * 96 + o]; s += v * v; }
    red[pl * 16 + ln] = s;
  }
  __syncthreads();
  if (t < 7) {
    float s = 0.f;
    for (int i = 0; i < 16; ++i) s += red[t * 16 + i];
    inv[t] = 1.f / fmaxf(sqrtf(s), 1e-8f);
  }
  __syncthreads();
  for (int i = t; i < 672; i += 128) {
    int pl = i / 96, o = i % 96;
    sq[(b * 49 + pr * 7 + pl) * 96 + o] = sv[pl * 96 + o] * inv[pl];
  }
}

// ---------------- K7: corr[b,ij,kl] = sum_c spt[c,ij]*qry[c,kl] ----------------
__global__ __launch_bounds__(256) void k_corr(const float* __restrict__ sq0,
                                              const float* __restrict__ sq1,
                                              float* __restrict__ corr) {
  int b = blockIdx.x, t = threadIdx.x;
  __shared__ float sL[49 * 97];
  __shared__ float qL[49 * 97];
  for (int i = t; i < 4704; i += 256) {
    int p = i / 96, c = i % 96;
    sL[p * 97 + c] = sq0[b * 4704 + i];
    qL[p * 97 + c] = sq1[b * 4704 + i];
  }
  __syncthreads();
  for (int i = t; i < 2401; i += 256) {
    int ij = i / 49, kl = i % 49;
    float a = 0.f;
#pragma unroll 4
    for (int c = 0; c < 96; ++c) a += sL[ij * 97 + c] * qL[kl * 97 + c];
    corr[b * 2401 + i] = a;
  }
}

// ---------------- sep4d #0: 1-channel 3x3 convs ----------------
__global__ void k_sep0(const float* __restrict__ in, const float* __restrict__ w9,
                       const float* __restrict__ bnp, float* __restrict__ out,
                       int overUV, int doRelu) {
  int b = blockIdx.x, t = threadIdx.x;
  __shared__ float c[2401];
  for (int i = t; i < 2401; i += 256) c[i] = in[b * 2401 + i];
  float w[9];
#pragma unroll
  for (int d = 0; d < 9; ++d) w[d] = w9[d];
  float g = BNINV * bnp[0], bt = bnp[1];
  __syncthreads();
  for (int i = t; i < 2401; i += 256) {
    int ij = i / 49, kl = i % 49;
    float a = 0.f;
    if (overUV) {
      int u = ij / 7, v = ij % 7;
      for (int du = 0; du < 3; ++du)
        for (int dv = 0; dv < 3; ++dv) {
          int uu = u + du - 1, vv = v + dv - 1;
          if (uu >= 0 && uu < 7 && vv >= 0 && vv < 7)
            a += w[du * 3 + dv] * c[(uu * 7 + vv) * 49 + kl];
        }
    } else {
      int kk = kl / 7, ll = kl % 7;
      for (int dh = 0; dh < 3; ++dh)
        for (int dw = 0; dw < 3; ++dw) {
          int k2 = kk + dh - 1, l2 = ll + dw - 1;
          if (k2 >= 0 && k2 < 7 && l2 >= 0 && l2 < 7)
            a += w[dh * 3 + dw] * c[ij * 49 + k2 * 7 + l2];
        }
    }
    a = a * g + bt;
    out[b * 2401 + i] = doRelu ? fmaxf(a, 0.f) : a;
  }
}

__global__ void k_sep0p(const float* __restrict__ in, const float* __restrict__ pw,
                        const float* __restrict__ pbn, float* __restrict__ out) {
  int b = blockIdx.x, o = blockIdx.y, t = threadIdx.x;
  float sc = pw[o] * BNINV * pbn[o], bt = pbn[16 + o];
  for (int i = t; i < 2401; i += 256)
    out[(b * 16 + o) * 2401 + i] = fmaxf(in[b * 2401 + i] * sc + bt, 0.f);
}

// ---------------- sep4d #1: 16-channel convs ----------------
__global__ __launch_bounds__(256) void k_sep1a(
    const float* __restrict__ in, const float* __restrict__ w,
    const float* __restrict__ bnp, float* __restrict__ out) {
  int kc = blockIdx.x, b = blockIdx.y, t = threadIdx.x;
  __shared__ float inL[16 * 343];
  __shared__ float wL[2304];
  for (int i = t; i < 2304; i += 256) wL[i] = w[i];
  for (int i = t; i < 5488; i += 256) {
    int ic = i / 343, r = i % 343;
    int ij = r / 7, s = r % 7;
    inL[ic * 343 + r] = in[(b * 16 + ic) * 2401 + ij * 49 + kc * 7 + s];
  }
  __syncthreads();
  for (int i = t; i < 5488; i += 256) {
    int o = i / 343, r = i % 343;
    int ij = r / 7, s = r % 7;
    int u = ij / 7, v = ij % 7;
    float a = 0.f;
    for (int ic = 0; ic < 16; ++ic)
#pragma unroll
      for (int du = 0; du < 3; ++du) {
        int uu = u + du - 1;
        if (uu < 0 || uu > 6) continue;
#pragma unroll
        for (int dv = 0; dv < 3; ++dv) {
          int vv = v + dv - 1;
          if (vv < 0 || vv > 6) continue;
          a += wL[((o * 16 + ic) * 3 + du) * 3 + dv] * inL[ic * 343 + (uu * 7 + vv) * 7 + s];
        }
      }
    float g = BNINV * bnp[o], bt = bnp[16 + o];
    out[(b * 16 + o) * 2401 + ij * 49 + kc * 7 + s] = fmaxf(a * g + bt, 0.f);
  }
}

__global__ __launch_bounds__(256) void k_sep1b(
    const float* __restrict__ in, const float* __restrict__ w,
    const float* __restrict__ bnp, float* __restrict__ out) {
  int ir = blockIdx.x, b = blockIdx.y, t = threadIdx.x;
  __shared__ float inL[16 * 343];
  __shared__ float wL[2304];
  for (int i = t; i < 2304; i += 256) wL[i] = w[i];
  for (int i = t; i < 5488; i += 256) {
    int ic = i / 343, r = i % 343;
    inL[ic * 343 + r] = in[(b * 16 + ic) * 2401 + ir * 343 + r];
  }
  __syncthreads();
  for (int i = t; i < 5488; i += 256) {
    int o = i / 343, r = i % 343;
    int jj = r / 49, kl = r % 49;
    int k = kl / 7, l = kl % 7;
    float a = 0.f;
    for (int ic = 0; ic < 16; ++ic)
#pragma unroll
      for (int dh = 0; dh < 3; ++dh) {
        int k2 = k + dh - 1;
        if (k2 < 0 || k2 > 6) continue;
#pragma unroll
        for (int dw = 0; dw < 3; ++dw) {
          int l2 = l + dw - 1;
          if (l2 < 0 || l2 > 6) continue;
          a += wL[((o * 16 + ic) * 3 + dh) * 3 + dw] * inL[ic * 343 + jj * 49 + k2 * 7 + l2];
        }
      }
    float g = BNINV * bnp[o], bt = bnp[16 + o];
    out[(b * 16 + o) * 2401 + ir * 343 + r] = a * g + bt;  // no relu
  }
}

__global__ void k_sep1p(const float* __restrict__ in, const float* __restrict__ pw,
                        const float* __restrict__ pbn, float* __restrict__ out) {
  int b = blockIdx.x, t = threadIdx.x;
  float g = BNINV * pbn[0], bt = pbn[1];
  __shared__ float pl[16];
  if (t < 16) pl[t] = pw[t];
  __syncthreads();
  for (int i = t; i < 2401; i += 256) {
    float a = 0.f;
#pragma unroll
    for (int ic = 0; ic < 16; ++ic) a += pl[ic] * in[(b * 16 + ic) * 2401 + i];
    out[b * 2401 + i] = a * g + bt;
  }
}

// ------- K10: gauss-normalize + softmax + attention sums -------
__global__ __launch_bounds__(64) void k_attn(const float* __restrict__ c4,
                                             float* __restrict__ attn_s,
                                             float* __restrict__ attn_q) {
  int b = blockIdx.x, t = threadIdx.x;
  __shared__ float c[2401];
  __shared__ float n[2401];
  for (int i = t; i < 2401; i += 64) c[i] = c4[b * 2401 + i];
  __syncthreads();
  if (t < 49) {
    float m = 0.f;
    for (int ij = 0; ij < 49; ++ij) m += c[ij * 49 + t];
    m *= (1.f / 49.f);
    float v = 0.f;
    for (int ij = 0; ij < 49; ++ij) { float d = c[ij * 49 + t] - m; v += d * d; }
    v *= (1.f / 48.f);
    float inv = 1.f / sqrtf(v + 1e-5f);
    float mx = -1e30f;
    for (int ij = 0; ij < 49; ++ij) mx = fmaxf(mx, (c[ij * 49 + t] - m) * inv);
    float s = 0.f;
    for (int ij = 0; ij < 49; ++ij) {
      float e = expf((c[ij * 49 + t] - m) * inv - mx);
      n[ij * 49 + t] = e; s += e;
    }
    float r = 1.f / s;
    for (int ij = 0; ij < 49; ++ij) n[ij * 49 + t] *= r;
  }
  __syncthreads();
  if (t < 49) {
    float s = 0.f;
    for (int kl = 0; kl < 49; ++kl) s += n[t * 49 + kl];
    attn_s[b * 49 + t] = s;
  }
  __syncthreads();
  if (t < 49) {
    float m = 0.f;
    for (int kl = 0; kl < 49; ++kl) m += c[t * 49 + kl];
    m *= (1.f / 49.f);
    float v = 0.f;
    for (int kl = 0; kl < 49; ++kl) { float d = c[t * 49 + kl] - m; v += d * d; }
    v *= (1.f / 48.f);
    float inv = 1.f / sqrtf(v + 1e-5f);
    float mx = -1e30f;
    for (int kl = 0; kl < 49; ++kl) mx = fmaxf(mx, (c[t * 49 + kl] - m) * inv);
    float s = 0.f;
    for (int kl = 0; kl < 49; ++kl) {
      float e = expf((c[t * 49 + kl] - m) * inv - mx);
      n[t * 49 + kl] = e; s += e;
    }
    float r = 1.f / s;
    for (int kl = 0; kl < 49; ++kl) n[t * 49 + kl] *= r;
  }
  __syncthreads();
  if (t < 49) {
    float s = 0.f;
    for (int ij = 0; ij < 49; ++ij) s += n[ij * 49 + t];
    attn_q[b * 49 + t] = s;
  }
}

// ------- K11: attention-weighted mean/max pooling -------
__global__ __launch_bounds__(256) void k_pool(const float* __restrict__ xpn,
                                              const float* __restrict__ attn,
                                              float* __restrict__ ep) {
  int b = blockIdx.x, br = blockIdx.y, t = threadIdx.x;
  const float* xb = xpn + br * 3010560 + b * 47040;  // (p,c)
  const float* a = attn + br * 3136 + b * 49;
  __shared__ float al[49];
  if (t < 49) al[t] = a[t];
  __syncthreads();
  float* eb = ep + br * 122880 + b * 1920;
  for (int c = t; c < 960; c += 256) {
    float s = 0.f, mx = -1e30f;
    for (int hw = 0; hw < 49; ++hw) {
      float v = al[hw] * xb[hw * 960 + c];
      s += v; mx = fmaxf(mx, v);
    }
    eb[c] = s * (1.f / 49.f);
    eb[960 + c] = mx;
  }
}

// ------- M=64 GEMM, split-K with atomicAdd -------
__global__ __launch_bounds__(256) void k_gemm64(
    const float* __restrict__ A0, const float* __restrict__ A1, int asplit,
    int reluA, const float* __restrict__ W, int K, int Kslice,
    float* __restrict__ C, int N) {
  int otile = blockIdx.x, ks = blockIdx.y;
  int t = threadIdx.x, bt = t >> 4, ot = t & 15;
  __shared__ __align__(16) float eT[48 * 68];
  __shared__ __align__(16) float wT[48 * 68];
  float acc[4][4];
#pragma unroll
  for (int i = 0; i < 4; ++i)
#pragma unroll
    for (int j = 0; j < 4; ++j) acc[i][j] = 0.f;
  int kbeg = ks * Kslice, kend = kbeg + Kslice;
  for (int k0 = kbeg; k0 < kend; k0 += 48) {
    __syncthreads();
    for (int i = t; i < 768; i += 256) {
      int b = i / 12, kg = i % 12;
      int k = k0 + kg * 4;
      float4 v;
      if (asplit) {
        v = (k < asplit) ? *(const float4*)&A0[b * 1920 + k]
                         : *(const float4*)&A1[b * 1920 + k - asplit];
      } else {
        v = *(const float4*)&A0[b * K + k];
      }
      if (reluA) {
        v.x = fmaxf(v.x, 0.f); v.y = fmaxf(v.y, 0.f);
        v.z = fmaxf(v.z, 0.f); v.w = fmaxf(v.w, 0.f);
      }
      eT[(kg * 4 + 0) * 68 + b] = v.x; eT[(kg * 4 + 1) * 68 + b] = v.y;
      eT[(kg * 4 + 2) * 68 + b] = v.z; eT[(kg * 4 + 3) * 68 + b] = v.w;
    }
    for (int i = t; i < 768; i += 256) {
      int o = i / 12, kg = i % 12;
      float4 v = *(const float4*)&W[(otile * 64 + o) * K + k0 + kg * 4];
      wT[(kg * 4 + 0) * 68 + o] = v.x; wT[(kg * 4 + 1) * 68 + o] = v.y;
      wT[(kg * 4 + 2) * 68 + o] = v.z; wT[(kg * 4 + 3) * 68 + o] = v.w;
    }
    __syncthreads();
#pragma unroll 4
    for (int kk = 0; kk < 48; ++kk) {
      float av[4], wv[4];
      *(float4*)av = *(const float4*)&eT[kk * 68 + bt * 4];
      *(float4*)wv = *(const float4*)&wT[kk * 68 + ot * 4];
#pragma unroll
      for (int i = 0; i < 4; ++i)
#pragma unroll
        for (int j = 0; j < 4; ++j) acc[i][j] += av[i] * wv[j];
    }
  }
#pragma unroll
  for (int i = 0; i < 4; ++i)
#pragma unroll
    for (int j = 0; j < 4; ++j)
      atomicAdd(&C[(bt * 4 + i) * N + otile * 64 + ot * 4 + j], acc[i][j]);
}

// ------- group pooling over 2.5D groups (+ deferred bias from mlp2) -------
__global__ void k_poolg(const float* __restrict__ em3m, const float* __restrict__ em3e,
                        const float* __restrict__ b2m, const float* __restrict__ b2e,
                        float* __restrict__ pm) {
  int g = blockIdx.x, which = blockIdx.y, t = threadIdx.x;
  const float* em = which ? em3e : em3m;
  const float* b2 = which ? b2e : b2m;
  for (int d = t; d < 960; d += 256) {
    float s = 0.f;
    for (int r = 0; r < 8; ++r) s += em[(g * 8 + r) * 960 + d];
    pm[which * 7680 + g * 960 + d] = s * 0.125f + b2[d];
  }
}

// ------- classifier layer 1: hardswish(pm @ W1^T + b1) -------
__global__ __launch_bounds__(256) void k_cls1(
    const float* __restrict__ pmbase, const float* __restrict__ w1mT,
    const float* __restrict__ b1m, const float* __restrict__ w1eT,
    const float* __restrict__ b1e, float* __restrict__ h2) {
  int which = blockIdx.y, t = threadIdx.x;
  const float* pmw = pmbase + which * 7680;
  const float* WT = which ? w1eT : w1mT;
  const float* b1 = which ? b1e : b1m;
  __shared__ float pl[7680];
  for (int i = t; i < 7680; i += 256) pl[i] = pmw[i];
  __syncthreads();
  int o = blockIdx.x * 256 + t;
  if (o >= 1920) return;
  float acc[8] = {0.f, 0.f, 0.f, 0.f, 0.f, 0.f, 0.f, 0.f};
#pragma unroll 4
  for (int k = 0; k < 960; ++k) {
    float w = WT[k * 1920 + o];
#pragma unroll
    for (int g = 0; g < 8; ++g) acc[g] += w * pl[g * 960 + k];
  }
  float bb = b1[o];
#pragma unroll
  for (int g = 0; g < 8; ++g) {
    float z = acc[g] + bb;
    h2[which * 15360 + g * 1920 + o] = z * fminf(fmaxf(z + 3.f, 0.f), 6.f) * (1.f / 6.f);
  }
}

// ------- classifier layer 2 + final concat -------
__global__ __launch_bounds__(256) void k_cls2(
    const float* __restrict__ h2, const float* __restrict__ w2m,
    const float* __restrict__ b2m, const float* __restrict__ w2e,
    const float* __restrict__ b2e, float* __restrict__ out) {
  int which = blockIdx.x, t = threadIdx.x;
  const float* h = h2 + which * 15360;
  const float* W = which ? w2e : w2m;
  const float* bb = which ? b2e : b2m;
  __shared__ float red[256];
  for (int gj = 0; gj < 16; ++gj) {
    int g = gj >> 1, j = gj & 1;
    float s = 0.f;
    for (int k = t; k < 1920; k += 256) s += h[g * 1920 + k] * W[j * 1920 + k];
    red[t] = s;
    __syncthreads();
    for (int off = 128; off >= 1; off >>= 1) {
      if (t < off) red[t] += red[t + off];
      __syncthreads();
    }
    if (t == 0) out[g * 4 + which * 2 + j] = red[0] + bb[j];
    __syncthreads();
  }
}

// =======================================================================
extern "C" void kernel_launch(void* const* d_in, const int* in_sizes, int n_in,
                              void* d_out, int out_size, void* d_ws, size_t ws_size,
                              hipStream_t stream) {
  const float* x_p = (const float*)d_in[0];
  const float* x_i = (const float*)d_in[1];
  const float* scr_w_in = (const float*)d_in[2];
  const float* scr_bn_in = (const float*)d_in[3];
  const float* scr_w1 = (const float*)d_in[4];
  const float* scr_bn1 = (const float*)d_in[5];
  const float* scr_w2 = (const float*)d_in[6];
  const float* scr_bn2 = (const float*)d_in[7];
  const float* scr_w_out = (const float*)d_in[8];
  const float* scr_bn_out = (const float*)d_in[9];
  const float* cca1x1_w = (const float*)d_in[10];
  const float* cca1x1_bn = (const float*)d_in[11];
  const float* cca0_c2_w = (const float*)d_in[12];
  const float* cca0_c2_bn = (const float*)d_in[13];
  const float* cca0_c1_w = (const float*)d_in[14];
  const float* cca0_c1_bn = (const float*)d_in[15];
  const float* cca0_p_w = (const float*)d_in[16];
  const float* cca0_p_bn = (const float*)d_in[17];
  const float* cca1_c2_w = (const float*)d_in[18];
  const float* cca1_c2_bn = (const float*)d_in[19];
  const float* cca1_c1_w = (const float*)d_in[20];
  const float* cca1_c1_bn = (const float*)d_in[21];
  const float* cca1_p_w = (const float*)d_in[22];
  const float* cca1_p_bn = (const float*)d_in[23];
  const float* meta_w1 = (const float*)d_in[24];
  const float* meta_w2 = (const float*)d_in[25];
  const float* meta_b2 = (const float*)d_in[26];
  const float* ene_w1 = (const float*)d_in[27];
  const float* ene_w2 = (const float*)d_in[28];
  const float* ene_b2 = (const float*)d_in[29];
  const float* mcls_w1 = (const float*)d_in[30];
  const float* mcls_b1 = (const float*)d_in[31];
  const float* mcls_w2 = (const float*)d_in[32];
  const float* mcls_b2 = (const float*)d_in[33];
  const float* ecls_w1 = (const float*)d_in[34];
  const float* ecls_b1 = (const float*)d_in[35];
  const float* ecls_w2 = (const float*)d_in[36];
  const float* ecls_b2 = (const float*)d_in[37];

  float* ws = (float*)d_ws;
  float* XN = ws + OFF_XN;
  float* Y1 = ws + OFF_Y1;
  float* Y2 = ws + OFF_Y2;
  float* T = ws + OFF_T;
  float* XPN = ws + OFF_XPN;
  float* SQ = ws + OFF_SQ;
  float* CORR = ws + OFF_CORR;
  float* S0Y1 = ws + OFF_S0Y1;
  float* S0Y2 = ws + OFF_S0Y2;
  float* S0P = ws + OFF_S0P;
  float* S1Y1 = ws + OFF_S1Y1;
  float* S1Y2 = ws + OFF_S1Y2;
  float* C4F = ws + OFF_C4F;
  float* ATT = ws + OFF_ATT;
  float* EPI = ws + OFF_EPI;
  float* H1 = ws + OFF_H1;
  float* EM3 = ws + OFF_EM3;
  float* PM = ws + OFF_PM;
  float* H2 = ws + OFF_H2;
  float* WOUTT = ws + OFF_WOUTT;
  float* CCAT = ws + OFF_CCAT;
  float* MCLST = ws + OFF_MCLST;
  float* ECLST = ws + OFF_ECLST;
  float* W1T = ws + OFF_W1T;
  float* W2T = ws + OFF_W2T;

  // weight preps (small, every call)
  k_transpose<<<(960 * 96 + 255) / 256, 256, 0, stream>>>(scr_w_out, WOUTT, 960, 96);
  k_transpose<<<(96 * 960 + 255) / 256, 256, 0, stream>>>(cca1x1_w, CCAT, 96, 960);
  k_transpose<<<(1920 * 960 + 255) / 256, 256, 0, stream>>>(mcls_w1, MCLST, 1920, 960);
  k_transpose<<<(1920 * 960 + 255) / 256, 256, 0, stream>>>(ecls_w1, ECLST, 1920, 960);
  k_prepw<<<dim3(432, 2), 256, 0, stream>>>(scr_w1, scr_w2, W1T, W2T);

  for (int br = 0; br < 2; ++br) {
    const float* x = br ? x_i : x_p;
    k_l2n<<<64, 256, 0, stream>>>(x, XN);
    k_scr_in<<<dim3(7, 64), 256, 0, stream>>>(XN, scr_w_in, scr_bn_in, Y1);
    k_conv1<<<392, 256, 0, stream>>>(Y1, W1T, scr_bn1, Y2);
    k_conv2<<<392, 128, 0, stream>>>(Y2, W2T, scr_bn2, T);
    k_scr_out<<<dim3(7, 64), 256, 0, stream>>>(T, WOUTT, scr_bn_out, x,
                                               XPN + br * 3010560);
    k_cca1<<<dim3(7, 64), 128, 0, stream>>>(XPN + br * 3010560, CCAT, cca1x1_bn,
                                            SQ + br * 301056);
  }
  k_corr<<<64, 256, 0, stream>>>(SQ, SQ + 301056, CORR);
  k_sep0<<<64, 256, 0, stream>>>(CORR, cca0_c2_w, cca0_c2_bn, S0Y1, 1, 1);
  k_sep0<<<64, 256, 0, stream>>>(S0Y1, cca0_c1_w, cca0_c1_bn, S0Y2, 0, 0);
  k_sep0p<<<dim3(64, 16), 256, 0, stream>>>(S0Y2, cca0_p_w, cca0_p_bn, S0P);
  k_sep1a<<<dim3(7, 64), 256, 0, stream>>>(S0P, cca1_c2_w, cca1_c2_bn, S1Y1);
  k_sep1b<<<dim3(7, 64), 256, 0, stream>>>(S1Y1, cca1_c1_w, cca1_c1_bn, S1Y2);
  k_sep1p<<<64, 256, 0, stream>>>(S1Y2, cca1_p_w, cca1_p_bn, C4F);
  k_attn<<<64, 64, 0, stream>>>(C4F, ATT, ATT + 3136);
  k_pool<<<dim3(64, 2), 256, 0, stream>>>(XPN, ATT, EPI);

  hipMemsetAsync(H1, 0, (245760u + 122880u) * sizeof(float), stream);
  k_gemm64<<<dim3(30, 8), 256, 0, stream>>>(EPI, EPI + 122880, 960, 0, meta_w1,
                                            1920, 240, H1, 1920);
  k_gemm64<<<dim3(30, 8), 256, 0, stream>>>(EPI + 960, EPI + 122880 + 960, 960, 0,
                                            ene_w1, 1920, 240, H1 + 122880, 1920);
  k_gemm64<<<dim3(15, 8), 256, 0, stream>>>(H1, nullptr, 0, 1, meta_w2, 1920, 240,
                                            EM3, 960);
  k_gemm64<<<dim3(15, 8), 256, 0, stream>>>(H1 + 122880, nullptr, 0, 1, ene_w2,
                                            1920, 240, EM3 + 61440, 960);
  k_poolg<<<dim3(8, 2), 256, 0, stream>>>(EM3, EM3 + 61440, meta_b2, ene_b2, PM);
  k_cls1<<<dim3(8, 2), 256, 0, stream>>>(PM, MCLST, mcls_b1, ECLST, ecls_b1, H2);
  k_cls2<<<2, 256, 0, stream>>>(H2, mcls_w2, mcls_b2, ecls_w2, ecls_b2,
                                (float*)d_out);
}

// Round 3
// 1952.292 us; speedup vs baseline: 2.0409x; 1.2143x over previous
//
#include <hip/hip_runtime.h>
#include <hip/hip_bf16.h>

// RtNet25DDualRENet forward. Round 3: k_scr_in rewritten with bf16 MFMA
// (was grid-limited occupancy fp32 VALU: 415us/dispatch, VALUBusy 44%, occ 21%).
// B=64, C=960, H=W=7. Workspace requirement: ~32.7M floats (~131 MB).

#define BNINV 0.9999950000374997f  // 1/sqrt(1+1e-5)

typedef __attribute__((ext_vector_type(8))) short bf16x8;
typedef __attribute__((ext_vector_type(4))) float f32x4;

__device__ inline unsigned short f2bf(float f) {
  union { float f; unsigned u; } x; x.f = f;
  unsigned r = x.u + 0x7fffu + ((x.u >> 16) & 1u);  // RNE
  return (unsigned short)(r >> 16);
}

// ---------------- workspace layout (float offsets) ----------------
#define OFF_XN      0u            // (b,960,49)  branch-reused
#define OFF_Y1      3010560u      // (b,96,49,25)
#define OFF_Y2      10536960u     // (b,49,96,9)
#define OFF_T       13246464u     // (b,49,96)
#define OFF_XPN     13547520u     // 2 x (b,49,960)
#define OFF_SQ      19568640u     // 2 x (b,49,96)
#define OFF_CORR    20170752u     // (b,49,49)
#define OFF_S0Y1    20324416u
#define OFF_S0Y2    20478080u
#define OFF_S0P     20631744u     // (b,16,49,49) -- ALSO reused early for W1T/W2T/WBF
#define OFF_S1Y1    23090368u
#define OFF_S1Y2    25548992u
#define OFF_C4F     28007616u     // (b,49,49)
#define OFF_ATT     28161280u     // attn_s[64*49], attn_q[64*49]
#define OFF_EPI     28167552u     // ep[64*1920], ei[64*1920]
#define OFF_H1      28413312u     // 2 x (64,1920)
#define OFF_EM3     28659072u     // 2 x (64,960)
#define OFF_PM      28781952u     // 2 x (8,960)
#define OFF_H2      28797312u     // 2 x (8,1920)
#define OFF_WOUTT   28828032u     // w_out^T [96][960]
#define OFF_CCAT    28920192u     // cca1x1_w^T [960][96]
#define OFF_MCLST   29012352u     // mcls_w1^T [960][1920]
#define OFF_ECLST   30855552u     // ecls_w1^T [960][1920]
// W1T/W2T/WBF live in the S0P region (only needed during branch loop)
#define OFF_W1T     OFF_S0P
#define OFF_W2T     (OFF_S0P + 110592u)
#define OFF_WBF     (OFF_S0P + 221184u)   // 46080 uints (96x960 bf16 pairs)

// ---------------- generic transpose: in[R][C] -> out[C][R] ----------------
__global__ void k_transpose(const float* __restrict__ in, float* __restrict__ out,
                            int R, int C) {
  int i = blockIdx.x * 256 + threadIdx.x;
  if (i < R * C) {
    int r = i / C, c = i % C;
    out[c * R + r] = in[i];
  }
}

// ---- prep: w[o][ic][9] -> WT[ic][o][12] (taps padded with 0) ----
__global__ void k_prepw(const float* __restrict__ w1, const float* __restrict__ w2,
                        float* __restrict__ W1T, float* __restrict__ W2T) {
  int i = blockIdx.x * 256 + threadIdx.x;  // over 96*96*12
  if (i >= 110592) return;
  int tap = i % 12, rest = i / 12, o = rest % 96, ic = rest / 96;
  const float* w = blockIdx.y ? w2 : w1;
  float v = (tap < 9) ? w[(o * 96 + ic) * 9 + tap] : 0.f;
  (blockIdx.y ? W2T : W1T)[i] = v;
}

// ---- prep: scr_w_in (96x960 fp32) -> packed bf16 pairs ----
__global__ void k_prepwbf(const float* __restrict__ w_in, unsigned* __restrict__ WbfU) {
  int i = blockIdx.x * 256 + threadIdx.x;  // 46080
  if (i >= 46080) return;
  float a = w_in[2 * i], b = w_in[2 * i + 1];
  WbfU[i] = (unsigned)f2bf(a) | ((unsigned)f2bf(b) << 16);
}

// ---------------- K1: relu + l2-normalize over C per (b,p) ----------------
__global__ __launch_bounds__(256) void k_l2n(const float* __restrict__ x,
                                             float* __restrict__ xn) {
  int b = blockIdx.x, t = threadIdx.x;
  __shared__ float red[256];
  __shared__ float inv[49];
  const float* xb = x + b * 47040;
  float* ob = xn + b * 47040;
  int p = t & 63, sl = t >> 6;
  float s = 0.f;
  if (p < 49) {
    for (int c = sl * 240; c < sl * 240 + 240; ++c) {
      float v = xb[c * 49 + p];
      if (v > 0.f) s += v * v;
    }
  }
  red[t] = s;
  __syncthreads();
  if (t < 49) {
    float q = red[t] + red[t + 64] + red[t + 128] + red[t + 192];
    inv[t] = 1.f / fmaxf(sqrtf(q), 1e-12f);
  }
  __syncthreads();
  for (int i = t; i < 47040; i += 256) {
    float v = xb[i];
    ob[i] = v > 0.f ? v * inv[i % 49] : 0.f;
  }
}

// ------- K2: fused self-corr x scr_w_in einsum + BN + relu (bf16 MFMA) -------
// Per (h,b) block: y1[96 o][175 cols] = W[96x960] x P[960x175],
// P[c,col] = xn[c,(h,wp)] * xn_pad[c,(h+du-2, wp+dv-2)] built on the fly.
// block 256 = 4 waves; wave handles 6 M-tiles x 3 N-tiles of 16x16.
__global__ __launch_bounds__(256) void k_scr_in(
    const float* __restrict__ xn, const unsigned* __restrict__ WbfU,
    const float* __restrict__ bn, float* __restrict__ y1) {
  const int h = blockIdx.x, b = blockIdx.y, t = threadIdx.x;
  const int wave = t >> 6, lane = t & 63, quad = lane >> 4, lr = lane & 15;
  __shared__ __align__(16) short Pl[192 * 72];   // [col][k] bf16, stride 72
  __shared__ __align__(16) short Wl[96 * 72];    // [o][k] bf16, stride 72
  __shared__ __align__(16) float xc[64 * 61];    // [k][5x12 window], stride 61
  unsigned* Plu = (unsigned*)Pl;
  unsigned* Wlu = (unsigned*)Wl;
  f32x4 acc[6][3];
#pragma unroll
  for (int m = 0; m < 6; ++m)
#pragma unroll
    for (int n = 0; n < 3; ++n) acc[m][n] = (f32x4){0.f, 0.f, 0.f, 0.f};
  const float* xb = xn + b * 47040;
  // P-build items: i = col*4 + kq  (col 0..191, kq 0..3 -> 16 k's each)
  int i1A[3], i2A[3], colA[3], kqA[3];
#pragma unroll
  for (int it = 0; it < 3; ++it) {
    int i = t + it * 256;
    int col = i >> 2, kq = i & 3;
    int cc = col < 175 ? col : 174;
    int wp = cc / 25, uv = cc - wp * 25, du = uv / 5, dv = uv - du * 5;
    colA[it] = col; kqA[it] = kq;
    i1A[it] = 26 + wp;             // center: row 2, col wp+2
    i2A[it] = du * 12 + wp + dv;   // neighbor
  }
  for (int k0 = 0; k0 < 960; k0 += 64) {
    __syncthreads();
    // stage xc: 64 k x 60 window floats
    for (int i = t; i < 3840; i += 256) {
      int kk = i / 60, j = i - kk * 60;
      int r = j / 12, wc = j - r * 12;
      int row = h + r - 2, w = wc - 2;
      float v = 0.f;
      if ((unsigned)row < 7u && (unsigned)w < 7u)
        v = xb[(k0 + kk) * 49 + row * 7 + w];
      xc[kk * 61 + j] = v;
    }
    // stage W bf16: 96 o x 32 uint-pairs
    {
      int base = k0 >> 1;
      for (int i = t; i < 3072; i += 256) {
        int o = i >> 5, kp = i & 31;
        Wlu[o * 36 + kp] = WbfU[o * 480 + base + kp];
      }
    }
    __syncthreads();
    // build P (bf16 packed pairs)
#pragma unroll
    for (int it = 0; it < 3; ++it) {
      int col = colA[it], i1 = i1A[it], i2 = i2A[it];
      int kb = kqA[it] * 16;
      unsigned* dst = Plu + col * 36 + (kb >> 1);
#pragma unroll
      for (int kk2 = 0; kk2 < 8; ++kk2) {
        int kA = kb + kk2 * 2;
        float v0 = xc[kA * 61 + i1] * xc[kA * 61 + i2];
        float v1 = xc[(kA + 1) * 61 + i1] * xc[(kA + 1) * 61 + i2];
        dst[kk2] = (unsigned)f2bf(v0) | ((unsigned)f2bf(v1) << 16);
      }
    }
    __syncthreads();
    // MFMA: 2 k-steps of 32
#pragma unroll
    for (int s = 0; s < 2; ++s) {
      int ko = s * 32 + quad * 8;
      bf16x8 af[6], bfr[3];
#pragma unroll
      for (int m = 0; m < 6; ++m)
        af[m] = *(const bf16x8*)&Wl[(m * 16 + lr) * 72 + ko];
#pragma unroll
      for (int n = 0; n < 3; ++n)
        bfr[n] = *(const bf16x8*)&Pl[(wave * 48 + n * 16 + lr) * 72 + ko];
#pragma unroll
      for (int m = 0; m < 6; ++m)
#pragma unroll
        for (int n = 0; n < 3; ++n)
          acc[m][n] = __builtin_amdgcn_mfma_f32_16x16x32_bf16(
              af[m], bfr[n], acc[m][n], 0, 0, 0);
    }
  }
  // epilogue: C/D layout col=lane&15, row=quad*4+reg
#pragma unroll
  for (int n = 0; n < 3; ++n) {
    int col = wave * 48 + n * 16 + lr;
    if (col >= 175) continue;
    int wp = col / 25, uv = col - wp * 25;
    long pb = ((long)(b * 96) * 49 + h * 7 + wp) * 25 + uv;
#pragma unroll
    for (int m = 0; m < 6; ++m) {
#pragma unroll
      for (int r = 0; r < 4; ++r) {
        int o = m * 16 + quad * 4 + r;
        float g = BNINV * bn[o], bt = bn[96 + o];
        y1[pb + (long)o * 49 * 25] = fmaxf(acc[m][n][r] * g + bt, 0.f);
      }
    }
  }
}

// ---------------- K3: SCR conv1 (1,3,3) 5x5->3x3, BN, relu ----------------
__global__ __launch_bounds__(256) void k_conv1(
    const float* __restrict__ y1, const float* __restrict__ W1T,
    const float* __restrict__ bn1, float* __restrict__ y2g) {
  const int t = threadIdx.x;
  const int tx = t & 7;    // pair slot
  const int ty = t >> 3;   // 0..31 -> o-trio
  const int pairBase = blockIdx.x * 8;
  __shared__ __align__(16) float Wc[9216];      // [8 ic][96 o][12 tap-pad]
  __shared__ __align__(16) float Raw[8 * 228];  // [pair][8 ic * 28-pad]
  float acc[3][9];
#pragma unroll
  for (int m = 0; m < 3; ++m)
#pragma unroll
    for (int d = 0; d < 9; ++d) acc[m][d] = 0.f;
  const int pair = pairBase + tx;
  for (int ch = 0; ch < 12; ++ch) {
    __syncthreads();
    {
      const float4* src = (const float4*)(W1T + ch * 9216);
      float4* dst = (float4*)Wc;
      for (int i = t; i < 2304; i += 256) dst[i] = src[i];
    }
    for (int i = t; i < 1600; i += 256) {
      int pr = i / 200, r = i - pr * 200, ic = r / 25, uv = r - ic * 25;
      int pp = pairBase + pr, bb = pp / 49, pq = pp - bb * 49;
      Raw[pr * 228 + ic * 28 + uv] =
          y1[((bb * 96 + ch * 8 + ic) * 49 + pq) * 25 + uv];
    }
    __syncthreads();
#pragma unroll
    for (int ic = 0; ic < 8; ++ic) {
      float r[25];
      const float* rb = &Raw[tx * 228 + ic * 28];
      *(float4*)&r[0]  = *(const float4*)&rb[0];
      *(float4*)&r[4]  = *(const float4*)&rb[4];
      *(float4*)&r[8]  = *(const float4*)&rb[8];
      *(float4*)&r[12] = *(const float4*)&rb[12];
      *(float4*)&r[16] = *(const float4*)&rb[16];
      *(float4*)&r[20] = *(const float4*)&rb[20];
      r[24] = rb[24];
#pragma unroll
      for (int m = 0; m < 3; ++m) {
        float w[12];
        const float* wb = &Wc[(ic * 96 + ty * 3 + m) * 12];
        *(float4*)&w[0] = *(const float4*)&wb[0];
        *(float4*)&w[4] = *(const float4*)&wb[4];
        *(float4*)&w[8] = *(const float4*)&wb[8];
#pragma unroll
        for (int i2 = 0; i2 < 3; ++i2)
#pragma unroll
          for (int j2 = 0; j2 < 3; ++j2) {
            float s = acc[m][i2 * 3 + j2];
#pragma unroll
            for (int di = 0; di < 3; ++di)
#pragma unroll
              for (int dj = 0; dj < 3; ++dj)
                s += w[di * 3 + dj] * r[(i2 + di) * 5 + (j2 + dj)];
            acc[m][i2 * 3 + j2] = s;
          }
      }
    }
  }
#pragma unroll
  for (int m = 0; m < 3; ++m) {
    int o = ty * 3 + m;
    float g = BNINV * bn1[o], bt = bn1[96 + o];
#pragma unroll
    for (int d = 0; d < 9; ++d)
      y2g[(pair * 96 + o) * 9 + d] = fmaxf(acc[m][d] * g + bt, 0.f);
  }
}

// ---------------- K4: SCR conv2 (1,3,3) 3x3->1, BN, relu ----------------
__global__ __launch_bounds__(128) void k_conv2(
    const float* __restrict__ y2g, const float* __restrict__ W2T,
    const float* __restrict__ bn2, float* __restrict__ tout) {
  const int t = threadIdx.x;
  const int tx = t & 7;    // pair
  const int ty = t >> 3;   // 0..15 -> o = ty*6 + j
  const int pairBase = blockIdx.x * 8;
  __shared__ __align__(16) float Wc[9216];      // [8 ic][96 o][12]
  __shared__ __align__(16) float Yl[8 * 100];   // [pair][8 ic * 12-pad]
  float acc[6] = {0.f, 0.f, 0.f, 0.f, 0.f, 0.f};
  const int pair = pairBase + tx;
  for (int ch = 0; ch < 12; ++ch) {
    __syncthreads();
    {
      const float4* src = (const float4*)(W2T + ch * 9216);
      float4* dst = (float4*)Wc;
      for (int i = t; i < 2304; i += 128) dst[i] = src[i];
    }
    for (int i = t; i < 576; i += 128) {
      int pr = i / 72, k = i - pr * 72, ic = k / 9, tap = k - ic * 9;
      Yl[pr * 100 + ic * 12 + tap] = y2g[(pairBase + pr) * 864 + ch * 72 + k];
    }
    __syncthreads();
#pragma unroll
    for (int ic = 0; ic < 8; ++ic) {
      float y[9];
      const float* yb = &Yl[tx * 100 + ic * 12];
      *(float4*)&y[0] = *(const float4*)&yb[0];
      *(float4*)&y[4] = *(const float4*)&yb[4];
      y[8] = yb[8];
#pragma unroll
      for (int j = 0; j < 6; ++j) {
        float w[12];
        const float* wb = &Wc[(ic * 96 + ty * 6 + j) * 12];
        *(float4*)&w[0] = *(const float4*)&wb[0];
        *(float4*)&w[4] = *(const float4*)&wb[4];
        *(float4*)&w[8] = *(const float4*)&wb[8];
        float s = acc[j];
#pragma unroll
        for (int d = 0; d < 9; ++d) s += w[d] * y[d];
        acc[j] = s;
      }
    }
  }
#pragma unroll
  for (int j = 0; j < 6; ++j) {
    int o = ty * 6 + j;
    tout[pair * 96 + o] =
        fmaxf(acc[j] * (BNINV * bn2[o]) + bn2[96 + o], 0.f);
  }
}

// ------- K5: w_out GEMM + BN + residual relu + channel-mean subtract -------
__global__ __launch_bounds__(256) void k_scr_out(
    const float* __restrict__ tin, const float* __restrict__ wouT,
    const float* __restrict__ bno, const float* __restrict__ x,
    float* __restrict__ xpn) {
  int pr = blockIdx.x, b = blockIdx.y, t = threadIdx.x;
  __shared__ __align__(16) float tl2[96 * 8];
  __shared__ float xr[7 * 960];
  __shared__ float xl[7 * 960];
  __shared__ float red[7 * 32];
  __shared__ float mean[7];
  for (int i = t; i < 672; i += 256) {
    int pl = i / 96, ic = i % 96;
    tl2[ic * 8 + pl] = tin[(b * 49 + pr * 7 + pl) * 96 + ic];
  }
  for (int i = t; i < 672; i += 256) tl2[(i % 96) * 8 + 7] = 0.f;
  for (int i = t; i < 6720; i += 256) {
    int o = i / 7, pl = i % 7;
    xl[pl * 960 + o] = x[(b * 960 + o) * 49 + pr * 7 + pl];
  }
  __syncthreads();
  for (int o = t; o < 960; o += 256) {
    float acc[7] = {0.f, 0.f, 0.f, 0.f, 0.f, 0.f, 0.f};
#pragma unroll 4
    for (int ic = 0; ic < 96; ++ic) {
      float w = wouT[ic * 960 + o];
      float tv[8];
      *(float4*)&tv[0] = *(const float4*)&tl2[ic * 8];
      *(float4*)&tv[4] = *(const float4*)&tl2[ic * 8 + 4];
#pragma unroll
      for (int pl = 0; pl < 7; ++pl) acc[pl] += w * tv[pl];
    }
    float g = BNINV * bno[o], bt = bno[960 + o];
#pragma unroll
    for (int pl = 0; pl < 7; ++pl)
      xr[pl * 960 + o] = fmaxf(xl[pl * 960 + o] + acc[pl] * g + bt, 0.f);
  }
  __syncthreads();
  if (t < 224) {
    int pl = t >> 5, ln = t & 31;
    float s = 0.f;
    for (int o = ln; o < 960; o += 32) s += xr[pl * 960 + o];
    red[pl * 32 + ln] = s;
  }
  __syncthreads();
  if (t < 7) {
    float s = 0.f;
    for (int i = 0; i < 32; ++i) s += red[t * 32 + i];
    mean[t] = s * (1.f / 960.f);
  }
  __syncthreads();
  for (int i = t; i < 6720; i += 256) {
    int pl = i / 960, o = i % 960;
    xpn[(b * 49 + pr * 7 + pl) * 960 + o] = xr[pl * 960 + o] - mean[pl];
  }
}

// ------- K6: cca1 1x1 + BN + relu + l2-normalize(96, eps 1e-8) -------
__global__ __launch_bounds__(128) void k_cca1(
    const float* __restrict__ xpn, const float* __restrict__ ccaT,
    const float* __restrict__ bnc, float* __restrict__ sq) {
  int pr = blockIdx.x, b = blockIdx.y, t = threadIdx.x;
  __shared__ __align__(16) float xl2[960 * 8];
  __shared__ float sv[7 * 96];
  __shared__ float red[7 * 16];
  __shared__ float inv[7];
  for (int i = t; i < 6720; i += 128) {
    int pl = i / 960, c = i % 960;
    xl2[c * 8 + pl] = xpn[(b * 49 + pr * 7 + pl) * 960 + c];
  }
  for (int c = t; c < 960; c += 128) xl2[c * 8 + 7] = 0.f;
  __syncthreads();
  if (t < 96) {
    float acc[7] = {0.f, 0.f, 0.f, 0.f, 0.f, 0.f, 0.f};
#pragma unroll 4
    for (int c = 0; c < 960; ++c) {
      float w = ccaT[c * 96 + t];
      float tv[8];
      *(float4*)&tv[0] = *(const float4*)&xl2[c * 8];
      *(float4*)&tv[4] = *(const float4*)&xl2[c * 8 + 4];
#pragma unroll
      for (int pl = 0; pl < 7; ++pl) acc[pl] += w * tv[pl];
    }
    float g = BNINV * bnc[t], bt = bnc[96 + t];
#pragma unroll
    for (int pl = 0; pl < 7; ++pl)
      sv[pl * 96 + t] = fmaxf(acc[pl] * g + bt, 0.f);
  }
  __syncthreads();
  if (t < 112) {
    int pl = t >> 4, ln = t & 15;
    float s = 0.f;
    for (int o = ln; o < 96; o += 16) { float v = sv[pl * 96 + o]; s += v * v; }
    red[pl * 16 + ln] = s;
  }
  __syncthreads();
  if (t < 7) {
    float s = 0.f;
    for (int i = 0; i < 16; ++i) s += red[t * 16 + i];
    inv[t] = 1.f / fmaxf(sqrtf(s), 1e-8f);
  }
  __syncthreads();
  for (int i = t; i < 672; i += 128) {
    int pl = i / 96, o = i % 96;
    sq[(b * 49 + pr * 7 + pl) * 96 + o] = sv[pl * 96 + o] * inv[pl];
  }
}

// ---------------- K7: corr[b,ij,kl] = sum_c spt[c,ij]*qry[c,kl] ----------------
__global__ __launch_bounds__(256) void k_corr(const float* __restrict__ sq0,
                                              const float* __restrict__ sq1,
                                              float* __restrict__ corr) {
  int b = blockIdx.x, t = threadIdx.x;
  __shared__ float sL[49 * 97];
  __shared__ float qL[49 * 97];
  for (int i = t; i < 4704; i += 256) {
    int p = i / 96, c = i % 96;
    sL[p * 97 + c] = sq0[b * 4704 + i];
    qL[p * 97 + c] = sq1[b * 4704 + i];
  }
  __syncthreads();
  for (int i = t; i < 2401; i += 256) {
    int ij = i / 49, kl = i % 49;
    float a = 0.f;
#pragma unroll 4
    for (int c = 0; c < 96; ++c) a += sL[ij * 97 + c] * qL[kl * 97 + c];
    corr[b * 2401 + i] = a;
  }
}

// ---------------- sep4d #0: 1-channel 3x3 convs ----------------
__global__ void k_sep0(const float* __restrict__ in, const float* __restrict__ w9,
                       const float* __restrict__ bnp, float* __restrict__ out,
                       int overUV, int doRelu) {
  int b = blockIdx.x, t = threadIdx.x;
  __shared__ float c[2401];
  for (int i = t; i < 2401; i += 256) c[i] = in[b * 2401 + i];
  float w[9];
#pragma unroll
  for (int d = 0; d < 9; ++d) w[d] = w9[d];
  float g = BNINV * bnp[0], bt = bnp[1];
  __syncthreads();
  for (int i = t; i < 2401; i += 256) {
    int ij = i / 49, kl = i % 49;
    float a = 0.f;
    if (overUV) {
      int u = ij / 7, v = ij % 7;
      for (int du = 0; du < 3; ++du)
        for (int dv = 0; dv < 3; ++dv) {
          int uu = u + du - 1, vv = v + dv - 1;
          if (uu >= 0 && uu < 7 && vv >= 0 && vv < 7)
            a += w[du * 3 + dv] * c[(uu * 7 + vv) * 49 + kl];
        }
    } else {
      int kk = kl / 7, ll = kl % 7;
      for (int dh = 0; dh < 3; ++dh)
        for (int dw = 0; dw < 3; ++dw) {
          int k2 = kk + dh - 1, l2 = ll + dw - 1;
          if (k2 >= 0 && k2 < 7 && l2 >= 0 && l2 < 7)
            a += w[dh * 3 + dw] * c[ij * 49 + k2 * 7 + l2];
        }
    }
    a = a * g + bt;
    out[b * 2401 + i] = doRelu ? fmaxf(a, 0.f) : a;
  }
}

__global__ void k_sep0p(const float* __restrict__ in, const float* __restrict__ pw,
                        const float* __restrict__ pbn, float* __restrict__ out) {
  int b = blockIdx.x, o = blockIdx.y, t = threadIdx.x;
  float sc = pw[o] * BNINV * pbn[o], bt = pbn[16 + o];
  for (int i = t; i < 2401; i += 256)
    out[(b * 16 + o) * 2401 + i] = fmaxf(in[b * 2401 + i] * sc + bt, 0.f);
}

// ---------------- sep4d #1: 16-channel convs ----------------
__global__ __launch_bounds__(256) void k_sep1a(
    const float* __restrict__ in, const float* __restrict__ w,
    const float* __restrict__ bnp, float* __restrict__ out) {
  int kc = blockIdx.x, b = blockIdx.y, t = threadIdx.x;
  __shared__ float inL[16 * 343];
  __shared__ float wL[2304];
  for (int i = t; i < 2304; i += 256) wL[i] = w[i];
  for (int i = t; i < 5488; i += 256) {
    int ic = i / 343, r = i % 343;
    int ij = r / 7, s = r % 7;
    inL[ic * 343 + r] = in[(b * 16 + ic) * 2401 + ij * 49 + kc * 7 + s];
  }
  __syncthreads();
  for (int i = t; i < 5488; i += 256) {
    int o = i / 343, r = i % 343;
    int ij = r / 7, s = r % 7;
    int u = ij / 7, v = ij % 7;
    float a = 0.f;
    for (int ic = 0; ic < 16; ++ic)
#pragma unroll
      for (int du = 0; du < 3; ++du) {
        int uu = u + du - 1;
        if (uu < 0 || uu > 6) continue;
#pragma unroll
        for (int dv = 0; dv < 3; ++dv) {
          int vv = v + dv - 1;
          if (vv < 0 || vv > 6) continue;
          a += wL[((o * 16 + ic) * 3 + du) * 3 + dv] * inL[ic * 343 + (uu * 7 + vv) * 7 + s];
        }
      }
    float g = BNINV * bnp[o], bt = bnp[16 + o];
    out[(b * 16 + o) * 2401 + ij * 49 + kc * 7 + s] = fmaxf(a * g + bt, 0.f);
  }
}

__global__ __launch_bounds__(256) void k_sep1b(
    const float* __restrict__ in, const float* __restrict__ w,
    const float* __restrict__ bnp, float* __restrict__ out) {
  int ir = blockIdx.x, b = blockIdx.y, t = threadIdx.x;
  __shared__ float inL[16 * 343];
  __shared__ float wL[2304];
  for (int i = t; i < 2304; i += 256) wL[i] = w[i];
  for (int i = t; i < 5488; i += 256) {
    int ic = i / 343, r = i % 343;
    inL[ic * 343 + r] = in[(b * 16 + ic) * 2401 + ir * 343 + r];
  }
  __syncthreads();
  for (int i = t; i < 5488; i += 256) {
    int o = i / 343, r = i % 343;
    int jj = r / 49, kl = r % 49;
    int k = kl / 7, l = kl % 7;
    float a = 0.f;
    for (int ic = 0; ic < 16; ++ic)
#pragma unroll
      for (int dh = 0; dh < 3; ++dh) {
        int k2 = k + dh - 1;
        if (k2 < 0 || k2 > 6) continue;
#pragma unroll
        for (int dw = 0; dw < 3; ++dw) {
          int l2 = l + dw - 1;
          if (l2 < 0 || l2 > 6) continue;
          a += wL[((o * 16 + ic) * 3 + dh) * 3 + dw] * inL[ic * 343 + jj * 49 + k2 * 7 + l2];
        }
      }
    float g = BNINV * bnp[o], bt = bnp[16 + o];
    out[(b * 16 + o) * 2401 + ir * 343 + r] = a * g + bt;  // no relu
  }
}

__global__ void k_sep1p(const float* __restrict__ in, const float* __restrict__ pw,
                        const float* __restrict__ pbn, float* __restrict__ out) {
  int b = blockIdx.x, t = threadIdx.x;
  float g = BNINV * pbn[0], bt = pbn[1];
  __shared__ float pl[16];
  if (t < 16) pl[t] = pw[t];
  __syncthreads();
  for (int i = t; i < 2401; i += 256) {
    float a = 0.f;
#pragma unroll
    for (int ic = 0; ic < 16; ++ic) a += pl[ic] * in[(b * 16 + ic) * 2401 + i];
    out[b * 2401 + i] = a * g + bt;
  }
}

// ------- K10: gauss-normalize + softmax + attention sums -------
__global__ __launch_bounds__(64) void k_attn(const float* __restrict__ c4,
                                             float* __restrict__ attn_s,
                                             float* __restrict__ attn_q) {
  int b = blockIdx.x, t = threadIdx.x;
  __shared__ float c[2401];
  __shared__ float n[2401];
  for (int i = t; i < 2401; i += 64) c[i] = c4[b * 2401 + i];
  __syncthreads();
  if (t < 49) {
    float m = 0.f;
    for (int ij = 0; ij < 49; ++ij) m += c[ij * 49 + t];
    m *= (1.f / 49.f);
    float v = 0.f;
    for (int ij = 0; ij < 49; ++ij) { float d = c[ij * 49 + t] - m; v += d * d; }
    v *= (1.f / 48.f);
    float inv = 1.f / sqrtf(v + 1e-5f);
    float mx = -1e30f;
    for (int ij = 0; ij < 49; ++ij) mx = fmaxf(mx, (c[ij * 49 + t] - m) * inv);
    float s = 0.f;
    for (int ij = 0; ij < 49; ++ij) {
      float e = expf((c[ij * 49 + t] - m) * inv - mx);
      n[ij * 49 + t] = e; s += e;
    }
    float r = 1.f / s;
    for (int ij = 0; ij < 49; ++ij) n[ij * 49 + t] *= r;
  }
  __syncthreads();
  if (t < 49) {
    float s = 0.f;
    for (int kl = 0; kl < 49; ++kl) s += n[t * 49 + kl];
    attn_s[b * 49 + t] = s;
  }
  __syncthreads();
  if (t < 49) {
    float m = 0.f;
    for (int kl = 0; kl < 49; ++kl) m += c[t * 49 + kl];
    m *= (1.f / 49.f);
    float v = 0.f;
    for (int kl = 0; kl < 49; ++kl) { float d = c[t * 49 + kl] - m; v += d * d; }
    v *= (1.f / 48.f);
    float inv = 1.f / sqrtf(v + 1e-5f);
    float mx = -1e30f;
    for (int kl = 0; kl < 49; ++kl) mx = fmaxf(mx, (c[t * 49 + kl] - m) * inv);
    float s = 0.f;
    for (int kl = 0; kl < 49; ++kl) {
      float e = expf((c[t * 49 + kl] - m) * inv - mx);
      n[t * 49 + kl] = e; s += e;
    }
    float r = 1.f / s;
    for (int kl = 0; kl < 49; ++kl) n[t * 49 + kl] *= r;
  }
  __syncthreads();
  if (t < 49) {
    float s = 0.f;
    for (int ij = 0; ij < 49; ++ij) s += n[ij * 49 + t];
    attn_q[b * 49 + t] = s;
  }
}

// ------- K11: attention-weighted mean/max pooling -------
__global__ __launch_bounds__(256) void k_pool(const float* __restrict__ xpn,
                                              const float* __restrict__ attn,
                                              float* __restrict__ ep) {
  int b = blockIdx.x, br = blockIdx.y, t = threadIdx.x;
  const float* xb = xpn + br * 3010560 + b * 47040;  // (p,c)
  const float* a = attn + br * 3136 + b * 49;
  __shared__ float al[49];
  if (t < 49) al[t] = a[t];
  __syncthreads();
  float* eb = ep + br * 122880 + b * 1920;
  for (int c = t; c < 960; c += 256) {
    float s = 0.f, mx = -1e30f;
    for (int hw = 0; hw < 49; ++hw) {
      float v = al[hw] * xb[hw * 960 + c];
      s += v; mx = fmaxf(mx, v);
    }
    eb[c] = s * (1.f / 49.f);
    eb[960 + c] = mx;
  }
}

// ------- M=64 GEMM, split-K with atomicAdd -------
__global__ __launch_bounds__(256) void k_gemm64(
    const float* __restrict__ A0, const float* __restrict__ A1, int asplit,
    int reluA, const float* __restrict__ W, int K, int Kslice,
    float* __restrict__ C, int N) {
  int otile = blockIdx.x, ks = blockIdx.y;
  int t = threadIdx.x, bt = t >> 4, ot = t & 15;
  __shared__ __align__(16) float eT[48 * 68];
  __shared__ __align__(16) float wT[48 * 68];
  float acc[4][4];
#pragma unroll
  for (int i = 0; i < 4; ++i)
#pragma unroll
    for (int j = 0; j < 4; ++j) acc[i][j] = 0.f;
  int kbeg = ks * Kslice, kend = kbeg + Kslice;
  for (int k0 = kbeg; k0 < kend; k0 += 48) {
    __syncthreads();
    for (int i = t; i < 768; i += 256) {
      int b = i / 12, kg = i % 12;
      int k = k0 + kg * 4;
      float4 v;
      if (asplit) {
        v = (k < asplit) ? *(const float4*)&A0[b * 1920 + k]
                         : *(const float4*)&A1[b * 1920 + k - asplit];
      } else {
        v = *(const float4*)&A0[b * K + k];
      }
      if (reluA) {
        v.x = fmaxf(v.x, 0.f); v.y = fmaxf(v.y, 0.f);
        v.z = fmaxf(v.z, 0.f); v.w = fmaxf(v.w, 0.f);
      }
      eT[(kg * 4 + 0) * 68 + b] = v.x; eT[(kg * 4 + 1) * 68 + b] = v.y;
      eT[(kg * 4 + 2) * 68 + b] = v.z; eT[(kg * 4 + 3) * 68 + b] = v.w;
    }
    for (int i = t; i < 768; i += 256) {
      int o = i / 12, kg = i % 12;
      float4 v = *(const float4*)&W[(otile * 64 + o) * K + k0 + kg * 4];
      wT[(kg * 4 + 0) * 68 + o] = v.x; wT[(kg * 4 + 1) * 68 + o] = v.y;
      wT[(kg * 4 + 2) * 68 + o] = v.z; wT[(kg * 4 + 3) * 68 + o] = v.w;
    }
    __syncthreads();
#pragma unroll 4
    for (int kk = 0; kk < 48; ++kk) {
      float av[4], wv[4];
      *(float4*)av = *(const float4*)&eT[kk * 68 + bt * 4];
      *(float4*)wv = *(const float4*)&wT[kk * 68 + ot * 4];
#pragma unroll
      for (int i = 0; i < 4; ++i)
#pragma unroll
        for (int j = 0; j < 4; ++j) acc[i][j] += av[i] * wv[j];
    }
  }
#pragma unroll
  for (int i = 0; i < 4; ++i)
#pragma unroll
    for (int j = 0; j < 4; ++j)
      atomicAdd(&C[(bt * 4 + i) * N + otile * 64 + ot * 4 + j], acc[i][j]);
}

// ------- group pooling over 2.5D groups (+ deferred bias from mlp2) -------
__global__ void k_poolg(const float* __restrict__ em3m, const float* __restrict__ em3e,
                        const float* __restrict__ b2m, const float* __restrict__ b2e,
                        float* __restrict__ pm) {
  int g = blockIdx.x, which = blockIdx.y, t = threadIdx.x;
  const float* em = which ? em3e : em3m;
  const float* b2 = which ? b2e : b2m;
  for (int d = t; d < 960; d += 256) {
    float s = 0.f;
    for (int r = 0; r < 8; ++r) s += em[(g * 8 + r) * 960 + d];
    pm[which * 7680 + g * 960 + d] = s * 0.125f + b2[d];
  }
}

// ------- classifier layer 1: hardswish(pm @ W1^T + b1) -------
__global__ __launch_bounds__(256) void k_cls1(
    const float* __restrict__ pmbase, const float* __restrict__ w1mT,
    const float* __restrict__ b1m, const float* __restrict__ w1eT,
    const float* __restrict__ b1e, float* __restrict__ h2) {
  int which = blockIdx.y, t = threadIdx.x;
  const float* pmw = pmbase + which * 7680;
  const float* WT = which ? w1eT : w1mT;
  const float* b1 = which ? b1e : b1m;
  __shared__ float pl[7680];
  for (int i = t; i < 7680; i += 256) pl[i] = pmw[i];
  __syncthreads();
  int o = blockIdx.x * 256 + t;
  if (o >= 1920) return;
  float acc[8] = {0.f, 0.f, 0.f, 0.f, 0.f, 0.f, 0.f, 0.f};
#pragma unroll 4
  for (int k = 0; k < 960; ++k) {
    float w = WT[k * 1920 + o];
#pragma unroll
    for (int g = 0; g < 8; ++g) acc[g] += w * pl[g * 960 + k];
  }
  float bb = b1[o];
#pragma unroll
  for (int g = 0; g < 8; ++g) {
    float z = acc[g] + bb;
    h2[which * 15360 + g * 1920 + o] = z * fminf(fmaxf(z + 3.f, 0.f), 6.f) * (1.f / 6.f);
  }
}

// ------- classifier layer 2 + final concat -------
__global__ __launch_bounds__(256) void k_cls2(
    const float* __restrict__ h2, const float* __restrict__ w2m,
    const float* __restrict__ b2m, const float* __restrict__ w2e,
    const float* __restrict__ b2e, float* __restrict__ out) {
  int which = blockIdx.x, t = threadIdx.x;
  const float* h = h2 + which * 15360;
  const float* W = which ? w2e : w2m;
  const float* bb = which ? b2e : b2m;
  __shared__ float red[256];
  for (int gj = 0; gj < 16; ++gj) {
    int g = gj >> 1, j = gj & 1;
    float s = 0.f;
    for (int k = t; k < 1920; k += 256) s += h[g * 1920 + k] * W[j * 1920 + k];
    red[t] = s;
    __syncthreads();
    for (int off = 128; off >= 1; off >>= 1) {
      if (t < off) red[t] += red[t + off];
      __syncthreads();
    }
    if (t == 0) out[g * 4 + which * 2 + j] = red[0] + bb[j];
    __syncthreads();
  }
}

// =======================================================================
extern "C" void kernel_launch(void* const* d_in, const int* in_sizes, int n_in,
                              void* d_out, int out_size, void* d_ws, size_t ws_size,
                              hipStream_t stream) {
  const float* x_p = (const float*)d_in[0];
  const float* x_i = (const float*)d_in[1];
  const float* scr_w_in = (const float*)d_in[2];
  const float* scr_bn_in = (const float*)d_in[3];
  const float* scr_w1 = (const float*)d_in[4];
  const float* scr_bn1 = (const float*)d_in[5];
  const float* scr_w2 = (const float*)d_in[6];
  const float* scr_bn2 = (const float*)d_in[7];
  const float* scr_w_out = (const float*)d_in[8];
  const float* scr_bn_out = (const float*)d_in[9];
  const float* cca1x1_w = (const float*)d_in[10];
  const float* cca1x1_bn = (const float*)d_in[11];
  const float* cca0_c2_w = (const float*)d_in[12];
  const float* cca0_c2_bn = (const float*)d_in[13];
  const float* cca0_c1_w = (const float*)d_in[14];
  const float* cca0_c1_bn = (const float*)d_in[15];
  const float* cca0_p_w = (const float*)d_in[16];
  const float* cca0_p_bn = (const float*)d_in[17];
  const float* cca1_c2_w = (const float*)d_in[18];
  const float* cca1_c2_bn = (const float*)d_in[19];
  const float* cca1_c1_w = (const float*)d_in[20];
  const float* cca1_c1_bn = (const float*)d_in[21];
  const float* cca1_p_w = (const float*)d_in[22];
  const float* cca1_p_bn = (const float*)d_in[23];
  const float* meta_w1 = (const float*)d_in[24];
  const float* meta_w2 = (const float*)d_in[25];
  const float* meta_b2 = (const float*)d_in[26];
  const float* ene_w1 = (const float*)d_in[27];
  const float* ene_w2 = (const float*)d_in[28];
  const float* ene_b2 = (const float*)d_in[29];
  const float* mcls_w1 = (const float*)d_in[30];
  const float* mcls_b1 = (const float*)d_in[31];
  const float* mcls_w2 = (const float*)d_in[32];
  const float* mcls_b2 = (const float*)d_in[33];
  const float* ecls_w1 = (const float*)d_in[34];
  const float* ecls_b1 = (const float*)d_in[35];
  const float* ecls_w2 = (const float*)d_in[36];
  const float* ecls_b2 = (const float*)d_in[37];

  float* ws = (float*)d_ws;
  float* XN = ws + OFF_XN;
  float* Y1 = ws + OFF_Y1;
  float* Y2 = ws + OFF_Y2;
  float* T = ws + OFF_T;
  float* XPN = ws + OFF_XPN;
  float* SQ = ws + OFF_SQ;
  float* CORR = ws + OFF_CORR;
  float* S0Y1 = ws + OFF_S0Y1;
  float* S0Y2 = ws + OFF_S0Y2;
  float* S0P = ws + OFF_S0P;
  float* S1Y1 = ws + OFF_S1Y1;
  float* S1Y2 = ws + OFF_S1Y2;
  float* C4F = ws + OFF_C4F;
  float* ATT = ws + OFF_ATT;
  float* EPI = ws + OFF_EPI;
  float* H1 = ws + OFF_H1;
  float* EM3 = ws + OFF_EM3;
  float* PM = ws + OFF_PM;
  float* H2 = ws + OFF_H2;
  float* WOUTT = ws + OFF_WOUTT;
  float* CCAT = ws + OFF_CCAT;
  float* MCLST = ws + OFF_MCLST;
  float* ECLST = ws + OFF_ECLST;
  float* W1T = ws + OFF_W1T;
  float* W2T = ws + OFF_W2T;
  unsigned* WBF = (unsigned*)(ws + OFF_WBF);

  // weight preps (small, every call)
  k_transpose<<<(960 * 96 + 255) / 256, 256, 0, stream>>>(scr_w_out, WOUTT, 960, 96);
  k_transpose<<<(96 * 960 + 255) / 256, 256, 0, stream>>>(cca1x1_w, CCAT, 96, 960);
  k_transpose<<<(1920 * 960 + 255) / 256, 256, 0, stream>>>(mcls_w1, MCLST, 1920, 960);
  k_transpose<<<(1920 * 960 + 255) / 256, 256, 0, stream>>>(ecls_w1, ECLST, 1920, 960);
  k_prepw<<<dim3(432, 2), 256, 0, stream>>>(scr_w1, scr_w2, W1T, W2T);
  k_prepwbf<<<180, 256, 0, stream>>>(scr_w_in, WBF);

  for (int br = 0; br < 2; ++br) {
    const float* x = br ? x_i : x_p;
    k_l2n<<<64, 256, 0, stream>>>(x, XN);
    k_scr_in<<<dim3(7, 64), 256, 0, stream>>>(XN, WBF, scr_bn_in, Y1);
    k_conv1<<<392, 256, 0, stream>>>(Y1, W1T, scr_bn1, Y2);
    k_conv2<<<392, 128, 0, stream>>>(Y2, W2T, scr_bn2, T);
    k_scr_out<<<dim3(7, 64), 256, 0, stream>>>(T, WOUTT, scr_bn_out, x,
                                               XPN + br * 3010560);
    k_cca1<<<dim3(7, 64), 128, 0, stream>>>(XPN + br * 3010560, CCAT, cca1x1_bn,
                                            SQ + br * 301056);
  }
  k_corr<<<64, 256, 0, stream>>>(SQ, SQ + 301056, CORR);
  k_sep0<<<64, 256, 0, stream>>>(CORR, cca0_c2_w, cca0_c2_bn, S0Y1, 1, 1);
  k_sep0<<<64, 256, 0, stream>>>(S0Y1, cca0_c1_w, cca0_c1_bn, S0Y2, 0, 0);
  k_sep0p<<<dim3(64, 16), 256, 0, stream>>>(S0Y2, cca0_p_w, cca0_p_bn, S0P);
  k_sep1a<<<dim3(7, 64), 256, 0, stream>>>(S0P, cca1_c2_w, cca1_c2_bn, S1Y1);
  k_sep1b<<<dim3(7, 64), 256, 0, stream>>>(S1Y1, cca1_c1_w, cca1_c1_bn, S1Y2);
  k_sep1p<<<64, 256, 0, stream>>>(S1Y2, cca1_p_w, cca1_p_bn, C4F);
  k_attn<<<64, 64, 0, stream>>>(C4F, ATT, ATT + 3136);
  k_pool<<<dim3(64, 2), 256, 0, stream>>>(XPN, ATT, EPI);

  hipMemsetAsync(H1, 0, (245760u + 122880u) * sizeof(float), stream);
  k_gemm64<<<dim3(30, 8), 256, 0, stream>>>(EPI, EPI + 122880, 960, 0, meta_w1,
                                            1920, 240, H1, 1920);
  k_gemm64<<<dim3(30, 8), 256, 0, stream>>>(EPI + 960, EPI + 122880 + 960, 960, 0,
                                            ene_w1, 1920, 240, H1 + 122880, 1920);
  k_gemm64<<<dim3(15, 8), 256, 0, stream>>>(H1, nullptr, 0, 1, meta_w2, 1920, 240,
                                            EM3, 960);
  k_gemm64<<<dim3(15, 8), 256, 0, stream>>>(H1 + 122880, nullptr, 0, 1, ene_w2,
                                            1920, 240, EM3 + 61440, 960);
  k_poolg<<<dim3(8, 2), 256, 0, stream>>>(EM3, EM3 + 61440, meta_b2, ene_b2, PM);
  k_cls1<<<dim3(8, 2), 256, 0, stream>>>(PM, MCLST, mcls_b1, ECLST, ecls_b1, H2);
  k_cls2<<<2, 256, 0, stream>>>(H2, mcls_w2, mcls_b2, ecls_w2, ecls_b2,
                                (float*)d_out);
}

// Round 4
// 1533.101 us; speedup vs baseline: 2.5989x; 1.2734x over previous
//
#include <hip/hip_runtime.h>
#include <hip/hip_bf16.h>

// RtNet25DDualRENet forward. Round 4:
//  - k_scr_in v3: 512-thr blocks, 32-k chunks (occupancy 22%->44%)
//  - sep1a/b row-vectorized (4x fewer LDS insts)
//  - tiled transposes, parallel cls1, shuffle cls2
//  - fused k_mid (corr+sep0a+sep0b+sep0p), k_c4attn (sep1p+attn)

#define BNINV 0.9999950000374997f  // 1/sqrt(1+1e-5)

typedef __attribute__((ext_vector_type(8))) short bf16x8;
typedef __attribute__((ext_vector_type(4))) float f32x4;

__device__ inline unsigned short f2bf(float f) {
  union { float f; unsigned u; } x; x.f = f;
  unsigned r = x.u + 0x7fffu + ((x.u >> 16) & 1u);  // RNE
  return (unsigned short)(r >> 16);
}

// ---------------- workspace layout (float offsets) ----------------
#define OFF_XN      0u            // (b,960,49)
#define OFF_Y1      3010560u      // (b,96,49,25)
#define OFF_Y2      10536960u     // (b,49,96,9)
#define OFF_T       13246464u     // (b,49,96)
#define OFF_XPN     13547520u     // 2 x (b,49,960)
#define OFF_SQ      19568640u     // 2 x (b,49,96)
#define OFF_S0P     20631744u     // (b,16,49,49) -- reused early for W1T/W2T/WBF
#define OFF_S1Y1    23090368u
#define OFF_S1Y2    25548992u
#define OFF_ATT     28161280u     // attn_s[64*49], attn_q[64*49]
#define OFF_EPI     28167552u     // ep[64*1920], ei[64*1920]
#define OFF_H1      28413312u     // 2 x (64,1920)
#define OFF_EM3     28659072u     // 2 x (64,960)
#define OFF_PM      28781952u     // 2 x (8,960)
#define OFF_H2      28797312u     // 2 x (8,1920)
#define OFF_WOUTT   28828032u     // w_out^T [96][960]
#define OFF_CCAT    28920192u     // cca1x1_w^T [960][96]
#define OFF_MCLST   29012352u     // mcls_w1^T [960][1920]
#define OFF_ECLST   30855552u     // ecls_w1^T [960][1920]
#define OFF_W1T     OFF_S0P
#define OFF_W2T     (OFF_S0P + 110592u)
#define OFF_WBF     (OFF_S0P + 221184u)   // 46080 uints (96x960 bf16 pairs)

// ---------------- tiled transpose: in[R][C] -> out[C][R], R,C %32==0 ----------------
__global__ __launch_bounds__(256) void k_transpose_t(const float* __restrict__ in,
                                                     float* __restrict__ out,
                                                     int R, int C) {
  __shared__ float tl[32][33];
  int c0 = blockIdx.x * 32, r0 = blockIdx.y * 32;
  int tx = threadIdx.x & 31, ty = threadIdx.x >> 5;
#pragma unroll
  for (int i = 0; i < 4; ++i)
    tl[ty + i * 8][tx] = in[(r0 + ty + i * 8) * C + c0 + tx];
  __syncthreads();
#pragma unroll
  for (int i = 0; i < 4; ++i)
    out[(c0 + ty + i * 8) * R + r0 + tx] = tl[tx][ty + i * 8];
}

// ---- prep: w[o][ic][9] -> WT[ic][o][12] (taps padded with 0) ----
__global__ void k_prepw(const float* __restrict__ w1, const float* __restrict__ w2,
                        float* __restrict__ W1T, float* __restrict__ W2T) {
  int i = blockIdx.x * 256 + threadIdx.x;
  if (i >= 110592) return;
  int tap = i % 12, rest = i / 12, o = rest % 96, ic = rest / 96;
  const float* w = blockIdx.y ? w2 : w1;
  float v = (tap < 9) ? w[(o * 96 + ic) * 9 + tap] : 0.f;
  (blockIdx.y ? W2T : W1T)[i] = v;
}

// ---- prep: scr_w_in (96x960 fp32) -> packed bf16 pairs ----
__global__ void k_prepwbf(const float* __restrict__ w_in, unsigned* __restrict__ WbfU) {
  int i = blockIdx.x * 256 + threadIdx.x;
  if (i >= 46080) return;
  float a = w_in[2 * i], b = w_in[2 * i + 1];
  WbfU[i] = (unsigned)f2bf(a) | ((unsigned)f2bf(b) << 16);
}

// ---------------- K1: relu + l2-normalize over C per (b,p) ----------------
__global__ __launch_bounds__(256) void k_l2n(const float* __restrict__ x,
                                             float* __restrict__ xn) {
  int b = blockIdx.x, t = threadIdx.x;
  __shared__ float red[256];
  __shared__ float inv[49];
  const float* xb = x + b * 47040;
  float* ob = xn + b * 47040;
  int p = t & 63, sl = t >> 6;
  float s = 0.f;
  if (p < 49) {
    for (int c = sl * 240; c < sl * 240 + 240; ++c) {
      float v = xb[c * 49 + p];
      if (v > 0.f) s += v * v;
    }
  }
  red[t] = s;
  __syncthreads();
  if (t < 49) {
    float q = red[t] + red[t + 64] + red[t + 128] + red[t + 192];
    inv[t] = 1.f / fmaxf(sqrtf(q), 1e-12f);
  }
  __syncthreads();
  for (int i = t; i < 47040; i += 256) {
    float v = xb[i];
    ob[i] = v > 0.f ? v * inv[i % 49] : 0.f;
  }
}

// ------- K2: fused self-corr x scr_w_in einsum + BN + relu (bf16 MFMA, v3) -------
// 512 threads = 8 waves: wave = (mh:2) x (ng:4); mh covers 3 m-tiles, ng covers 3 n-tiles.
// K chunked by 32 (one MFMA k-step per chunk).
__global__ __launch_bounds__(512) void k_scr_in(
    const float* __restrict__ xn, const unsigned* __restrict__ WbfU,
    const float* __restrict__ bn, float* __restrict__ y1) {
  const int h = blockIdx.x, b = blockIdx.y, t = threadIdx.x;
  const int wave = t >> 6, lane = t & 63, quad = lane >> 4, lr = lane & 15;
  const int mh = wave >> 2, ng = wave & 3;
  __shared__ __align__(16) short Pl[192 * 40];   // [col][k] bf16, stride 40
  __shared__ __align__(16) short Wl[96 * 40];    // [o][k] bf16, stride 40
  __shared__ __align__(16) float xc[60 * 36];    // [j][k] f32, stride 36
  unsigned* Plu = (unsigned*)Pl;
  unsigned* Wlu = (unsigned*)Wl;
  f32x4 acc[3][3];
#pragma unroll
  for (int m = 0; m < 3; ++m)
#pragma unroll
    for (int n = 0; n < 3; ++n) acc[m][n] = (f32x4){0.f, 0.f, 0.f, 0.f};
  const float* xb = xn + b * 47040;
  // P-build role: threads 0..383: col = t>>1, k-half = t&1
  const int colB = t >> 1, halfB = t & 1;
  int i1 = 0, i2 = 0;
  if (t < 384) {
    int cc = colB < 175 ? colB : 174;
    int wp = cc / 25, uv = cc - wp * 25, du = uv / 5, dv = uv - du * 5;
    i1 = (26 + wp) * 36;
    i2 = (du * 12 + wp + dv) * 36;
  }
  for (int k0 = 0; k0 < 960; k0 += 32) {
    __syncthreads();
    // stage xc transposed [j][k]
    for (int i = t; i < 1920; i += 512) {
      int kk = i / 60, j = i - kk * 60;
      int r = j / 12, wc = j - r * 12;
      int row = h + r - 2, w = wc - 2;
      float v = 0.f;
      if ((unsigned)row < 7u && (unsigned)w < 7u)
        v = xb[(k0 + kk) * 49 + row * 7 + w];
      xc[j * 36 + kk] = v;
    }
    // stage W bf16: 96 o x 16 uints
    {
      int base = k0 >> 1;
      for (int i = t; i < 1536; i += 512) {
        int o = i >> 4, kp = i & 15;
        Wlu[o * 20 + kp] = WbfU[o * 480 + base + kp];
      }
    }
    __syncthreads();
    // build P: each active thread builds 16 k-values of one col
    if (t < 384) {
      const float* r1 = &xc[i1 + halfB * 16];
      const float* r2 = &xc[i2 + halfB * 16];
      float a[16], c[16];
#pragma unroll
      for (int q = 0; q < 4; ++q) {
        *(float4*)&a[q * 4] = *(const float4*)&r1[q * 4];
        *(float4*)&c[q * 4] = *(const float4*)&r2[q * 4];
      }
      unsigned* dst = Plu + colB * 20 + halfB * 8;
#pragma unroll
      for (int q = 0; q < 8; ++q) {
        float v0 = a[q * 2] * c[q * 2];
        float v1 = a[q * 2 + 1] * c[q * 2 + 1];
        dst[q] = (unsigned)f2bf(v0) | ((unsigned)f2bf(v1) << 16);
      }
    }
    __syncthreads();
    // MFMA: one 32-k step, 3x3 tiles per wave
    const int ko = quad * 8;
    bf16x8 af[3], bfr[3];
#pragma unroll
    for (int m = 0; m < 3; ++m)
      af[m] = *(const bf16x8*)&Wl[((mh * 3 + m) * 16 + lr) * 40 + ko];
#pragma unroll
    for (int n = 0; n < 3; ++n)
      bfr[n] = *(const bf16x8*)&Pl[((ng * 3 + n) * 16 + lr) * 40 + ko];
#pragma unroll
    for (int m = 0; m < 3; ++m)
#pragma unroll
      for (int n = 0; n < 3; ++n)
        acc[m][n] = __builtin_amdgcn_mfma_f32_16x16x32_bf16(
            af[m], bfr[n], acc[m][n], 0, 0, 0);
  }
  // epilogue: C/D layout col=lane&15, row=quad*4+reg
#pragma unroll
  for (int n = 0; n < 3; ++n) {
    int col = (ng * 3 + n) * 16 + lr;
    if (col >= 175) continue;
    int wp = col / 25, uv = col - wp * 25;
    long pb = ((long)(b * 96) * 49 + h * 7 + wp) * 25 + uv;
#pragma unroll
    for (int m = 0; m < 3; ++m) {
#pragma unroll
      for (int r = 0; r < 4; ++r) {
        int o = (mh * 3 + m) * 16 + quad * 4 + r;
        float g = BNINV * bn[o], bt = bn[96 + o];
        y1[pb + (long)o * 49 * 25] = fmaxf(acc[m][n][r] * g + bt, 0.f);
      }
    }
  }
}

// ---------------- K3: SCR conv1 (1,3,3) 5x5->3x3, BN, relu ----------------
__global__ __launch_bounds__(256) void k_conv1(
    const float* __restrict__ y1, const float* __restrict__ W1T,
    const float* __restrict__ bn1, float* __restrict__ y2g) {
  const int t = threadIdx.x;
  const int tx = t & 7;
  const int ty = t >> 3;
  const int pairBase = blockIdx.x * 8;
  __shared__ __align__(16) float Wc[9216];
  __shared__ __align__(16) float Raw[8 * 228];
  float acc[3][9];
#pragma unroll
  for (int m = 0; m < 3; ++m)
#pragma unroll
    for (int d = 0; d < 9; ++d) acc[m][d] = 0.f;
  const int pair = pairBase + tx;
  for (int ch = 0; ch < 12; ++ch) {
    __syncthreads();
    {
      const float4* src = (const float4*)(W1T + ch * 9216);
      float4* dst = (float4*)Wc;
      for (int i = t; i < 2304; i += 256) dst[i] = src[i];
    }
    for (int i = t; i < 1600; i += 256) {
      int pr = i / 200, r = i - pr * 200, ic = r / 25, uv = r - ic * 25;
      int pp = pairBase + pr, bb = pp / 49, pq = pp - bb * 49;
      Raw[pr * 228 + ic * 28 + uv] =
          y1[((bb * 96 + ch * 8 + ic) * 49 + pq) * 25 + uv];
    }
    __syncthreads();
#pragma unroll
    for (int ic = 0; ic < 8; ++ic) {
      float r[25];
      const float* rb = &Raw[tx * 228 + ic * 28];
      *(float4*)&r[0]  = *(const float4*)&rb[0];
      *(float4*)&r[4]  = *(const float4*)&rb[4];
      *(float4*)&r[8]  = *(const float4*)&rb[8];
      *(float4*)&r[12] = *(const float4*)&rb[12];
      *(float4*)&r[16] = *(const float4*)&rb[16];
      *(float4*)&r[20] = *(const float4*)&rb[20];
      r[24] = rb[24];
#pragma unroll
      for (int m = 0; m < 3; ++m) {
        float w[12];
        const float* wb = &Wc[(ic * 96 + ty * 3 + m) * 12];
        *(float4*)&w[0] = *(const float4*)&wb[0];
        *(float4*)&w[4] = *(const float4*)&wb[4];
        *(float4*)&w[8] = *(const float4*)&wb[8];
#pragma unroll
        for (int i2 = 0; i2 < 3; ++i2)
#pragma unroll
          for (int j2 = 0; j2 < 3; ++j2) {
            float s = acc[m][i2 * 3 + j2];
#pragma unroll
            for (int di = 0; di < 3; ++di)
#pragma unroll
              for (int dj = 0; dj < 3; ++dj)
                s += w[di * 3 + dj] * r[(i2 + di) * 5 + (j2 + dj)];
            acc[m][i2 * 3 + j2] = s;
          }
      }
    }
  }
#pragma unroll
  for (int m = 0; m < 3; ++m) {
    int o = ty * 3 + m;
    float g = BNINV * bn1[o], bt = bn1[96 + o];
#pragma unroll
    for (int d = 0; d < 9; ++d)
      y2g[(pair * 96 + o) * 9 + d] = fmaxf(acc[m][d] * g + bt, 0.f);
  }
}

// ---------------- K4: SCR conv2 (1,3,3) 3x3->1, BN, relu ----------------
__global__ __launch_bounds__(128) void k_conv2(
    const float* __restrict__ y2g, const float* __restrict__ W2T,
    const float* __restrict__ bn2, float* __restrict__ tout) {
  const int t = threadIdx.x;
  const int tx = t & 7;
  const int ty = t >> 3;
  const int pairBase = blockIdx.x * 8;
  __shared__ __align__(16) float Wc[9216];
  __shared__ __align__(16) float Yl[8 * 100];
  float acc[6] = {0.f, 0.f, 0.f, 0.f, 0.f, 0.f};
  const int pair = pairBase + tx;
  for (int ch = 0; ch < 12; ++ch) {
    __syncthreads();
    {
      const float4* src = (const float4*)(W2T + ch * 9216);
      float4* dst = (float4*)Wc;
      for (int i = t; i < 2304; i += 128) dst[i] = src[i];
    }
    for (int i = t; i < 576; i += 128) {
      int pr = i / 72, k = i - pr * 72, ic = k / 9, tap = k - ic * 9;
      Yl[pr * 100 + ic * 12 + tap] = y2g[(pairBase + pr) * 864 + ch * 72 + k];
    }
    __syncthreads();
#pragma unroll
    for (int ic = 0; ic < 8; ++ic) {
      float y[9];
      const float* yb = &Yl[tx * 100 + ic * 12];
      *(float4*)&y[0] = *(const float4*)&yb[0];
      *(float4*)&y[4] = *(const float4*)&yb[4];
      y[8] = yb[8];
#pragma unroll
      for (int j = 0; j < 6; ++j) {
        float w[12];
        const float* wb = &Wc[(ic * 96 + ty * 6 + j) * 12];
        *(float4*)&w[0] = *(const float4*)&wb[0];
        *(float4*)&w[4] = *(const float4*)&wb[4];
        *(float4*)&w[8] = *(const float4*)&wb[8];
        float s = acc[j];
#pragma unroll
        for (int d = 0; d < 9; ++d) s += w[d] * y[d];
        acc[j] = s;
      }
    }
  }
#pragma unroll
  for (int j = 0; j < 6; ++j) {
    int o = ty * 6 + j;
    tout[pair * 96 + o] =
        fmaxf(acc[j] * (BNINV * bn2[o]) + bn2[96 + o], 0.f);
  }
}

// ------- K5: w_out GEMM + BN + residual relu + channel-mean subtract -------
__global__ __launch_bounds__(256) void k_scr_out(
    const float* __restrict__ tin, const float* __restrict__ wouT,
    const float* __restrict__ bno, const float* __restrict__ x,
    float* __restrict__ xpn) {
  int pr = blockIdx.x, b = blockIdx.y, t = threadIdx.x;
  __shared__ __align__(16) float tl2[96 * 8];
  __shared__ float xr[7 * 960];
  __shared__ float xl[7 * 960];
  __shared__ float red[7 * 32];
  __shared__ float mean[7];
  for (int i = t; i < 672; i += 256) {
    int pl = i / 96, ic = i % 96;
    tl2[ic * 8 + pl] = tin[(b * 49 + pr * 7 + pl) * 96 + ic];
  }
  for (int i = t; i < 672; i += 256) tl2[(i % 96) * 8 + 7] = 0.f;
  for (int i = t; i < 6720; i += 256) {
    int o = i / 7, pl = i % 7;
    xl[pl * 960 + o] = x[(b * 960 + o) * 49 + pr * 7 + pl];
  }
  __syncthreads();
  for (int o = t; o < 960; o += 256) {
    float acc[7] = {0.f, 0.f, 0.f, 0.f, 0.f, 0.f, 0.f};
#pragma unroll 4
    for (int ic = 0; ic < 96; ++ic) {
      float w = wouT[ic * 960 + o];
      float tv[8];
      *(float4*)&tv[0] = *(const float4*)&tl2[ic * 8];
      *(float4*)&tv[4] = *(const float4*)&tl2[ic * 8 + 4];
#pragma unroll
      for (int pl = 0; pl < 7; ++pl) acc[pl] += w * tv[pl];
    }
    float g = BNINV * bno[o], bt = bno[960 + o];
#pragma unroll
    for (int pl = 0; pl < 7; ++pl)
      xr[pl * 960 + o] = fmaxf(xl[pl * 960 + o] + acc[pl] * g + bt, 0.f);
  }
  __syncthreads();
  if (t < 224) {
    int pl = t >> 5, ln = t & 31;
    float s = 0.f;
    for (int o = ln; o < 960; o += 32) s += xr[pl * 960 + o];
    red[pl * 32 + ln] = s;
  }
  __syncthreads();
  if (t < 7) {
    float s = 0.f;
    for (int i = 0; i < 32; ++i) s += red[t * 32 + i];
    mean[t] = s * (1.f / 960.f);
  }
  __syncthreads();
  for (int i = t; i < 6720; i += 256) {
    int pl = i / 960, o = i % 960;
    xpn[(b * 49 + pr * 7 + pl) * 960 + o] = xr[pl * 960 + o] - mean[pl];
  }
}

// ------- K6: cca1 1x1 + BN + relu + l2-normalize(96, eps 1e-8) -------
__global__ __launch_bounds__(128) void k_cca1(
    const float* __restrict__ xpn, const float* __restrict__ ccaT,
    const float* __restrict__ bnc, float* __restrict__ sq) {
  int pr = blockIdx.x, b = blockIdx.y, t = threadIdx.x;
  __shared__ __align__(16) float xl2[960 * 8];
  __shared__ float sv[7 * 96];
  __shared__ float red[7 * 16];
  __shared__ float inv[7];
  for (int i = t; i < 6720; i += 128) {
    int pl = i / 960, c = i % 960;
    xl2[c * 8 + pl] = xpn[(b * 49 + pr * 7 + pl) * 960 + c];
  }
  for (int c = t; c < 960; c += 128) xl2[c * 8 + 7] = 0.f;
  __syncthreads();
  if (t < 96) {
    float acc[7] = {0.f, 0.f, 0.f, 0.f, 0.f, 0.f, 0.f};
#pragma unroll 4
    for (int c = 0; c < 960; ++c) {
      float w = ccaT[c * 96 + t];
      float tv[8];
      *(float4*)&tv[0] = *(const float4*)&xl2[c * 8];
      *(float4*)&tv[4] = *(const float4*)&xl2[c * 8 + 4];
#pragma unroll
      for (int pl = 0; pl < 7; ++pl) acc[pl] += w * tv[pl];
    }
    float g = BNINV * bnc[t], bt = bnc[96 + t];
#pragma unroll
    for (int pl = 0; pl < 7; ++pl)
      sv[pl * 96 + t] = fmaxf(acc[pl] * g + bt, 0.f);
  }
  __syncthreads();
  if (t < 112) {
    int pl = t >> 4, ln = t & 15;
    float s = 0.f;
    for (int o = ln; o < 96; o += 16) { float v = sv[pl * 96 + o]; s += v * v; }
    red[pl * 16 + ln] = s;
  }
  __syncthreads();
  if (t < 7) {
    float s = 0.f;
    for (int i = 0; i < 16; ++i) s += red[t * 16 + i];
    inv[t] = 1.f / fmaxf(sqrtf(s), 1e-8f);
  }
  __syncthreads();
  for (int i = t; i < 672; i += 128) {
    int pl = i / 96, o = i % 96;
    sq[(b * 49 + pr * 7 + pl) * 96 + o] = sv[pl * 96 + o] * inv[pl];
  }
}

// ------- K7: fused corr + sep4d#0 (conv uv, conv kl, 1->16 proj) -------
__global__ __launch_bounds__(256) void k_mid(
    const float* __restrict__ sq0, const float* __restrict__ sq1,
    const float* __restrict__ wuv, const float* __restrict__ bnuv,
    const float* __restrict__ wkl, const float* __restrict__ bnkl,
    const float* __restrict__ pw16, const float* __restrict__ pbn16,
    float* __restrict__ s0p) {
  int b = blockIdx.x, t = threadIdx.x;
  __shared__ float smem[12304];
  float* sL = smem;            // [49][100]
  float* qL = smem + 4900;     // [49][100]
  float* A = smem + 9800;      // corr [2401]
  for (int i = t; i < 4704; i += 256) {
    int p = i / 96, c = i % 96;
    sL[p * 100 + c] = sq0[b * 4704 + i];
    qL[p * 100 + c] = sq1[b * 4704 + i];
  }
  __syncthreads();
  for (int i = t; i < 2401; i += 256) {
    int ij = i / 49, kl = i % 49;
    float a = 0.f;
#pragma unroll 4
    for (int c = 0; c < 96; ++c) a += sL[ij * 100 + c] * qL[kl * 100 + c];
    A[i] = a;
  }
  __syncthreads();
  float* B = smem;             // reuse sL region
  {
    float w0[9];
#pragma unroll
    for (int d = 0; d < 9; ++d) w0[d] = wuv[d];
    float g = BNINV * bnuv[0], bt = bnuv[1];
    for (int i = t; i < 2401; i += 256) {
      int ij = i / 49, kl = i % 49;
      int u = ij / 7, v = ij % 7;
      float a = 0.f;
#pragma unroll
      for (int du = 0; du < 3; ++du) {
        int uu = u + du - 1;
        if ((unsigned)uu >= 7u) continue;
#pragma unroll
        for (int dv = 0; dv < 3; ++dv) {
          int vv = v + dv - 1;
          if ((unsigned)vv >= 7u) continue;
          a += w0[du * 3 + dv] * A[(uu * 7 + vv) * 49 + kl];
        }
      }
      B[i] = fmaxf(a * g + bt, 0.f);
    }
  }
  __syncthreads();
  float* Cc = smem + 4900;     // reuse qL region
  {
    float w1[9];
#pragma unroll
    for (int d = 0; d < 9; ++d) w1[d] = wkl[d];
    float g = BNINV * bnkl[0], bt = bnkl[1];
    for (int i = t; i < 2401; i += 256) {
      int ij = i / 49, kl = i % 49;
      int kk = kl / 7, ll = kl % 7;
      float a = 0.f;
#pragma unroll
      for (int dh = 0; dh < 3; ++dh) {
        int k2 = kk + dh - 1;
        if ((unsigned)k2 >= 7u) continue;
#pragma unroll
        for (int dw = 0; dw < 3; ++dw) {
          int l2 = ll + dw - 1;
          if ((unsigned)l2 >= 7u) continue;
          a += w1[dh * 3 + dw] * B[ij * 49 + k2 * 7 + l2];
        }
      }
      Cc[i] = a * g + bt;
    }
  }
  __syncthreads();
  for (int o = 0; o < 16; ++o) {
    float sc = pw16[o] * BNINV * pbn16[o], bt2 = pbn16[16 + o];
    for (int i = t; i < 2401; i += 256)
      s0p[(b * 16 + o) * 2401 + i] = fmaxf(Cc[i] * sc + bt2, 0.f);
  }
}

// ---------------- sep4d #1 conv a (over u,v), row-vectorized ----------------
__global__ __launch_bounds__(256) void k_sep1a(
    const float* __restrict__ in, const float* __restrict__ w,
    const float* __restrict__ bnp, float* __restrict__ out) {
  int kc = blockIdx.x, b = blockIdx.y, t = threadIdx.x;
  __shared__ float inS[16 * 350];              // [ic][s][ij], stride s=50
  __shared__ __align__(16) float wP[3072];     // [(o*16+ic)][12]
  for (int i = t; i < 3072; i += 256) {
    int oc = i / 12, d = i % 12;
    wP[i] = (d < 9) ? w[oc * 9 + d] : 0.f;
  }
  for (int i = t; i < 5488; i += 256) {
    int ic = i / 343, r = i - ic * 343;
    int ij = r / 7, s = r - ij * 7;
    inS[ic * 350 + s * 50 + ij] = in[(b * 16 + ic) * 2401 + ij * 49 + kc * 7 + s];
  }
  __syncthreads();
  for (int rho = t; rho < 784; rho += 256) {
    int o = rho / 49, rem = rho - o * 49, u = rem / 7, s = rem - u * 7;
    float acc[7] = {0.f, 0.f, 0.f, 0.f, 0.f, 0.f, 0.f};
    for (int ic = 0; ic < 16; ++ic) {
      float wv[12];
      const float* wb = &wP[(o * 16 + ic) * 12];
      *(float4*)&wv[0] = *(const float4*)&wb[0];
      *(float4*)&wv[4] = *(const float4*)&wb[4];
      *(float4*)&wv[8] = *(const float4*)&wb[8];
      const float* rowb = &inS[ic * 350 + s * 50];
#pragma unroll
      for (int du = 0; du < 3; ++du) {
        int uu = u + du - 1;
        if ((unsigned)uu >= 7u) continue;
        const float* rr = rowb + uu * 7;
        float r7[7];
#pragma unroll
        for (int q = 0; q < 7; ++q) r7[q] = rr[q];
#pragma unroll
        for (int v = 0; v < 7; ++v) {
          float a = acc[v];
          if (v > 0) a += wv[du * 3 + 0] * r7[v - 1];
          a += wv[du * 3 + 1] * r7[v];
          if (v < 6) a += wv[du * 3 + 2] * r7[v + 1];
          acc[v] = a;
        }
      }
    }
    float g = BNINV * bnp[o], bt = bnp[16 + o];
    long ob = (long)(b * 16 + o) * 2401 + kc * 7 + s;
#pragma unroll
    for (int v = 0; v < 7; ++v)
      out[ob + (u * 7 + v) * 49] = fmaxf(acc[v] * g + bt, 0.f);
  }
}

// ---------------- sep4d #1 conv b (over h,w), row-vectorized ----------------
__global__ __launch_bounds__(256) void k_sep1b(
    const float* __restrict__ in, const float* __restrict__ w,
    const float* __restrict__ bnp, float* __restrict__ out) {
  int ir = blockIdx.x, b = blockIdx.y, t = threadIdx.x;
  __shared__ float inS[16 * 345];              // [ic][jj][k][l], stride ic=345
  __shared__ __align__(16) float wP[3072];
  for (int i = t; i < 3072; i += 256) {
    int oc = i / 12, d = i % 12;
    wP[i] = (d < 9) ? w[oc * 9 + d] : 0.f;
  }
  for (int i = t; i < 5488; i += 256) {
    int ic = i / 343, r = i - ic * 343;
    inS[ic * 345 + r] = in[(b * 16 + ic) * 2401 + ir * 343 + r];
  }
  __syncthreads();
  for (int rho = t; rho < 784; rho += 256) {
    int o = rho / 49, rem = rho - o * 49, jj = rem / 7, k = rem - jj * 7;
    float acc[7] = {0.f, 0.f, 0.f, 0.f, 0.f, 0.f, 0.f};
    for (int ic = 0; ic < 16; ++ic) {
      float wv[12];
      const float* wb = &wP[(o * 16 + ic) * 12];
      *(float4*)&wv[0] = *(const float4*)&wb[0];
      *(float4*)&wv[4] = *(const float4*)&wb[4];
      *(float4*)&wv[8] = *(const float4*)&wb[8];
      const float* rowb = &inS[ic * 345 + jj * 49];
#pragma unroll
      for (int dh = 0; dh < 3; ++dh) {
        int k2 = k + dh - 1;
        if ((unsigned)k2 >= 7u) continue;
        const float* rr = rowb + k2 * 7;
        float r7[7];
#pragma unroll
        for (int q = 0; q < 7; ++q) r7[q] = rr[q];
#pragma unroll
        for (int l = 0; l < 7; ++l) {
          float a = acc[l];
          if (l > 0) a += wv[dh * 3 + 0] * r7[l - 1];
          a += wv[dh * 3 + 1] * r7[l];
          if (l < 6) a += wv[dh * 3 + 2] * r7[l + 1];
          acc[l] = a;
        }
      }
    }
    float g = BNINV * bnp[o], bt = bnp[16 + o];
    long ob = (long)(b * 16 + o) * 2401 + ir * 343 + jj * 49 + k * 7;
#pragma unroll
    for (int l = 0; l < 7; ++l)
      out[ob + l] = acc[l] * g + bt;  // no relu
  }
}

// ------- K10: fused sep1p (16->1 proj) + gauss-softmax attention -------
__global__ __launch_bounds__(256) void k_c4attn(
    const float* __restrict__ in, const float* __restrict__ pw,
    const float* __restrict__ pbn, float* __restrict__ attn_s,
    float* __restrict__ attn_q) {
  int b = blockIdx.x, t = threadIdx.x;
  __shared__ float c[2401];
  __shared__ float n[2401];
  __shared__ float plw[16];
  if (t < 16) plw[t] = pw[t];
  __syncthreads();
  float g0 = BNINV * pbn[0], bt0 = pbn[1];
  for (int i = t; i < 2401; i += 256) {
    float a = 0.f;
#pragma unroll
    for (int ic = 0; ic < 16; ++ic) a += plw[ic] * in[(b * 16 + ic) * 2401 + i];
    c[i] = a * g0 + bt0;
  }
  __syncthreads();
  if (t < 49) {
    float m = 0.f;
    for (int ij = 0; ij < 49; ++ij) m += c[ij * 49 + t];
    m *= (1.f / 49.f);
    float v = 0.f;
    for (int ij = 0; ij < 49; ++ij) { float d = c[ij * 49 + t] - m; v += d * d; }
    v *= (1.f / 48.f);
    float inv = 1.f / sqrtf(v + 1e-5f);
    float mx = -1e30f;
    for (int ij = 0; ij < 49; ++ij) mx = fmaxf(mx, (c[ij * 49 + t] - m) * inv);
    float s = 0.f;
    for (int ij = 0; ij < 49; ++ij) {
      float e = expf((c[ij * 49 + t] - m) * inv - mx);
      n[ij * 49 + t] = e; s += e;
    }
    float r = 1.f / s;
    for (int ij = 0; ij < 49; ++ij) n[ij * 49 + t] *= r;
  }
  __syncthreads();
  if (t < 49) {
    float s = 0.f;
    for (int kl = 0; kl < 49; ++kl) s += n[t * 49 + kl];
    attn_s[b * 49 + t] = s;
  }
  __syncthreads();
  if (t < 49) {
    float m = 0.f;
    for (int kl = 0; kl < 49; ++kl) m += c[t * 49 + kl];
    m *= (1.f / 49.f);
    float v = 0.f;
    for (int kl = 0; kl < 49; ++kl) { float d = c[t * 49 + kl] - m; v += d * d; }
    v *= (1.f / 48.f);
    float inv = 1.f / sqrtf(v + 1e-5f);
    float mx = -1e30f;
    for (int kl = 0; kl < 49; ++kl) mx = fmaxf(mx, (c[t * 49 + kl] - m) * inv);
    float s = 0.f;
    for (int kl = 0; kl < 49; ++kl) {
      float e = expf((c[t * 49 + kl] - m) * inv - mx);
      n[t * 49 + kl] = e; s += e;
    }
    float r = 1.f / s;
    for (int kl = 0; kl < 49; ++kl) n[t * 49 + kl] *= r;
  }
  __syncthreads();
  if (t < 49) {
    float s = 0.f;
    for (int ij = 0; ij < 49; ++ij) s += n[ij * 49 + t];
    attn_q[b * 49 + t] = s;
  }
}

// ------- K11: attention-weighted mean/max pooling -------
__global__ __launch_bounds__(256) void k_pool(const float* __restrict__ xpn,
                                              const float* __restrict__ attn,
                                              float* __restrict__ ep) {
  int b = blockIdx.x, br = blockIdx.y, t = threadIdx.x;
  const float* xb = xpn + br * 3010560 + b * 47040;
  const float* a = attn + br * 3136 + b * 49;
  __shared__ float al[49];
  if (t < 49) al[t] = a[t];
  __syncthreads();
  float* eb = ep + br * 122880 + b * 1920;
  for (int c = t; c < 960; c += 256) {
    float s = 0.f, mx = -1e30f;
    for (int hw = 0; hw < 49; ++hw) {
      float v = al[hw] * xb[hw * 960 + c];
      s += v; mx = fmaxf(mx, v);
    }
    eb[c] = s * (1.f / 49.f);
    eb[960 + c] = mx;
  }
}

// ------- M=64 GEMM, split-K with atomicAdd -------
__global__ __launch_bounds__(256) void k_gemm64(
    const float* __restrict__ A0, const float* __restrict__ A1, int asplit,
    int reluA, const float* __restrict__ W, int K, int Kslice,
    float* __restrict__ C, int N) {
  int otile = blockIdx.x, ks = blockIdx.y;
  int t = threadIdx.x, bt = t >> 4, ot = t & 15;
  __shared__ __align__(16) float eT[48 * 68];
  __shared__ __align__(16) float wT[48 * 68];
  float acc[4][4];
#pragma unroll
  for (int i = 0; i < 4; ++i)
#pragma unroll
    for (int j = 0; j < 4; ++j) acc[i][j] = 0.f;
  int kbeg = ks * Kslice, kend = kbeg + Kslice;
  for (int k0 = kbeg; k0 < kend; k0 += 48) {
    __syncthreads();
    for (int i = t; i < 768; i += 256) {
      int b = i / 12, kg = i % 12;
      int k = k0 + kg * 4;
      float4 v;
      if (asplit) {
        v = (k < asplit) ? *(const float4*)&A0[b * 1920 + k]
                         : *(const float4*)&A1[b * 1920 + k - asplit];
      } else {
        v = *(const float4*)&A0[b * K + k];
      }
      if (reluA) {
        v.x = fmaxf(v.x, 0.f); v.y = fmaxf(v.y, 0.f);
        v.z = fmaxf(v.z, 0.f); v.w = fmaxf(v.w, 0.f);
      }
      eT[(kg * 4 + 0) * 68 + b] = v.x; eT[(kg * 4 + 1) * 68 + b] = v.y;
      eT[(kg * 4 + 2) * 68 + b] = v.z; eT[(kg * 4 + 3) * 68 + b] = v.w;
    }
    for (int i = t; i < 768; i += 256) {
      int o = i / 12, kg = i % 12;
      float4 v = *(const float4*)&W[(otile * 64 + o) * K + k0 + kg * 4];
      wT[(kg * 4 + 0) * 68 + o] = v.x; wT[(kg * 4 + 1) * 68 + o] = v.y;
      wT[(kg * 4 + 2) * 68 + o] = v.z; wT[(kg * 4 + 3) * 68 + o] = v.w;
    }
    __syncthreads();
#pragma unroll 4
    for (int kk = 0; kk < 48; ++kk) {
      float av[4], wv[4];
      *(float4*)av = *(const float4*)&eT[kk * 68 + bt * 4];
      *(float4*)wv = *(const float4*)&wT[kk * 68 + ot * 4];
#pragma unroll
      for (int i = 0; i < 4; ++i)
#pragma unroll
        for (int j = 0; j < 4; ++j) acc[i][j] += av[i] * wv[j];
    }
  }
#pragma unroll
  for (int i = 0; i < 4; ++i)
#pragma unroll
    for (int j = 0; j < 4; ++j)
      atomicAdd(&C[(bt * 4 + i) * N + otile * 64 + ot * 4 + j], acc[i][j]);
}

// ------- group pooling over 2.5D groups (+ deferred bias from mlp2) -------
__global__ void k_poolg(const float* __restrict__ em3m, const float* __restrict__ em3e,
                        const float* __restrict__ b2m, const float* __restrict__ b2e,
                        float* __restrict__ pm) {
  int g = blockIdx.x, which = blockIdx.y, t = threadIdx.x;
  const float* em = which ? em3e : em3m;
  const float* b2 = which ? b2e : b2m;
  for (int d = t; d < 960; d += 256) {
    float s = 0.f;
    for (int r = 0; r < 8; ++r) s += em[(g * 8 + r) * 960 + d];
    pm[which * 7680 + g * 960 + d] = s * 0.125f + b2[d];
  }
}

// ------- classifier layer 1: hardswish(pm @ W1^T + b1), per (o-tile, g, which) -------
__global__ __launch_bounds__(256) void k_cls1(
    const float* __restrict__ pmbase, const float* __restrict__ w1mT,
    const float* __restrict__ b1m, const float* __restrict__ w1eT,
    const float* __restrict__ b1e, float* __restrict__ h2) {
  int which = blockIdx.z, g = blockIdx.y, t = threadIdx.x;
  const float* pmw = pmbase + which * 7680 + g * 960;
  const float* WT = which ? w1eT : w1mT;
  const float* b1 = which ? b1e : b1m;
  __shared__ float pl[960];
  for (int i = t; i < 960; i += 256) pl[i] = pmw[i];
  __syncthreads();
  int o = blockIdx.x * 256 + t;
  if (o >= 1920) return;
  float acc = 0.f;
#pragma unroll 8
  for (int k = 0; k < 960; ++k) acc += WT[k * 1920 + o] * pl[k];
  float z = acc + b1[o];
  h2[which * 15360 + g * 1920 + o] = z * fminf(fmaxf(z + 3.f, 0.f), 6.f) * (1.f / 6.f);
}

// ------- classifier layer 2 + final concat (2 waves per (g,which)) -------
__global__ __launch_bounds__(128) void k_cls2(
    const float* __restrict__ h2, const float* __restrict__ w2m,
    const float* __restrict__ b2m, const float* __restrict__ w2e,
    const float* __restrict__ b2e, float* __restrict__ out) {
  int g = blockIdx.x, which = blockIdx.y;
  int t = threadIdx.x, j = t >> 6, lane = t & 63;
  const float* h = h2 + which * 15360 + g * 1920;
  const float* W = (which ? w2e : w2m) + j * 1920;
  const float* bb = which ? b2e : b2m;
  float s = 0.f;
  for (int k = lane; k < 1920; k += 64) s += h[k] * W[k];
  for (int off = 32; off >= 1; off >>= 1) s += __shfl_down(s, off);
  if (lane == 0) out[g * 4 + which * 2 + j] = s + bb[j];
}

// =======================================================================
extern "C" void kernel_launch(void* const* d_in, const int* in_sizes, int n_in,
                              void* d_out, int out_size, void* d_ws, size_t ws_size,
                              hipStream_t stream) {
  const float* x_p = (const float*)d_in[0];
  const float* x_i = (const float*)d_in[1];
  const float* scr_w_in = (const float*)d_in[2];
  const float* scr_bn_in = (const float*)d_in[3];
  const float* scr_w1 = (const float*)d_in[4];
  const float* scr_bn1 = (const float*)d_in[5];
  const float* scr_w2 = (const float*)d_in[6];
  const float* scr_bn2 = (const float*)d_in[7];
  const float* scr_w_out = (const float*)d_in[8];
  const float* scr_bn_out = (const float*)d_in[9];
  const float* cca1x1_w = (const float*)d_in[10];
  const float* cca1x1_bn = (const float*)d_in[11];
  const float* cca0_c2_w = (const float*)d_in[12];
  const float* cca0_c2_bn = (const float*)d_in[13];
  const float* cca0_c1_w = (const float*)d_in[14];
  const float* cca0_c1_bn = (const float*)d_in[15];
  const float* cca0_p_w = (const float*)d_in[16];
  const float* cca0_p_bn = (const float*)d_in[17];
  const float* cca1_c2_w = (const float*)d_in[18];
  const float* cca1_c2_bn = (const float*)d_in[19];
  const float* cca1_c1_w = (const float*)d_in[20];
  const float* cca1_c1_bn = (const float*)d_in[21];
  const float* cca1_p_w = (const float*)d_in[22];
  const float* cca1_p_bn = (const float*)d_in[23];
  const float* meta_w1 = (const float*)d_in[24];
  const float* meta_w2 = (const float*)d_in[25];
  const float* meta_b2 = (const float*)d_in[26];
  const float* ene_w1 = (const float*)d_in[27];
  const float* ene_w2 = (const float*)d_in[28];
  const float* ene_b2 = (const float*)d_in[29];
  const float* mcls_w1 = (const float*)d_in[30];
  const float* mcls_b1 = (const float*)d_in[31];
  const float* mcls_w2 = (const float*)d_in[32];
  const float* mcls_b2 = (const float*)d_in[33];
  const float* ecls_w1 = (const float*)d_in[34];
  const float* ecls_b1 = (const float*)d_in[35];
  const float* ecls_w2 = (const float*)d_in[36];
  const float* ecls_b2 = (const float*)d_in[37];

  float* ws = (float*)d_ws;
  float* XN = ws + OFF_XN;
  float* Y1 = ws + OFF_Y1;
  float* Y2 = ws + OFF_Y2;
  float* T = ws + OFF_T;
  float* XPN = ws + OFF_XPN;
  float* SQ = ws + OFF_SQ;
  float* S0P = ws + OFF_S0P;
  float* S1Y1 = ws + OFF_S1Y1;
  float* S1Y2 = ws + OFF_S1Y2;
  float* ATT = ws + OFF_ATT;
  float* EPI = ws + OFF_EPI;
  float* H1 = ws + OFF_H1;
  float* EM3 = ws + OFF_EM3;
  float* PM = ws + OFF_PM;
  float* H2 = ws + OFF_H2;
  float* WOUTT = ws + OFF_WOUTT;
  float* CCAT = ws + OFF_CCAT;
  float* MCLST = ws + OFF_MCLST;
  float* ECLST = ws + OFF_ECLST;
  float* W1T = ws + OFF_W1T;
  float* W2T = ws + OFF_W2T;
  unsigned* WBF = (unsigned*)(ws + OFF_WBF);

  // weight preps (tiled transposes; R,C all %32)
  k_transpose_t<<<dim3(3, 30), 256, 0, stream>>>(scr_w_out, WOUTT, 960, 96);
  k_transpose_t<<<dim3(30, 3), 256, 0, stream>>>(cca1x1_w, CCAT, 96, 960);
  k_transpose_t<<<dim3(30, 60), 256, 0, stream>>>(mcls_w1, MCLST, 1920, 960);
  k_transpose_t<<<dim3(30, 60), 256, 0, stream>>>(ecls_w1, ECLST, 1920, 960);
  k_prepw<<<dim3(432, 2), 256, 0, stream>>>(scr_w1, scr_w2, W1T, W2T);
  k_prepwbf<<<180, 256, 0, stream>>>(scr_w_in, WBF);

  for (int br = 0; br < 2; ++br) {
    const float* x = br ? x_i : x_p;
    k_l2n<<<64, 256, 0, stream>>>(x, XN);
    k_scr_in<<<dim3(7, 64), 512, 0, stream>>>(XN, WBF, scr_bn_in, Y1);
    k_conv1<<<392, 256, 0, stream>>>(Y1, W1T, scr_bn1, Y2);
    k_conv2<<<392, 128, 0, stream>>>(Y2, W2T, scr_bn2, T);
    k_scr_out<<<dim3(7, 64), 256, 0, stream>>>(T, WOUTT, scr_bn_out, x,
                                               XPN + br * 3010560);
    k_cca1<<<dim3(7, 64), 128, 0, stream>>>(XPN + br * 3010560, CCAT, cca1x1_bn,
                                            SQ + br * 301056);
  }
  k_mid<<<64, 256, 0, stream>>>(SQ, SQ + 301056, cca0_c2_w, cca0_c2_bn,
                                cca0_c1_w, cca0_c1_bn, cca0_p_w, cca0_p_bn, S0P);
  k_sep1a<<<dim3(7, 64), 256, 0, stream>>>(S0P, cca1_c2_w, cca1_c2_bn, S1Y1);
  k_sep1b<<<dim3(7, 64), 256, 0, stream>>>(S1Y1, cca1_c1_w, cca1_c1_bn, S1Y2);
  k_c4attn<<<64, 256, 0, stream>>>(S1Y2, cca1_p_w, cca1_p_bn, ATT, ATT + 3136);
  k_pool<<<dim3(64, 2), 256, 0, stream>>>(XPN, ATT, EPI);

  hipMemsetAsync(H1, 0, (245760u + 122880u) * sizeof(float), stream);
  k_gemm64<<<dim3(30, 8), 256, 0, stream>>>(EPI, EPI + 122880, 960, 0, meta_w1,
                                            1920, 240, H1, 1920);
  k_gemm64<<<dim3(30, 8), 256, 0, stream>>>(EPI + 960, EPI + 122880 + 960, 960, 0,
                                            ene_w1, 1920, 240, H1 + 122880, 1920);
  k_gemm64<<<dim3(15, 8), 256, 0, stream>>>(H1, nullptr, 0, 1, meta_w2, 1920, 240,
                                            EM3, 960);
  k_gemm64<<<dim3(15, 8), 256, 0, stream>>>(H1 + 122880, nullptr, 0, 1, ene_w2,
                                            1920, 240, EM3 + 61440, 960);
  k_poolg<<<dim3(8, 2), 256, 0, stream>>>(EM3, EM3 + 61440, meta_b2, ene_b2, PM);
  k_cls1<<<dim3(8, 8, 2), 256, 0, stream>>>(PM, MCLST, mcls_b1, ECLST, ecls_b1, H2);
  k_cls2<<<dim3(8, 2), 128, 0, stream>>>(H2, mcls_w2, mcls_b2, ecls_w2, ecls_b2,
                                         (float*)d_out);
}

// Round 5
// 1066.070 us; speedup vs baseline: 3.7375x; 1.4381x over previous
//
#include <hip/hip_runtime.h>
#include <hip/hip_bf16.h>

// RtNet25DDualRENet forward. Round 5:
//  - conv1/conv2 as bf16 MFMA GEMMs via precomputed kernel matrix (no im2col):
//    y2[pair,(o,d)] = Y1bf[pair,2432] x Kmat_t[(o,d),2432]; t = y2bf x w2bf.
//  - scr_in emits y1 directly as bf16 [pair][2432] (write traffic halved)
//  - fused k_out_cca (scr_out + cca1), z-merged MLP GEMMs

#define BNINV 0.9999950000374997f  // 1/sqrt(1+1e-5)

typedef __attribute__((ext_vector_type(8))) short bf16x8;
typedef __attribute__((ext_vector_type(4))) float f32x4;

__device__ inline unsigned short f2bf(float f) {
  union { float f; unsigned u; } x; x.f = f;
  unsigned r = x.u + 0x7fffu + ((x.u >> 16) & 1u);  // RNE
  return (unsigned short)(r >> 16);
}

// ---------------- workspace layout (float offsets) ----------------
#define OFF_XN      0u          // (b,960,49)
#define OFF_Y1BF    3010560u    // bf16 [3136 pairs][2432]
#define OFF_KMT     6823936u    // bf16 [896 n][2432 k]
#define OFF_W2BF    7913472u    // bf16 [96][896]
#define OFF_Y2BF    7956480u    // bf16 [3136][896]
#define OFF_T       9361408u    // (b,49,96)
#define OFF_XPN     9662464u    // 2 x (b,49,960)
#define OFF_SQ      15683584u   // 2 x (b,49,96)
#define OFF_S0P     16285696u   // (b,16,49,49)
#define OFF_S1Y1    18744320u
#define OFF_S1Y2    21202944u
#define OFF_ATT     23661568u
#define OFF_EPI     23667840u
#define OFF_H1      23913600u   // 2 x (64,1920), followed by EM3 (contiguous)
#define OFF_EM3     24159360u
#define OFF_PM      24282240u
#define OFF_H2      24297600u
#define OFF_WOUTT   24328320u
#define OFF_CCAT    24420480u
#define OFF_MCLST   24512640u
#define OFF_ECLST   26355840u
#define OFF_WBF     28199040u   // 46080 uints (96x960 bf16 pairs)

// ---------------- tiled transpose: in[R][C] -> out[C][R], R,C %32==0 ----------------
__global__ __launch_bounds__(256) void k_transpose_t(const float* __restrict__ in,
                                                     float* __restrict__ out,
                                                     int R, int C) {
  __shared__ float tl[32][33];
  int c0 = blockIdx.x * 32, r0 = blockIdx.y * 32;
  int tx = threadIdx.x & 31, ty = threadIdx.x >> 5;
#pragma unroll
  for (int i = 0; i < 4; ++i)
    tl[ty + i * 8][tx] = in[(r0 + ty + i * 8) * C + c0 + tx];
  __syncthreads();
#pragma unroll
  for (int i = 0; i < 4; ++i)
    out[(c0 + ty + i * 8) * R + r0 + tx] = tl[tx][ty + i * 8];
}

// ---- prep: scr_w_in (96x960 fp32) -> packed bf16 pairs ----
__global__ void k_prepwbf(const float* __restrict__ w_in, unsigned* __restrict__ WbfU) {
  int i = blockIdx.x * 256 + threadIdx.x;
  if (i >= 46080) return;
  float a = w_in[2 * i], b = w_in[2 * i + 1];
  WbfU[i] = (unsigned)f2bf(a) | ((unsigned)f2bf(b) << 16);
}

// ---- prep: conv1 kernel matrix Kmat_t[n=(o,d)][k=(ic,pos)] bf16, [896][2432] ----
__global__ void k_kmat(const float* __restrict__ w1, unsigned* __restrict__ kmtu) {
  int i = blockIdx.x * 256 + threadIdx.x;  // over 896*1216 uints
  if (i >= 896 * 1216) return;
  int n = i / 1216, ku = i % 1216;
  unsigned out = 0;
#pragma unroll
  for (int h = 0; h < 2; ++h) {
    int k = ku * 2 + h;
    float v = 0.f;
    if (n < 864 && k < 2400) {
      int o = n / 9, d = n % 9, i2 = d / 3, j2 = d % 3;
      int ic = k / 25, pos = k % 25, u = pos / 5, vv = pos % 5;
      int di = u - i2, dj = vv - j2;
      if ((unsigned)di < 3u && (unsigned)dj < 3u)
        v = w1[(o * 96 + ic) * 9 + di * 3 + dj];
    }
    out |= ((unsigned)f2bf(v)) << (16 * h);
  }
  kmtu[i] = out;
}

// ---- prep: w2 -> bf16 [96][896] (rows are w2[o2][864] + zero pad) ----
__global__ void k_w2bf(const float* __restrict__ w2, unsigned short* __restrict__ w2b) {
  int i = blockIdx.x * 256 + threadIdx.x;  // 96*896
  if (i >= 86016) return;
  int o2 = i / 896, k = i % 896;
  w2b[i] = (k < 864) ? f2bf(w2[o2 * 864 + k]) : (unsigned short)0;
}

// ---------------- K1: relu + l2-normalize over C per (b,p) ----------------
__global__ __launch_bounds__(256) void k_l2n(const float* __restrict__ x,
                                             float* __restrict__ xn) {
  int b = blockIdx.x, t = threadIdx.x;
  __shared__ float red[256];
  __shared__ float inv[49];
  const float* xb = x + b * 47040;
  float* ob = xn + b * 47040;
  int p = t & 63, sl = t >> 6;
  float s = 0.f;
  if (p < 49) {
    for (int c = sl * 240; c < sl * 240 + 240; ++c) {
      float v = xb[c * 49 + p];
      if (v > 0.f) s += v * v;
    }
  }
  red[t] = s;
  __syncthreads();
  if (t < 49) {
    float q = red[t] + red[t + 64] + red[t + 128] + red[t + 192];
    inv[t] = 1.f / fmaxf(sqrtf(q), 1e-12f);
  }
  __syncthreads();
  for (int i = t; i < 47040; i += 256) {
    float v = xb[i];
    ob[i] = v > 0.f ? v * inv[i % 49] : 0.f;
  }
}

// ------- K2: fused self-corr x scr_w_in einsum + BN + relu (bf16 MFMA) -------
// Writes y1 as bf16 [pair = b*49+h*7+wp][k = o*25 + uv] with zero pad to 2432.
__global__ __launch_bounds__(512) void k_scr_in(
    const float* __restrict__ xn, const unsigned* __restrict__ WbfU,
    const float* __restrict__ bn, unsigned short* __restrict__ y1bf) {
  const int h = blockIdx.x, b = blockIdx.y, t = threadIdx.x;
  const int wave = t >> 6, lane = t & 63, quad = lane >> 4, lr = lane & 15;
  const int mh = wave >> 2, ng = wave & 3;
  __shared__ __align__(16) short Pl[192 * 40];   // [col][k] bf16, stride 40
  __shared__ __align__(16) short Wl[96 * 40];    // [o][k] bf16, stride 40
  __shared__ __align__(16) float xc[60 * 36];    // [j][k] f32, stride 36
  unsigned* Plu = (unsigned*)Pl;
  unsigned* Wlu = (unsigned*)Wl;
  // zero-pad y1bf[pair][2400..2432)
  if (t < 112) {
    int pairL = t >> 4, ku = t & 15;
    ((unsigned*)y1bf)[(unsigned)(b * 49 + h * 7 + pairL) * 1216u + 1200u + ku] = 0u;
  }
  f32x4 acc[3][3];
#pragma unroll
  for (int m = 0; m < 3; ++m)
#pragma unroll
    for (int n = 0; n < 3; ++n) acc[m][n] = (f32x4){0.f, 0.f, 0.f, 0.f};
  const float* xb = xn + b * 47040;
  const int colB = t >> 1, halfB = t & 1;
  int i1 = 0, i2 = 0;
  if (t < 384) {
    int cc = colB < 175 ? colB : 174;
    int wp = cc / 25, uv = cc - wp * 25, du = uv / 5, dv = uv - du * 5;
    i1 = (26 + wp) * 36;
    i2 = (du * 12 + wp + dv) * 36;
  }
  for (int k0 = 0; k0 < 960; k0 += 32) {
    __syncthreads();
    for (int i = t; i < 1920; i += 512) {
      int kk = i / 60, j = i - kk * 60;
      int r = j / 12, wc = j - r * 12;
      int row = h + r - 2, w = wc - 2;
      float v = 0.f;
      if ((unsigned)row < 7u && (unsigned)w < 7u)
        v = xb[(k0 + kk) * 49 + row * 7 + w];
      xc[j * 36 + kk] = v;
    }
    {
      int base = k0 >> 1;
      for (int i = t; i < 1536; i += 512) {
        int o = i >> 4, kp = i & 15;
        Wlu[o * 20 + kp] = WbfU[o * 480 + base + kp];
      }
    }
    __syncthreads();
    if (t < 384) {
      const float* r1 = &xc[i1 + halfB * 16];
      const float* r2 = &xc[i2 + halfB * 16];
      float a[16], c[16];
#pragma unroll
      for (int q = 0; q < 4; ++q) {
        *(float4*)&a[q * 4] = *(const float4*)&r1[q * 4];
        *(float4*)&c[q * 4] = *(const float4*)&r2[q * 4];
      }
      unsigned* dst = Plu + colB * 20 + halfB * 8;
#pragma unroll
      for (int q = 0; q < 8; ++q) {
        float v0 = a[q * 2] * c[q * 2];
        float v1 = a[q * 2 + 1] * c[q * 2 + 1];
        dst[q] = (unsigned)f2bf(v0) | ((unsigned)f2bf(v1) << 16);
      }
    }
    __syncthreads();
    const int ko = quad * 8;
    bf16x8 af[3], bfr[3];
#pragma unroll
    for (int m = 0; m < 3; ++m)
      af[m] = *(const bf16x8*)&Wl[((mh * 3 + m) * 16 + lr) * 40 + ko];
#pragma unroll
    for (int n = 0; n < 3; ++n)
      bfr[n] = *(const bf16x8*)&Pl[((ng * 3 + n) * 16 + lr) * 40 + ko];
#pragma unroll
    for (int m = 0; m < 3; ++m)
#pragma unroll
      for (int n = 0; n < 3; ++n)
        acc[m][n] = __builtin_amdgcn_mfma_f32_16x16x32_bf16(
            af[m], bfr[n], acc[m][n], 0, 0, 0);
  }
  // epilogue: C/D layout col=lane&15, row=quad*4+reg; write bf16 y1
#pragma unroll
  for (int n = 0; n < 3; ++n) {
    int col = (ng * 3 + n) * 16 + lr;
    if (col >= 175) continue;
    int wp = col / 25, uv = col - wp * 25;
    unsigned pairIdx = (unsigned)(b * 49 + h * 7 + wp);
#pragma unroll
    for (int m = 0; m < 3; ++m) {
#pragma unroll
      for (int r = 0; r < 4; ++r) {
        int o = (mh * 3 + m) * 16 + quad * 4 + r;
        float g = BNINV * bn[o], bt = bn[96 + o];
        float v = fmaxf(acc[m][n][r] * g + bt, 0.f);
        y1bf[pairIdx * 2432u + (unsigned)(o * 25 + uv)] = f2bf(v);
      }
    }
  }
}

// ------- K3: conv1 as MFMA GEMM: y2bf[3136][896] = Y1bf[3136][2432] x Kmat_t^T -------
// grid (49 m-blocks of 64 pairs, 7 n-blocks of 128), 256 thr = 4 waves (2mh x 2nh).
__global__ __launch_bounds__(256) void k_conv1g(
    const unsigned* __restrict__ y1u, const unsigned* __restrict__ kmtu,
    const float* __restrict__ bn1, unsigned short* __restrict__ y2bf) {
  const int t = threadIdx.x;
  const int wave = t >> 6, lane = t & 63, quad = lane >> 4, lr = lane & 15;
  const int mh = wave >> 1, nh = wave & 1;
  const int pairBase = blockIdx.x * 64, nBase = blockIdx.y * 128;
  __shared__ __align__(16) short Ash[64 * 72];
  __shared__ __align__(16) short Bsh[128 * 72];
  __shared__ float bnl[192];
  unsigned* Au = (unsigned*)Ash;
  unsigned* Bu = (unsigned*)Bsh;
  if (t < 192) bnl[t] = bn1[t];
  f32x4 acc[2][4];
#pragma unroll
  for (int m = 0; m < 2; ++m)
#pragma unroll
    for (int n = 0; n < 4; ++n) acc[m][n] = (f32x4){0.f, 0.f, 0.f, 0.f};
  const int prA = t >> 2, qA = t & 3;     // A stage: 64 rows x 4 quarters of 8 uints
  const int nB = t >> 1, qB = t & 1;      // B stage: 128 rows x 2 halves of 16 uints
  for (int c = 0; c < 38; ++c) {
    int ku0 = c * 32;
    __syncthreads();
    {
      const unsigned* src = y1u + (unsigned)(pairBase + prA) * 1216u + ku0 + qA * 8;
      unsigned* dst = Au + prA * 36 + qA * 8;
      *(uint4*)dst = *(const uint4*)src;
      *(uint4*)(dst + 4) = *(const uint4*)(src + 4);
    }
    {
      const unsigned* src = kmtu + (unsigned)(nBase + nB) * 1216u + ku0 + qB * 16;
      unsigned* dst = Bu + nB * 36 + qB * 16;
#pragma unroll
      for (int q = 0; q < 4; ++q)
        *(uint4*)(dst + q * 4) = *(const uint4*)(src + q * 4);
    }
    __syncthreads();
#pragma unroll
    for (int s = 0; s < 2; ++s) {
      int ko = s * 32 + quad * 8;
      bf16x8 af[2], bf[4];
#pragma unroll
      for (int m = 0; m < 2; ++m)
        af[m] = *(const bf16x8*)&Ash[((mh * 2 + m) * 16 + lr) * 72 + ko];
#pragma unroll
      for (int n = 0; n < 4; ++n)
        bf[n] = *(const bf16x8*)&Bsh[((nh * 4 + n) * 16 + lr) * 72 + ko];
#pragma unroll
      for (int m = 0; m < 2; ++m)
#pragma unroll
        for (int n = 0; n < 4; ++n)
          acc[m][n] = __builtin_amdgcn_mfma_f32_16x16x32_bf16(
              af[m], bf[n], acc[m][n], 0, 0, 0);
    }
  }
#pragma unroll
  for (int m = 0; m < 2; ++m) {
#pragma unroll
    for (int r = 0; r < 4; ++r) {
      unsigned pair = (unsigned)(pairBase + (mh * 2 + m) * 16 + quad * 4 + r);
#pragma unroll
      for (int n = 0; n < 4; ++n) {
        int nn = nBase + (nh * 4 + n) * 16 + lr;
        unsigned short outv = 0;
        if (nn < 864) {
          int o = nn / 9;
          float v = fmaxf(acc[m][n][r] * (BNINV * bnl[o]) + bnl[96 + o], 0.f);
          outv = f2bf(v);
        }
        y2bf[pair * 896u + nn] = outv;
      }
    }
  }
}

// ------- K4: conv2 as MFMA GEMM: T[3136][96] = y2bf[3136][896] x w2bf^T -------
// grid 49 (64 pairs each), 256 thr = 4 waves (2mh x 2nh; wave = 2m x 3n tiles).
__global__ __launch_bounds__(256) void k_conv2g(
    const unsigned* __restrict__ y2u, const unsigned* __restrict__ w2u,
    const float* __restrict__ bn2, float* __restrict__ tout) {
  const int t = threadIdx.x;
  const int wave = t >> 6, lane = t & 63, quad = lane >> 4, lr = lane & 15;
  const int mh = wave >> 1, nh = wave & 1;
  const int pairBase = blockIdx.x * 64;
  __shared__ __align__(16) short Ash[64 * 72];
  __shared__ __align__(16) short Bsh[96 * 72];
  __shared__ float bnl[192];
  unsigned* Au = (unsigned*)Ash;
  unsigned* Bu = (unsigned*)Bsh;
  if (t < 192) bnl[t] = bn2[t];
  f32x4 acc[2][3];
#pragma unroll
  for (int m = 0; m < 2; ++m)
#pragma unroll
    for (int n = 0; n < 3; ++n) acc[m][n] = (f32x4){0.f, 0.f, 0.f, 0.f};
  const int prA = t >> 2, qA = t & 3;
  const int nB = t >> 1, qB = t & 1;  // active t<192: 96 rows x 2 halves
  for (int c = 0; c < 14; ++c) {
    int ku0 = c * 32;
    __syncthreads();
    {
      const unsigned* src = y2u + (unsigned)(pairBase + prA) * 448u + ku0 + qA * 8;
      unsigned* dst = Au + prA * 36 + qA * 8;
      *(uint4*)dst = *(const uint4*)src;
      *(uint4*)(dst + 4) = *(const uint4*)(src + 4);
    }
    if (t < 192) {
      const unsigned* src = w2u + (unsigned)nB * 448u + ku0 + qB * 16;
      unsigned* dst = Bu + nB * 36 + qB * 16;
#pragma unroll
      for (int q = 0; q < 4; ++q)
        *(uint4*)(dst + q * 4) = *(const uint4*)(src + q * 4);
    }
    __syncthreads();
#pragma unroll
    for (int s = 0; s < 2; ++s) {
      int ko = s * 32 + quad * 8;
      bf16x8 af[2], bf[3];
#pragma unroll
      for (int m = 0; m < 2; ++m)
        af[m] = *(const bf16x8*)&Ash[((mh * 2 + m) * 16 + lr) * 72 + ko];
#pragma unroll
      for (int n = 0; n < 3; ++n)
        bf[n] = *(const bf16x8*)&Bsh[((nh * 3 + n) * 16 + lr) * 72 + ko];
#pragma unroll
      for (int m = 0; m < 2; ++m)
#pragma unroll
        for (int n = 0; n < 3; ++n)
          acc[m][n] = __builtin_amdgcn_mfma_f32_16x16x32_bf16(
              af[m], bf[n], acc[m][n], 0, 0, 0);
    }
  }
#pragma unroll
  for (int m = 0; m < 2; ++m) {
#pragma unroll
    for (int r = 0; r < 4; ++r) {
      unsigned pair = (unsigned)(pairBase + (mh * 2 + m) * 16 + quad * 4 + r);
#pragma unroll
      for (int n = 0; n < 3; ++n) {
        int o = (nh * 3 + n) * 16 + lr;
        float v = fmaxf(acc[m][n][r] * (BNINV * bnl[o]) + bnl[96 + o], 0.f);
        tout[pair * 96u + o] = v;
      }
    }
  }
}

// ------- K5: fused w_out GEMM + BN + residual relu + mean-sub + cca1 + l2norm -------
__global__ __launch_bounds__(256) void k_out_cca(
    const float* __restrict__ tin, const float* __restrict__ wouT,
    const float* __restrict__ bno, const float* __restrict__ x,
    const float* __restrict__ ccaT, const float* __restrict__ bnc,
    float* __restrict__ xpn, float* __restrict__ sq) {
  int pr = blockIdx.x, b = blockIdx.y, t = threadIdx.x;
  __shared__ __align__(16) float tl2[96 * 8];
  __shared__ float xl[6720];
  __shared__ __align__(16) float xrT[7680];   // [o][8] (7 pl + pad)
  __shared__ float red[2048];
  __shared__ float mean[7];
  __shared__ float sv[672];
  __shared__ float inv7[7];
  for (int i = t; i < 672; i += 256) {
    int pl = i / 96, ic = i % 96;
    tl2[ic * 8 + pl] = tin[(b * 49 + pr * 7 + pl) * 96 + ic];
  }
  for (int i = t; i < 672; i += 256) tl2[(i % 96) * 8 + 7] = 0.f;
  for (int i = t; i < 6720; i += 256) {
    int o = i / 7, pl = i % 7;
    xl[pl * 960 + o] = x[(b * 960 + o) * 49 + pr * 7 + pl];
  }
  __syncthreads();
  float part[7] = {0.f, 0.f, 0.f, 0.f, 0.f, 0.f, 0.f};
  for (int o = t; o < 960; o += 256) {
    float acc[7] = {0.f, 0.f, 0.f, 0.f, 0.f, 0.f, 0.f};
#pragma unroll 4
    for (int ic = 0; ic < 96; ++ic) {
      float w = wouT[ic * 960 + o];
      float tv[8];
      *(float4*)&tv[0] = *(const float4*)&tl2[ic * 8];
      *(float4*)&tv[4] = *(const float4*)&tl2[ic * 8 + 4];
#pragma unroll
      for (int pl = 0; pl < 7; ++pl) acc[pl] += w * tv[pl];
    }
    float g = BNINV * bno[o], bt = bno[960 + o];
#pragma unroll
    for (int pl = 0; pl < 7; ++pl) {
      float v = fmaxf(xl[pl * 960 + o] + acc[pl] * g + bt, 0.f);
      xrT[o * 8 + pl] = v;
      part[pl] += v;
    }
  }
#pragma unroll
  for (int pl = 0; pl < 7; ++pl) red[t * 8 + pl] = part[pl];
  __syncthreads();
  if (t < 64) {
#pragma unroll
    for (int pl = 0; pl < 7; ++pl)
      red[t * 8 + pl] += red[(t + 64) * 8 + pl] + red[(t + 128) * 8 + pl] +
                         red[(t + 192) * 8 + pl];
  }
  __syncthreads();
  if (t < 7) {
    float s = 0.f;
    for (int i = 0; i < 64; ++i) s += red[i * 8 + t];
    mean[t] = s * (1.f / 960.f);
  }
  __syncthreads();
  // write xpn = xr - mean
  for (int i = t; i < 6720; i += 256) {
    int pl = i / 960, o = i % 960;
    xpn[(b * 49 + pr * 7 + pl) * 960 + o] = xrT[o * 8 + pl] - mean[pl];
  }
  // cca phase: acc2[pl] = sum_c w[c,o2]*xr[c][pl]; mean handled via sum(w)
  float acc2[7] = {0.f, 0.f, 0.f, 0.f, 0.f, 0.f, 0.f};
  float sw = 0.f;
  int o2 = t % 96, chalf = t / 96;
  if (t < 192) {
    int c0 = chalf * 480;
    for (int c = c0; c < c0 + 480; ++c) {
      float w = ccaT[c * 96 + o2];
      sw += w;
      float tv[8];
      *(float4*)&tv[0] = *(const float4*)&xrT[c * 8];
      *(float4*)&tv[4] = *(const float4*)&xrT[c * 8 + 4];
#pragma unroll
      for (int pl = 0; pl < 7; ++pl) acc2[pl] += w * tv[pl];
    }
  }
  __syncthreads();
  if (t < 192) {
#pragma unroll
    for (int pl = 0; pl < 7; ++pl) red[(chalf * 96 + o2) * 8 + pl] = acc2[pl];
    red[(chalf * 96 + o2) * 8 + 7] = sw;
  }
  __syncthreads();
  if (t < 96) {
    float g = BNINV * bnc[t], bt = bnc[96 + t];
    float swt = red[t * 8 + 7] + red[(96 + t) * 8 + 7];
#pragma unroll
    for (int pl = 0; pl < 7; ++pl) {
      float a = red[t * 8 + pl] + red[(96 + t) * 8 + pl] - mean[pl] * swt;
      sv[pl * 96 + t] = fmaxf(a * g + bt, 0.f);
    }
  }
  __syncthreads();
  if (t < 112) {
    int pl = t >> 4, ln = t & 15;
    float s = 0.f;
    for (int o = ln; o < 96; o += 16) { float v = sv[pl * 96 + o]; s += v * v; }
    red[pl * 16 + ln] = s;
  }
  __syncthreads();
  if (t < 7) {
    float s = 0.f;
    for (int i = 0; i < 16; ++i) s += red[t * 16 + i];
    inv7[t] = 1.f / fmaxf(sqrtf(s), 1e-8f);
  }
  __syncthreads();
  for (int i = t; i < 672; i += 256) {
    int pl = i / 96, o = i % 96;
    sq[(b * 49 + pr * 7 + pl) * 96 + o] = sv[pl * 96 + o] * inv7[pl];
  }
}

// ------- K7: fused corr + sep4d#0 (conv uv, conv kl, 1->16 proj) -------
__global__ __launch_bounds__(256) void k_mid(
    const float* __restrict__ sq0, const float* __restrict__ sq1,
    const float* __restrict__ wuv, const float* __restrict__ bnuv,
    const float* __restrict__ wkl, const float* __restrict__ bnkl,
    const float* __restrict__ pw16, const float* __restrict__ pbn16,
    float* __restrict__ s0p) {
  int b = blockIdx.x, t = threadIdx.x;
  __shared__ float smem[12304];
  float* sL = smem;
  float* qL = smem + 4900;
  float* A = smem + 9800;
  for (int i = t; i < 4704; i += 256) {
    int p = i / 96, c = i % 96;
    sL[p * 100 + c] = sq0[b * 4704 + i];
    qL[p * 100 + c] = sq1[b * 4704 + i];
  }
  __syncthreads();
  for (int i = t; i < 2401; i += 256) {
    int ij = i / 49, kl = i % 49;
    float a = 0.f;
#pragma unroll 4
    for (int c = 0; c < 96; ++c) a += sL[ij * 100 + c] * qL[kl * 100 + c];
    A[i] = a;
  }
  __syncthreads();
  float* B = smem;
  {
    float w0[9];
#pragma unroll
    for (int d = 0; d < 9; ++d) w0[d] = wuv[d];
    float g = BNINV * bnuv[0], bt = bnuv[1];
    for (int i = t; i < 2401; i += 256) {
      int ij = i / 49, kl = i % 49;
      int u = ij / 7, v = ij % 7;
      float a = 0.f;
#pragma unroll
      for (int du = 0; du < 3; ++du) {
        int uu = u + du - 1;
        if ((unsigned)uu >= 7u) continue;
#pragma unroll
        for (int dv = 0; dv < 3; ++dv) {
          int vv = v + dv - 1;
          if ((unsigned)vv >= 7u) continue;
          a += w0[du * 3 + dv] * A[(uu * 7 + vv) * 49 + kl];
        }
      }
      B[i] = fmaxf(a * g + bt, 0.f);
    }
  }
  __syncthreads();
  float* Cc = smem + 4900;
  {
    float w1[9];
#pragma unroll
    for (int d = 0; d < 9; ++d) w1[d] = wkl[d];
    float g = BNINV * bnkl[0], bt = bnkl[1];
    for (int i = t; i < 2401; i += 256) {
      int ij = i / 49, kl = i % 49;
      int kk = kl / 7, ll = kl % 7;
      float a = 0.f;
#pragma unroll
      for (int dh = 0; dh < 3; ++dh) {
        int k2 = kk + dh - 1;
        if ((unsigned)k2 >= 7u) continue;
#pragma unroll
        for (int dw = 0; dw < 3; ++dw) {
          int l2 = ll + dw - 1;
          if ((unsigned)l2 >= 7u) continue;
          a += w1[dh * 3 + dw] * B[ij * 49 + k2 * 7 + l2];
        }
      }
      Cc[i] = a * g + bt;
    }
  }
  __syncthreads();
  for (int o = 0; o < 16; ++o) {
    float sc = pw16[o] * BNINV * pbn16[o], bt2 = pbn16[16 + o];
    for (int i = t; i < 2401; i += 256)
      s0p[(b * 16 + o) * 2401 + i] = fmaxf(Cc[i] * sc + bt2, 0.f);
  }
}

// ---------------- sep4d #1 conv a (over u,v), row-vectorized ----------------
__global__ __launch_bounds__(256) void k_sep1a(
    const float* __restrict__ in, const float* __restrict__ w,
    const float* __restrict__ bnp, float* __restrict__ out) {
  int kc = blockIdx.x, b = blockIdx.y, t = threadIdx.x;
  __shared__ float inS[16 * 350];
  __shared__ __align__(16) float wP[3072];
  for (int i = t; i < 3072; i += 256) {
    int oc = i / 12, d = i % 12;
    wP[i] = (d < 9) ? w[oc * 9 + d] : 0.f;
  }
  for (int i = t; i < 5488; i += 256) {
    int ic = i / 343, r = i - ic * 343;
    int ij = r / 7, s = r - ij * 7;
    inS[ic * 350 + s * 50 + ij] = in[(b * 16 + ic) * 2401 + ij * 49 + kc * 7 + s];
  }
  __syncthreads();
  for (int rho = t; rho < 784; rho += 256) {
    int o = rho / 49, rem = rho - o * 49, u = rem / 7, s = rem - u * 7;
    float acc[7] = {0.f, 0.f, 0.f, 0.f, 0.f, 0.f, 0.f};
    for (int ic = 0; ic < 16; ++ic) {
      float wv[12];
      const float* wb = &wP[(o * 16 + ic) * 12];
      *(float4*)&wv[0] = *(const float4*)&wb[0];
      *(float4*)&wv[4] = *(const float4*)&wb[4];
      *(float4*)&wv[8] = *(const float4*)&wb[8];
      const float* rowb = &inS[ic * 350 + s * 50];
#pragma unroll
      for (int du = 0; du < 3; ++du) {
        int uu = u + du - 1;
        if ((unsigned)uu >= 7u) continue;
        const float* rr = rowb + uu * 7;
        float r7[7];
#pragma unroll
        for (int q = 0; q < 7; ++q) r7[q] = rr[q];
#pragma unroll
        for (int v = 0; v < 7; ++v) {
          float a = acc[v];
          if (v > 0) a += wv[du * 3 + 0] * r7[v - 1];
          a += wv[du * 3 + 1] * r7[v];
          if (v < 6) a += wv[du * 3 + 2] * r7[v + 1];
          acc[v] = a;
        }
      }
    }
    float g = BNINV * bnp[o], bt = bnp[16 + o];
    long ob = (long)(b * 16 + o) * 2401 + kc * 7 + s;
#pragma unroll
    for (int v = 0; v < 7; ++v)
      out[ob + (u * 7 + v) * 49] = fmaxf(acc[v] * g + bt, 0.f);
  }
}

// ---------------- sep4d #1 conv b (over h,w), row-vectorized ----------------
__global__ __launch_bounds__(256) void k_sep1b(
    const float* __restrict__ in, const float* __restrict__ w,
    const float* __restrict__ bnp, float* __restrict__ out) {
  int ir = blockIdx.x, b = blockIdx.y, t = threadIdx.x;
  __shared__ float inS[16 * 345];
  __shared__ __align__(16) float wP[3072];
  for (int i = t; i < 3072; i += 256) {
    int oc = i / 12, d = i % 12;
    wP[i] = (d < 9) ? w[oc * 9 + d] : 0.f;
  }
  for (int i = t; i < 5488; i += 256) {
    int ic = i / 343, r = i - ic * 343;
    inS[ic * 345 + r] = in[(b * 16 + ic) * 2401 + ir * 343 + r];
  }
  __syncthreads();
  for (int rho = t; rho < 784; rho += 256) {
    int o = rho / 49, rem = rho - o * 49, jj = rem / 7, k = rem - jj * 7;
    float acc[7] = {0.f, 0.f, 0.f, 0.f, 0.f, 0.f, 0.f};
    for (int ic = 0; ic < 16; ++ic) {
      float wv[12];
      const float* wb = &wP[(o * 16 + ic) * 12];
      *(float4*)&wv[0] = *(const float4*)&wb[0];
      *(float4*)&wv[4] = *(const float4*)&wb[4];
      *(float4*)&wv[8] = *(const float4*)&wb[8];
      const float* rowb = &inS[ic * 345 + jj * 49];
#pragma unroll
      for (int dh = 0; dh < 3; ++dh) {
        int k2 = k + dh - 1;
        if ((unsigned)k2 >= 7u) continue;
        const float* rr = rowb + k2 * 7;
        float r7[7];
#pragma unroll
        for (int q = 0; q < 7; ++q) r7[q] = rr[q];
#pragma unroll
        for (int l = 0; l < 7; ++l) {
          float a = acc[l];
          if (l > 0) a += wv[dh * 3 + 0] * r7[l - 1];
          a += wv[dh * 3 + 1] * r7[l];
          if (l < 6) a += wv[dh * 3 + 2] * r7[l + 1];
          acc[l] = a;
        }
      }
    }
    float g = BNINV * bnp[o], bt = bnp[16 + o];
    long ob = (long)(b * 16 + o) * 2401 + ir * 343 + jj * 49 + k * 7;
#pragma unroll
    for (int l = 0; l < 7; ++l)
      out[ob + l] = acc[l] * g + bt;
  }
}

// ------- K10: fused sep1p (16->1 proj) + gauss-softmax attention -------
__global__ __launch_bounds__(256) void k_c4attn(
    const float* __restrict__ in, const float* __restrict__ pw,
    const float* __restrict__ pbn, float* __restrict__ attn_s,
    float* __restrict__ attn_q) {
  int b = blockIdx.x, t = threadIdx.x;
  __shared__ float c[2401];
  __shared__ float n[2401];
  __shared__ float plw[16];
  if (t < 16) plw[t] = pw[t];
  __syncthreads();
  float g0 = BNINV * pbn[0], bt0 = pbn[1];
  for (int i = t; i < 2401; i += 256) {
    float a = 0.f;
#pragma unroll
    for (int ic = 0; ic < 16; ++ic) a += plw[ic] * in[(b * 16 + ic) * 2401 + i];
    c[i] = a * g0 + bt0;
  }
  __syncthreads();
  if (t < 49) {
    float m = 0.f;
    for (int ij = 0; ij < 49; ++ij) m += c[ij * 49 + t];
    m *= (1.f / 49.f);
    float v = 0.f;
    for (int ij = 0; ij < 49; ++ij) { float d = c[ij * 49 + t] - m; v += d * d; }
    v *= (1.f / 48.f);
    float inv = 1.f / sqrtf(v + 1e-5f);
    float mx = -1e30f;
    for (int ij = 0; ij < 49; ++ij) mx = fmaxf(mx, (c[ij * 49 + t] - m) * inv);
    float s = 0.f;
    for (int ij = 0; ij < 49; ++ij) {
      float e = expf((c[ij * 49 + t] - m) * inv - mx);
      n[ij * 49 + t] = e; s += e;
    }
    float r = 1.f / s;
    for (int ij = 0; ij < 49; ++ij) n[ij * 49 + t] *= r;
  }
  __syncthreads();
  if (t < 49) {
    float s = 0.f;
    for (int kl = 0; kl < 49; ++kl) s += n[t * 49 + kl];
    attn_s[b * 49 + t] = s;
  }
  __syncthreads();
  if (t < 49) {
    float m = 0.f;
    for (int kl = 0; kl < 49; ++kl) m += c[t * 49 + kl];
    m *= (1.f / 49.f);
    float v = 0.f;
    for (int kl = 0; kl < 49; ++kl) { float d = c[t * 49 + kl] - m; v += d * d; }
    v *= (1.f / 48.f);
    float inv = 1.f / sqrtf(v + 1e-5f);
    float mx = -1e30f;
    for (int kl = 0; kl < 49; ++kl) mx = fmaxf(mx, (c[t * 49 + kl] - m) * inv);
    float s = 0.f;
    for (int kl = 0; kl < 49; ++kl) {
      float e = expf((c[t * 49 + kl] - m) * inv - mx);
      n[t * 49 + kl] = e; s += e;
    }
    float r = 1.f / s;
    for (int kl = 0; kl < 49; ++kl) n[t * 49 + kl] *= r;
  }
  __syncthreads();
  if (t < 49) {
    float s = 0.f;
    for (int ij = 0; ij < 49; ++ij) s += n[ij * 49 + t];
    attn_q[b * 49 + t] = s;
  }
}

// ------- K11: attention-weighted mean/max pooling -------
__global__ __launch_bounds__(256) void k_pool(const float* __restrict__ xpn,
                                              const float* __restrict__ attn,
                                              float* __restrict__ ep) {
  int b = blockIdx.x, br = blockIdx.y, t = threadIdx.x;
  const float* xb = xpn + br * 3010560 + b * 47040;
  const float* a = attn + br * 3136 + b * 49;
  __shared__ float al[49];
  if (t < 49) al[t] = a[t];
  __syncthreads();
  float* eb = ep + br * 122880 + b * 1920;
  for (int c = t; c < 960; c += 256) {
    float s = 0.f, mx = -1e30f;
    for (int hw = 0; hw < 49; ++hw) {
      float v = al[hw] * xb[hw * 960 + c];
      s += v; mx = fmaxf(mx, v);
    }
    eb[c] = s * (1.f / 49.f);
    eb[960 + c] = mx;
  }
}

// ------- M=64 GEMM, split-K with atomicAdd; z selects meta/ene -------
__global__ __launch_bounds__(256) void k_gemm64(
    const float* __restrict__ A0, const float* __restrict__ A1, int asplit,
    int reluA, const float* __restrict__ Wm, const float* __restrict__ We,
    int K, int Kslice, float* __restrict__ Cm, float* __restrict__ Ce,
    int N, int zAoff) {
  int otile = blockIdx.x, ks = blockIdx.y, z = blockIdx.z;
  const float* W = z ? We : Wm;
  float* C = z ? Ce : Cm;
  int zo = z * zAoff;
  int t = threadIdx.x, bt = t >> 4, ot = t & 15;
  __shared__ __align__(16) float eT[48 * 68];
  __shared__ __align__(16) float wT[48 * 68];
  float acc[4][4];
#pragma unroll
  for (int i = 0; i < 4; ++i)
#pragma unroll
    for (int j = 0; j < 4; ++j) acc[i][j] = 0.f;
  int kbeg = ks * Kslice, kend = kbeg + Kslice;
  for (int k0 = kbeg; k0 < kend; k0 += 48) {
    __syncthreads();
    for (int i = t; i < 768; i += 256) {
      int b = i / 12, kg = i % 12;
      int k = k0 + kg * 4;
      float4 v;
      if (asplit) {
        v = (k < asplit) ? *(const float4*)&A0[b * 1920 + zo + k]
                         : *(const float4*)&A1[b * 1920 + zo + k - asplit];
      } else {
        v = *(const float4*)&A0[zo + b * K + k];
      }
      if (reluA) {
        v.x = fmaxf(v.x, 0.f); v.y = fmaxf(v.y, 0.f);
        v.z = fmaxf(v.z, 0.f); v.w = fmaxf(v.w, 0.f);
      }
      eT[(kg * 4 + 0) * 68 + b] = v.x; eT[(kg * 4 + 1) * 68 + b] = v.y;
      eT[(kg * 4 + 2) * 68 + b] = v.z; eT[(kg * 4 + 3) * 68 + b] = v.w;
    }
    for (int i = t; i < 768; i += 256) {
      int o = i / 12, kg = i % 12;
      float4 v = *(const float4*)&W[(otile * 64 + o) * K + k0 + kg * 4];
      wT[(kg * 4 + 0) * 68 + o] = v.x; wT[(kg * 4 + 1) * 68 + o] = v.y;
      wT[(kg * 4 + 2) * 68 + o] = v.z; wT[(kg * 4 + 3) * 68 + o] = v.w;
    }
    __syncthreads();
#pragma unroll 4
    for (int kk = 0; kk < 48; ++kk) {
      float av[4], wv[4];
      *(float4*)av = *(const float4*)&eT[kk * 68 + bt * 4];
      *(float4*)wv = *(const float4*)&wT[kk * 68 + ot * 4];
#pragma unroll
      for (int i = 0; i < 4; ++i)
#pragma unroll
        for (int j = 0; j < 4; ++j) acc[i][j] += av[i] * wv[j];
    }
  }
#pragma unroll
  for (int i = 0; i < 4; ++i)
#pragma unroll
    for (int j = 0; j < 4; ++j)
      atomicAdd(&C[(bt * 4 + i) * N + otile * 64 + ot * 4 + j], acc[i][j]);
}

// ------- group pooling over 2.5D groups (+ deferred bias from mlp2) -------
__global__ void k_poolg(const float* __restrict__ em3m, const float* __restrict__ em3e,
                        const float* __restrict__ b2m, const float* __restrict__ b2e,
                        float* __restrict__ pm) {
  int g = blockIdx.x, which = blockIdx.y, t = threadIdx.x;
  const float* em = which ? em3e : em3m;
  const float* b2 = which ? b2e : b2m;
  for (int d = t; d < 960; d += 256) {
    float s = 0.f;
    for (int r = 0; r < 8; ++r) s += em[(g * 8 + r) * 960 + d];
    pm[which * 7680 + g * 960 + d] = s * 0.125f + b2[d];
  }
}

// ------- classifier layer 1 -------
__global__ __launch_bounds__(256) void k_cls1(
    const float* __restrict__ pmbase, const float* __restrict__ w1mT,
    const float* __restrict__ b1m, const float* __restrict__ w1eT,
    const float* __restrict__ b1e, float* __restrict__ h2) {
  int which = blockIdx.z, g = blockIdx.y, t = threadIdx.x;
  const float* pmw = pmbase + which * 7680 + g * 960;
  const float* WT = which ? w1eT : w1mT;
  const float* b1 = which ? b1e : b1m;
  __shared__ float pl[960];
  for (int i = t; i < 960; i += 256) pl[i] = pmw[i];
  __syncthreads();
  int o = blockIdx.x * 256 + t;
  if (o >= 1920) return;
  float acc = 0.f;
#pragma unroll 8
  for (int k = 0; k < 960; ++k) acc += WT[k * 1920 + o] * pl[k];
  float z = acc + b1[o];
  h2[which * 15360 + g * 1920 + o] = z * fminf(fmaxf(z + 3.f, 0.f), 6.f) * (1.f / 6.f);
}

// ------- classifier layer 2 + final concat -------
__global__ __launch_bounds__(128) void k_cls2(
    const float* __restrict__ h2, const float* __restrict__ w2m,
    const float* __restrict__ b2m, const float* __restrict__ w2e,
    const float* __restrict__ b2e, float* __restrict__ out) {
  int g = blockIdx.x, which = blockIdx.y;
  int t = threadIdx.x, j = t >> 6, lane = t & 63;
  const float* h = h2 + which * 15360 + g * 1920;
  const float* W = (which ? w2e : w2m) + j * 1920;
  const float* bb = which ? b2e : b2m;
  float s = 0.f;
  for (int k = lane; k < 1920; k += 64) s += h[k] * W[k];
  for (int off = 32; off >= 1; off >>= 1) s += __shfl_down(s, off);
  if (lane == 0) out[g * 4 + which * 2 + j] = s + bb[j];
}

// =======================================================================
extern "C" void kernel_launch(void* const* d_in, const int* in_sizes, int n_in,
                              void* d_out, int out_size, void* d_ws, size_t ws_size,
                              hipStream_t stream) {
  const float* x_p = (const float*)d_in[0];
  const float* x_i = (const float*)d_in[1];
  const float* scr_w_in = (const float*)d_in[2];
  const float* scr_bn_in = (const float*)d_in[3];
  const float* scr_w1 = (const float*)d_in[4];
  const float* scr_bn1 = (const float*)d_in[5];
  const float* scr_w2 = (const float*)d_in[6];
  const float* scr_bn2 = (const float*)d_in[7];
  const float* scr_w_out = (const float*)d_in[8];
  const float* scr_bn_out = (const float*)d_in[9];
  const float* cca1x1_w = (const float*)d_in[10];
  const float* cca1x1_bn = (const float*)d_in[11];
  const float* cca0_c2_w = (const float*)d_in[12];
  const float* cca0_c2_bn = (const float*)d_in[13];
  const float* cca0_c1_w = (const float*)d_in[14];
  const float* cca0_c1_bn = (const float*)d_in[15];
  const float* cca0_p_w = (const float*)d_in[16];
  const float* cca0_p_bn = (const float*)d_in[17];
  const float* cca1_c2_w = (const float*)d_in[18];
  const float* cca1_c2_bn = (const float*)d_in[19];
  const float* cca1_c1_w = (const float*)d_in[20];
  const float* cca1_c1_bn = (const float*)d_in[21];
  const float* cca1_p_w = (const float*)d_in[22];
  const float* cca1_p_bn = (const float*)d_in[23];
  const float* meta_w1 = (const float*)d_in[24];
  const float* meta_w2 = (const float*)d_in[25];
  const float* meta_b2 = (const float*)d_in[26];
  const float* ene_w1 = (const float*)d_in[27];
  const float* ene_w2 = (const float*)d_in[28];
  const float* ene_b2 = (const float*)d_in[29];
  const float* mcls_w1 = (const float*)d_in[30];
  const float* mcls_b1 = (const float*)d_in[31];
  const float* mcls_w2 = (const float*)d_in[32];
  const float* mcls_b2 = (const float*)d_in[33];
  const float* ecls_w1 = (const float*)d_in[34];
  const float* ecls_b1 = (const float*)d_in[35];
  const float* ecls_w2 = (const float*)d_in[36];
  const float* ecls_b2 = (const float*)d_in[37];

  float* ws = (float*)d_ws;
  float* XN = ws + OFF_XN;
  unsigned short* Y1BF = (unsigned short*)(ws + OFF_Y1BF);
  unsigned* KMTU = (unsigned*)(ws + OFF_KMT);
  unsigned short* W2BF = (unsigned short*)(ws + OFF_W2BF);
  unsigned short* Y2BF = (unsigned short*)(ws + OFF_Y2BF);
  float* T = ws + OFF_T;
  float* XPN = ws + OFF_XPN;
  float* SQ = ws + OFF_SQ;
  float* S0P = ws + OFF_S0P;
  float* S1Y1 = ws + OFF_S1Y1;
  float* S1Y2 = ws + OFF_S1Y2;
  float* ATT = ws + OFF_ATT;
  float* EPI = ws + OFF_EPI;
  float* H1 = ws + OFF_H1;
  float* EM3 = ws + OFF_EM3;
  float* PM = ws + OFF_PM;
  float* H2 = ws + OFF_H2;
  float* WOUTT = ws + OFF_WOUTT;
  float* CCAT = ws + OFF_CCAT;
  float* MCLST = ws + OFF_MCLST;
  float* ECLST = ws + OFF_ECLST;
  unsigned* WBF = (unsigned*)(ws + OFF_WBF);

  // weight preps
  k_transpose_t<<<dim3(3, 30), 256, 0, stream>>>(scr_w_out, WOUTT, 960, 96);
  k_transpose_t<<<dim3(30, 3), 256, 0, stream>>>(cca1x1_w, CCAT, 96, 960);
  k_transpose_t<<<dim3(30, 60), 256, 0, stream>>>(mcls_w1, MCLST, 1920, 960);
  k_transpose_t<<<dim3(30, 60), 256, 0, stream>>>(ecls_w1, ECLST, 1920, 960);
  k_prepwbf<<<180, 256, 0, stream>>>(scr_w_in, WBF);
  k_kmat<<<4256, 256, 0, stream>>>(scr_w1, KMTU);
  k_w2bf<<<336, 256, 0, stream>>>(scr_w2, W2BF);

  for (int br = 0; br < 2; ++br) {
    const float* x = br ? x_i : x_p;
    k_l2n<<<64, 256, 0, stream>>>(x, XN);
    k_scr_in<<<dim3(7, 64), 512, 0, stream>>>(XN, WBF, scr_bn_in, Y1BF);
    k_conv1g<<<dim3(49, 7), 256, 0, stream>>>((const unsigned*)Y1BF, KMTU,
                                              scr_bn1, Y2BF);
    k_conv2g<<<49, 256, 0, stream>>>((const unsigned*)Y2BF, (const unsigned*)W2BF,
                                     scr_bn2, T);
    k_out_cca<<<dim3(7, 64), 256, 0, stream>>>(T, WOUTT, scr_bn_out, x, CCAT,
                                               cca1x1_bn, XPN + br * 3010560,
                                               SQ + br * 301056);
  }
  k_mid<<<64, 256, 0, stream>>>(SQ, SQ + 301056, cca0_c2_w, cca0_c2_bn,
                                cca0_c1_w, cca0_c1_bn, cca0_p_w, cca0_p_bn, S0P);
  k_sep1a<<<dim3(7, 64), 256, 0, stream>>>(S0P, cca1_c2_w, cca1_c2_bn, S1Y1);
  k_sep1b<<<dim3(7, 64), 256, 0, stream>>>(S1Y1, cca1_c1_w, cca1_c1_bn, S1Y2);
  k_c4attn<<<64, 256, 0, stream>>>(S1Y2, cca1_p_w, cca1_p_bn, ATT, ATT + 3136);
  k_pool<<<dim3(64, 2), 256, 0, stream>>>(XPN, ATT, EPI);

  hipMemsetAsync(H1, 0, (245760u + 122880u) * sizeof(float), stream);
  k_gemm64<<<dim3(30, 8, 2), 256, 0, stream>>>(EPI, EPI + 122880, 960, 0,
                                               meta_w1, ene_w1, 1920, 240,
                                               H1, H1 + 122880, 1920, 960);
  k_gemm64<<<dim3(15, 8, 2), 256, 0, stream>>>(H1, nullptr, 0, 1,
                                               meta_w2, ene_w2, 1920, 240,
                                               EM3, EM3 + 61440, 960, 122880);
  k_poolg<<<dim3(8, 2), 256, 0, stream>>>(EM3, EM3 + 61440, meta_b2, ene_b2, PM);
  k_cls1<<<dim3(8, 8, 2), 256, 0, stream>>>(PM, MCLST, mcls_b1, ECLST, ecls_b1, H2);
  k_cls2<<<dim3(8, 2), 128, 0, stream>>>(H2, mcls_w2, mcls_b2, ecls_w2, ecls_b2,
                                         (float*)d_out);
}

// Round 6
// 941.245 us; speedup vs baseline: 4.2331x; 1.1326x over previous
//
#include <hip/hip_runtime.h>
#include <hip/hip_bf16.h>

// RtNet25DDualRENet forward. Round 6:
//  - k_scr_in v4: XCD swizzle (grid 64b x 7h), ping-pong LDS (2 barriers/chunk),
//    register prefetch of next chunk overlapping MFMA
//  - XCD swizzles for out_cca / sep1a / sep1b / conv1g
//  - conv2g: 98 blocks (was 49)
//  - k_mid 512 thr; c4attn dual-softmax concurrency; poolg folded into cls1

#define BNINV 0.9999950000374997f  // 1/sqrt(1+1e-5)

typedef __attribute__((ext_vector_type(8))) short bf16x8;
typedef __attribute__((ext_vector_type(4))) float f32x4;

__device__ inline unsigned short f2bf(float f) {
  union { float f; unsigned u; } x; x.f = f;
  unsigned r = x.u + 0x7fffu + ((x.u >> 16) & 1u);  // RNE
  return (unsigned short)(r >> 16);
}

// ---------------- workspace layout (float offsets) ----------------
#define OFF_XN      0u          // (b,960,49)
#define OFF_Y1BF    3010560u    // bf16 [3136 pairs][2432]
#define OFF_KMT     6823936u    // bf16 [896 n][2432 k]
#define OFF_W2BF    7913472u    // bf16 [96][896]
#define OFF_Y2BF    7956480u    // bf16 [3136][896]
#define OFF_T       9361408u    // (b,49,96)
#define OFF_XPN     9662464u    // 2 x (b,49,960)
#define OFF_SQ      15683584u   // 2 x (b,49,96)
#define OFF_S0P     16285696u   // (b,16,49,49)
#define OFF_S1Y1    18744320u
#define OFF_S1Y2    21202944u
#define OFF_ATT     23661568u
#define OFF_EPI     23667840u
#define OFF_H1      23913600u   // 2 x (64,1920)
#define OFF_EM3     24159360u   // 2 x (64,960)
#define OFF_H2      24297600u
#define OFF_WOUTT   24328320u
#define OFF_CCAT    24420480u
#define OFF_MCLST   24512640u
#define OFF_ECLST   26355840u
#define OFF_WBF     28199040u   // 46080 uints (96x960 bf16 pairs)

// ---------------- tiled transpose ----------------
__global__ __launch_bounds__(256) void k_transpose_t(const float* __restrict__ in,
                                                     float* __restrict__ out,
                                                     int R, int C) {
  __shared__ float tl[32][33];
  int c0 = blockIdx.x * 32, r0 = blockIdx.y * 32;
  int tx = threadIdx.x & 31, ty = threadIdx.x >> 5;
#pragma unroll
  for (int i = 0; i < 4; ++i)
    tl[ty + i * 8][tx] = in[(r0 + ty + i * 8) * C + c0 + tx];
  __syncthreads();
#pragma unroll
  for (int i = 0; i < 4; ++i)
    out[(c0 + ty + i * 8) * R + r0 + tx] = tl[tx][ty + i * 8];
}

// ---- prep: scr_w_in -> packed bf16 pairs ----
__global__ void k_prepwbf(const float* __restrict__ w_in, unsigned* __restrict__ WbfU) {
  int i = blockIdx.x * 256 + threadIdx.x;
  if (i >= 46080) return;
  float a = w_in[2 * i], b = w_in[2 * i + 1];
  WbfU[i] = (unsigned)f2bf(a) | ((unsigned)f2bf(b) << 16);
}

// ---- prep: conv1 kernel matrix Kmat_t[n=(o,d)][k=(ic,pos)] bf16 [896][2432] ----
__global__ void k_kmat(const float* __restrict__ w1, unsigned* __restrict__ kmtu) {
  int i = blockIdx.x * 256 + threadIdx.x;
  if (i >= 896 * 1216) return;
  int n = i / 1216, ku = i % 1216;
  unsigned out = 0;
#pragma unroll
  for (int h = 0; h < 2; ++h) {
    int k = ku * 2 + h;
    float v = 0.f;
    if (n < 864 && k < 2400) {
      int o = n / 9, d = n % 9, i2 = d / 3, j2 = d % 3;
      int ic = k / 25, pos = k % 25, u = pos / 5, vv = pos % 5;
      int di = u - i2, dj = vv - j2;
      if ((unsigned)di < 3u && (unsigned)dj < 3u)
        v = w1[(o * 96 + ic) * 9 + di * 3 + dj];
    }
    out |= ((unsigned)f2bf(v)) << (16 * h);
  }
  kmtu[i] = out;
}

// ---- prep: w2 -> bf16 [96][896] ----
__global__ void k_w2bf(const float* __restrict__ w2, unsigned short* __restrict__ w2b) {
  int i = blockIdx.x * 256 + threadIdx.x;
  if (i >= 86016) return;
  int o2 = i / 896, k = i % 896;
  w2b[i] = (k < 864) ? f2bf(w2[o2 * 864 + k]) : (unsigned short)0;
}

// ---------------- K1: relu + l2-normalize over C per (b,p) ----------------
__global__ __launch_bounds__(256) void k_l2n(const float* __restrict__ x,
                                             float* __restrict__ xn) {
  int b = blockIdx.x, t = threadIdx.x;
  __shared__ float red[256];
  __shared__ float inv[49];
  const float* xb = x + b * 47040;
  float* ob = xn + b * 47040;
  int p = t & 63, sl = t >> 6;
  float s = 0.f;
  if (p < 49) {
    for (int c = sl * 240; c < sl * 240 + 240; ++c) {
      float v = xb[c * 49 + p];
      if (v > 0.f) s += v * v;
    }
  }
  red[t] = s;
  __syncthreads();
  if (t < 49) {
    float q = red[t] + red[t + 64] + red[t + 128] + red[t + 192];
    inv[t] = 1.f / fmaxf(sqrtf(q), 1e-12f);
  }
  __syncthreads();
  for (int i = t; i < 47040; i += 256) {
    float v = xb[i];
    ob[i] = v > 0.f ? v * inv[i % 49] : 0.f;
  }
}

// ------- K2: fused self-corr x scr_w_in einsum + BN + relu (bf16 MFMA, v4) -------
// grid (64 b, 7 h) — same-b blocks stride 64 => same XCD (L2 reuse of xn).
// Ping-pong LDS, 2 barriers/chunk, register prefetch overlapping MFMA.
__global__ __launch_bounds__(512) void k_scr_in(
    const float* __restrict__ xn, const unsigned* __restrict__ WbfU,
    const float* __restrict__ bn, unsigned short* __restrict__ y1bf) {
  const int b = blockIdx.x, h = blockIdx.y, t = threadIdx.x;
  const int wave = t >> 6, lane = t & 63, quad = lane >> 4, lr = lane & 15;
  const int mh = wave >> 2, ng = wave & 3;
  __shared__ __align__(16) short Pl[2][192 * 40];
  __shared__ __align__(16) short Wl[2][96 * 40];
  __shared__ __align__(16) float xc[2][2160];   // [j][k] stride 36
  // zero-pad y1bf[pair][2400..2432)
  if (t < 112) {
    int pairL = t >> 4, ku = t & 15;
    ((unsigned*)y1bf)[(unsigned)(b * 49 + h * 7 + pairL) * 1216u + 1200u + ku] = 0u;
  }
  f32x4 acc[3][3];
#pragma unroll
  for (int m = 0; m < 3; ++m)
#pragma unroll
    for (int n = 0; n < 3; ++n) acc[m][n] = (f32x4){0.f, 0.f, 0.f, 0.f};
  const float* xb = xn + b * 47040;
  const int colB = t >> 1, halfB = t & 1;
  int i1 = 0, i2 = 0;
  if (t < 384) {
    int cc = colB < 175 ? colB : 174;
    int wp = cc / 25, uv = cc - wp * 25, du = uv / 5, dv = uv - du * 5;
    i1 = (26 + wp) * 36;
    i2 = (du * 12 + wp + dv) * 36;
  }
  float xr0[4];
  unsigned wr0[3];
  // prefetch chunk 0
  {
    const int k0 = 0;
#pragma unroll
    for (int it = 0; it < 4; ++it) {
      int i = t + it * 512;
      float v = 0.f;
      if (i < 1920) {
        int kk = i / 60, j = i - kk * 60;
        int r = j / 12, wc = j - r * 12;
        int row = h + r - 2, w = wc - 2;
        if ((unsigned)row < 7u && (unsigned)w < 7u)
          v = xb[(k0 + kk) * 49 + row * 7 + w];
      }
      xr0[it] = v;
    }
#pragma unroll
    for (int it = 0; it < 3; ++it) {
      int i = t + it * 512;
      wr0[it] = WbfU[(i >> 4) * 480 + (i & 15)];
    }
  }
  int p = 0;
  for (int c = 0; c < 30; ++c, p ^= 1) {
    // store prefetched regs into LDS buffer p
    float* xcb = xc[p];
#pragma unroll
    for (int it = 0; it < 4; ++it) {
      int i = t + it * 512;
      if (i < 1920) {
        int kk = i / 60, j = i - kk * 60;
        xcb[j * 36 + kk] = xr0[it];
      }
    }
    unsigned* Wlu = (unsigned*)Wl[p];
#pragma unroll
    for (int it = 0; it < 3; ++it) {
      int i = t + it * 512;
      Wlu[(i >> 4) * 20 + (i & 15)] = wr0[it];
    }
    __syncthreads();
    // build P[p]
    if (t < 384) {
      const float* r1 = &xcb[i1 + halfB * 16];
      const float* r2 = &xcb[i2 + halfB * 16];
      float a[16], cc[16];
#pragma unroll
      for (int q = 0; q < 4; ++q) {
        *(float4*)&a[q * 4] = *(const float4*)&r1[q * 4];
        *(float4*)&cc[q * 4] = *(const float4*)&r2[q * 4];
      }
      unsigned* dst = (unsigned*)Pl[p] + colB * 20 + halfB * 8;
#pragma unroll
      for (int q = 0; q < 8; ++q) {
        float v0 = a[q * 2] * cc[q * 2];
        float v1 = a[q * 2 + 1] * cc[q * 2 + 1];
        dst[q] = (unsigned)f2bf(v0) | ((unsigned)f2bf(v1) << 16);
      }
    }
    __syncthreads();
    // prefetch chunk c+1 (rides across the MFMA phase)
    if (c < 29) {
      const int k0 = (c + 1) * 32;
#pragma unroll
      for (int it = 0; it < 4; ++it) {
        int i = t + it * 512;
        float v = 0.f;
        if (i < 1920) {
          int kk = i / 60, j = i - kk * 60;
          int r = j / 12, wc = j - r * 12;
          int row = h + r - 2, w = wc - 2;
          if ((unsigned)row < 7u && (unsigned)w < 7u)
            v = xb[(k0 + kk) * 49 + row * 7 + w];
        }
        xr0[it] = v;
      }
      int base = k0 >> 1;
#pragma unroll
      for (int it = 0; it < 3; ++it) {
        int i = t + it * 512;
        wr0[it] = WbfU[(i >> 4) * 480 + base + (i & 15)];
      }
    }
    // MFMA on buffer p
    const int ko = quad * 8;
    bf16x8 af[3], bfr[3];
#pragma unroll
    for (int m = 0; m < 3; ++m)
      af[m] = *(const bf16x8*)&Wl[p][((mh * 3 + m) * 16 + lr) * 40 + ko];
#pragma unroll
    for (int n = 0; n < 3; ++n)
      bfr[n] = *(const bf16x8*)&Pl[p][((ng * 3 + n) * 16 + lr) * 40 + ko];
#pragma unroll
    for (int m = 0; m < 3; ++m)
#pragma unroll
      for (int n = 0; n < 3; ++n)
        acc[m][n] = __builtin_amdgcn_mfma_f32_16x16x32_bf16(
            af[m], bfr[n], acc[m][n], 0, 0, 0);
  }
  // epilogue: C/D col=lane&15, row=quad*4+reg
#pragma unroll
  for (int n = 0; n < 3; ++n) {
    int col = (ng * 3 + n) * 16 + lr;
    if (col >= 175) continue;
    int wp = col / 25, uv = col - wp * 25;
    unsigned pairIdx = (unsigned)(b * 49 + h * 7 + wp);
#pragma unroll
    for (int m = 0; m < 3; ++m) {
#pragma unroll
      for (int r = 0; r < 4; ++r) {
        int o = (mh * 3 + m) * 16 + quad * 4 + r;
        float g = BNINV * bn[o], bt = bn[96 + o];
        float v = fmaxf(acc[m][n][r] * g + bt, 0.f);
        y1bf[pairIdx * 2432u + (unsigned)(o * 25 + uv)] = f2bf(v);
      }
    }
  }
}

// ------- K3: conv1 MFMA GEMM. grid (64 m-slots [49 used], 7 n) -------
__global__ __launch_bounds__(256) void k_conv1g(
    const unsigned* __restrict__ y1u, const unsigned* __restrict__ kmtu,
    const float* __restrict__ bn1, unsigned short* __restrict__ y2bf) {
  if (blockIdx.x >= 49) return;
  const int t = threadIdx.x;
  const int wave = t >> 6, lane = t & 63, quad = lane >> 4, lr = lane & 15;
  const int mh = wave >> 1, nh = wave & 1;
  const int pairBase = blockIdx.x * 64, nBase = blockIdx.y * 128;
  __shared__ __align__(16) short Ash[64 * 72];
  __shared__ __align__(16) short Bsh[128 * 72];
  __shared__ float bnl[192];
  unsigned* Au = (unsigned*)Ash;
  unsigned* Bu = (unsigned*)Bsh;
  if (t < 192) bnl[t] = bn1[t];
  f32x4 acc[2][4];
#pragma unroll
  for (int m = 0; m < 2; ++m)
#pragma unroll
    for (int n = 0; n < 4; ++n) acc[m][n] = (f32x4){0.f, 0.f, 0.f, 0.f};
  const int prA = t >> 2, qA = t & 3;
  const int nB = t >> 1, qB = t & 1;
  for (int c = 0; c < 38; ++c) {
    int ku0 = c * 32;
    __syncthreads();
    {
      const unsigned* src = y1u + (unsigned)(pairBase + prA) * 1216u + ku0 + qA * 8;
      unsigned* dst = Au + prA * 36 + qA * 8;
      *(uint4*)dst = *(const uint4*)src;
      *(uint4*)(dst + 4) = *(const uint4*)(src + 4);
    }
    {
      const unsigned* src = kmtu + (unsigned)(nBase + nB) * 1216u + ku0 + qB * 16;
      unsigned* dst = Bu + nB * 36 + qB * 16;
#pragma unroll
      for (int q = 0; q < 4; ++q)
        *(uint4*)(dst + q * 4) = *(const uint4*)(src + q * 4);
    }
    __syncthreads();
#pragma unroll
    for (int s = 0; s < 2; ++s) {
      int ko = s * 32 + quad * 8;
      bf16x8 af[2], bf[4];
#pragma unroll
      for (int m = 0; m < 2; ++m)
        af[m] = *(const bf16x8*)&Ash[((mh * 2 + m) * 16 + lr) * 72 + ko];
#pragma unroll
      for (int n = 0; n < 4; ++n)
        bf[n] = *(const bf16x8*)&Bsh[((nh * 4 + n) * 16 + lr) * 72 + ko];
#pragma unroll
      for (int m = 0; m < 2; ++m)
#pragma unroll
        for (int n = 0; n < 4; ++n)
          acc[m][n] = __builtin_amdgcn_mfma_f32_16x16x32_bf16(
              af[m], bf[n], acc[m][n], 0, 0, 0);
    }
  }
#pragma unroll
  for (int m = 0; m < 2; ++m) {
#pragma unroll
    for (int r = 0; r < 4; ++r) {
      unsigned pair = (unsigned)(pairBase + (mh * 2 + m) * 16 + quad * 4 + r);
#pragma unroll
      for (int n = 0; n < 4; ++n) {
        int nn = nBase + (nh * 4 + n) * 16 + lr;
        unsigned short outv = 0;
        if (nn < 864) {
          int o = nn / 9;
          float v = fmaxf(acc[m][n][r] * (BNINV * bnl[o]) + bnl[96 + o], 0.f);
          outv = f2bf(v);
        }
        y2bf[pair * 896u + nn] = outv;
      }
    }
  }
}

// ------- K4: conv2 MFMA GEMM, 98 blocks of 32 pairs -------
__global__ __launch_bounds__(256) void k_conv2g(
    const unsigned* __restrict__ y2u, const unsigned* __restrict__ w2u,
    const float* __restrict__ bn2, float* __restrict__ tout) {
  const int t = threadIdx.x;
  const int wave = t >> 6, lane = t & 63, quad = lane >> 4, lr = lane & 15;
  const int mh = wave >> 1, nh = wave & 1;
  const int pairBase = blockIdx.x * 32;
  __shared__ __align__(16) short Ash[32 * 72];
  __shared__ __align__(16) short Bsh[96 * 72];
  __shared__ float bnl[192];
  unsigned* Au = (unsigned*)Ash;
  unsigned* Bu = (unsigned*)Bsh;
  if (t < 192) bnl[t] = bn2[t];
  f32x4 acc[3];
#pragma unroll
  for (int n = 0; n < 3; ++n) acc[n] = (f32x4){0.f, 0.f, 0.f, 0.f};
  const int prA = t >> 3, qA = (t & 7) * 4;
  const int nB = t >> 1, qB = (t & 1) * 16;
  for (int c = 0; c < 14; ++c) {
    int ku0 = c * 32;
    __syncthreads();
    {
      const unsigned* src = y2u + (unsigned)(pairBase + prA) * 448u + ku0 + qA;
      *(uint4*)(Au + prA * 36 + qA) = *(const uint4*)src;
    }
    if (t < 192) {
      const unsigned* src = w2u + (unsigned)nB * 448u + ku0 + qB;
      unsigned* dst = Bu + nB * 36 + qB;
#pragma unroll
      for (int q = 0; q < 4; ++q)
        *(uint4*)(dst + q * 4) = *(const uint4*)(src + q * 4);
    }
    __syncthreads();
#pragma unroll
    for (int s = 0; s < 2; ++s) {
      int ko = s * 32 + quad * 8;
      bf16x8 af;
      af = *(const bf16x8*)&Ash[(mh * 16 + lr) * 72 + ko];
#pragma unroll
      for (int n = 0; n < 3; ++n) {
        bf16x8 bf = *(const bf16x8*)&Bsh[((nh * 3 + n) * 16 + lr) * 72 + ko];
        acc[n] = __builtin_amdgcn_mfma_f32_16x16x32_bf16(af, bf, acc[n], 0, 0, 0);
      }
    }
  }
#pragma unroll
  for (int r = 0; r < 4; ++r) {
    unsigned pair = (unsigned)(pairBase + mh * 16 + quad * 4 + r);
#pragma unroll
    for (int n = 0; n < 3; ++n) {
      int o = (nh * 3 + n) * 16 + lr;
      float v = fmaxf(acc[n][r] * (BNINV * bnl[o]) + bnl[96 + o], 0.f);
      tout[pair * 96u + o] = v;
    }
  }
}

// ------- K5: fused w_out GEMM + BN + residual relu + mean-sub + cca1 + l2norm -------
// grid (64 b, 7 pr) — same-b blocks stride 64 => same XCD.
__global__ __launch_bounds__(256) void k_out_cca(
    const float* __restrict__ tin, const float* __restrict__ wouT,
    const float* __restrict__ bno, const float* __restrict__ x,
    const float* __restrict__ ccaT, const float* __restrict__ bnc,
    float* __restrict__ xpn, float* __restrict__ sq) {
  int b = blockIdx.x, pr = blockIdx.y, t = threadIdx.x;
  __shared__ __align__(16) float tl2[96 * 8];
  __shared__ float xl[6720];
  __shared__ __align__(16) float xrT[7680];
  __shared__ float red[2048];
  __shared__ float mean[7];
  __shared__ float sv[672];
  __shared__ float inv7[7];
  for (int i = t; i < 672; i += 256) {
    int pl = i / 96, ic = i % 96;
    tl2[ic * 8 + pl] = tin[(b * 49 + pr * 7 + pl) * 96 + ic];
  }
  for (int i = t; i < 672; i += 256) tl2[(i % 96) * 8 + 7] = 0.f;
  for (int i = t; i < 6720; i += 256) {
    int o = i / 7, pl = i % 7;
    xl[pl * 960 + o] = x[(b * 960 + o) * 49 + pr * 7 + pl];
  }
  __syncthreads();
  float part[7] = {0.f, 0.f, 0.f, 0.f, 0.f, 0.f, 0.f};
  for (int o = t; o < 960; o += 256) {
    float acc[7] = {0.f, 0.f, 0.f, 0.f, 0.f, 0.f, 0.f};
#pragma unroll 4
    for (int ic = 0; ic < 96; ++ic) {
      float w = wouT[ic * 960 + o];
      float tv[8];
      *(float4*)&tv[0] = *(const float4*)&tl2[ic * 8];
      *(float4*)&tv[4] = *(const float4*)&tl2[ic * 8 + 4];
#pragma unroll
      for (int pl = 0; pl < 7; ++pl) acc[pl] += w * tv[pl];
    }
    float g = BNINV * bno[o], bt = bno[960 + o];
#pragma unroll
    for (int pl = 0; pl < 7; ++pl) {
      float v = fmaxf(xl[pl * 960 + o] + acc[pl] * g + bt, 0.f);
      xrT[o * 8 + pl] = v;
      part[pl] += v;
    }
  }
#pragma unroll
  for (int pl = 0; pl < 7; ++pl) red[t * 8 + pl] = part[pl];
  __syncthreads();
  if (t < 64) {
#pragma unroll
    for (int pl = 0; pl < 7; ++pl)
      red[t * 8 + pl] += red[(t + 64) * 8 + pl] + red[(t + 128) * 8 + pl] +
                         red[(t + 192) * 8 + pl];
  }
  __syncthreads();
  if (t < 7) {
    float s = 0.f;
    for (int i = 0; i < 64; ++i) s += red[i * 8 + t];
    mean[t] = s * (1.f / 960.f);
  }
  __syncthreads();
  for (int i = t; i < 6720; i += 256) {
    int pl = i / 960, o = i % 960;
    xpn[(b * 49 + pr * 7 + pl) * 960 + o] = xrT[o * 8 + pl] - mean[pl];
  }
  float acc2[7] = {0.f, 0.f, 0.f, 0.f, 0.f, 0.f, 0.f};
  float sw = 0.f;
  int o2 = t % 96, chalf = t / 96;
  if (t < 192) {
    int c0 = chalf * 480;
    for (int c = c0; c < c0 + 480; ++c) {
      float w = ccaT[c * 96 + o2];
      sw += w;
      float tv[8];
      *(float4*)&tv[0] = *(const float4*)&xrT[c * 8];
      *(float4*)&tv[4] = *(const float4*)&xrT[c * 8 + 4];
#pragma unroll
      for (int pl = 0; pl < 7; ++pl) acc2[pl] += w * tv[pl];
    }
  }
  __syncthreads();
  if (t < 192) {
#pragma unroll
    for (int pl = 0; pl < 7; ++pl) red[(chalf * 96 + o2) * 8 + pl] = acc2[pl];
    red[(chalf * 96 + o2) * 8 + 7] = sw;
  }
  __syncthreads();
  if (t < 96) {
    float g = BNINV * bnc[t], bt = bnc[96 + t];
    float swt = red[t * 8 + 7] + red[(96 + t) * 8 + 7];
#pragma unroll
    for (int pl = 0; pl < 7; ++pl) {
      float a = red[t * 8 + pl] + red[(96 + t) * 8 + pl] - mean[pl] * swt;
      sv[pl * 96 + t] = fmaxf(a * g + bt, 0.f);
    }
  }
  __syncthreads();
  if (t < 112) {
    int pl = t >> 4, ln = t & 15;
    float s = 0.f;
    for (int o = ln; o < 96; o += 16) { float v = sv[pl * 96 + o]; s += v * v; }
    red[pl * 16 + ln] = s;
  }
  __syncthreads();
  if (t < 7) {
    float s = 0.f;
    for (int i = 0; i < 16; ++i) s += red[t * 16 + i];
    inv7[t] = 1.f / fmaxf(sqrtf(s), 1e-8f);
  }
  __syncthreads();
  for (int i = t; i < 672; i += 256) {
    int pl = i / 96, o = i % 96;
    sq[(b * 49 + pr * 7 + pl) * 96 + o] = sv[pl * 96 + o] * inv7[pl];
  }
}

// ------- K7: fused corr + sep4d#0 (512 threads) -------
__global__ __launch_bounds__(512) void k_mid(
    const float* __restrict__ sq0, const float* __restrict__ sq1,
    const float* __restrict__ wuv, const float* __restrict__ bnuv,
    const float* __restrict__ wkl, const float* __restrict__ bnkl,
    const float* __restrict__ pw16, const float* __restrict__ pbn16,
    float* __restrict__ s0p) {
  int b = blockIdx.x, t = threadIdx.x;
  __shared__ float smem[12304];
  float* sL = smem;
  float* qL = smem + 4900;
  float* A = smem + 9800;
  for (int i = t; i < 4704; i += 512) {
    int p = i / 96, c = i % 96;
    sL[p * 100 + c] = sq0[b * 4704 + i];
    qL[p * 100 + c] = sq1[b * 4704 + i];
  }
  __syncthreads();
  for (int i = t; i < 2401; i += 512) {
    int ij = i / 49, kl = i % 49;
    float a = 0.f;
#pragma unroll 4
    for (int c = 0; c < 96; ++c) a += sL[ij * 100 + c] * qL[kl * 100 + c];
    A[i] = a;
  }
  __syncthreads();
  float* B = smem;
  {
    float w0[9];
#pragma unroll
    for (int d = 0; d < 9; ++d) w0[d] = wuv[d];
    float g = BNINV * bnuv[0], bt = bnuv[1];
    for (int i = t; i < 2401; i += 512) {
      int ij = i / 49, kl = i % 49;
      int u = ij / 7, v = ij % 7;
      float a = 0.f;
#pragma unroll
      for (int du = 0; du < 3; ++du) {
        int uu = u + du - 1;
        if ((unsigned)uu >= 7u) continue;
#pragma unroll
        for (int dv = 0; dv < 3; ++dv) {
          int vv = v + dv - 1;
          if ((unsigned)vv >= 7u) continue;
          a += w0[du * 3 + dv] * A[(uu * 7 + vv) * 49 + kl];
        }
      }
      B[i] = fmaxf(a * g + bt, 0.f);
    }
  }
  __syncthreads();
  float* Cc = smem + 4900;
  {
    float w1[9];
#pragma unroll
    for (int d = 0; d < 9; ++d) w1[d] = wkl[d];
    float g = BNINV * bnkl[0], bt = bnkl[1];
    for (int i = t; i < 2401; i += 512) {
      int ij = i / 49, kl = i % 49;
      int kk = kl / 7, ll = kl % 7;
      float a = 0.f;
#pragma unroll
      for (int dh = 0; dh < 3; ++dh) {
        int k2 = kk + dh - 1;
        if ((unsigned)k2 >= 7u) continue;
#pragma unroll
        for (int dw = 0; dw < 3; ++dw) {
          int l2 = ll + dw - 1;
          if ((unsigned)l2 >= 7u) continue;
          a += w1[dh * 3 + dw] * B[ij * 49 + k2 * 7 + l2];
        }
      }
      Cc[i] = a * g + bt;
    }
  }
  __syncthreads();
  for (int o = 0; o < 16; ++o) {
    float sc = pw16[o] * BNINV * pbn16[o], bt2 = pbn16[16 + o];
    for (int i = t; i < 2401; i += 512)
      s0p[(b * 16 + o) * 2401 + i] = fmaxf(Cc[i] * sc + bt2, 0.f);
  }
}

// ---------------- sep4d #1 conv a. grid (64 b, 7 kc) ----------------
__global__ __launch_bounds__(256) void k_sep1a(
    const float* __restrict__ in, const float* __restrict__ w,
    const float* __restrict__ bnp, float* __restrict__ out) {
  int b = blockIdx.x, kc = blockIdx.y, t = threadIdx.x;
  __shared__ float inS[16 * 350];
  __shared__ __align__(16) float wP[3072];
  for (int i = t; i < 3072; i += 256) {
    int oc = i / 12, d = i % 12;
    wP[i] = (d < 9) ? w[oc * 9 + d] : 0.f;
  }
  for (int i = t; i < 5488; i += 256) {
    int ic = i / 343, r = i - ic * 343;
    int ij = r / 7, s = r - ij * 7;
    inS[ic * 350 + s * 50 + ij] = in[(b * 16 + ic) * 2401 + ij * 49 + kc * 7 + s];
  }
  __syncthreads();
  for (int rho = t; rho < 784; rho += 256) {
    int o = rho / 49, rem = rho - o * 49, u = rem / 7, s = rem - u * 7;
    float acc[7] = {0.f, 0.f, 0.f, 0.f, 0.f, 0.f, 0.f};
    for (int ic = 0; ic < 16; ++ic) {
      float wv[12];
      const float* wb = &wP[(o * 16 + ic) * 12];
      *(float4*)&wv[0] = *(const float4*)&wb[0];
      *(float4*)&wv[4] = *(const float4*)&wb[4];
      *(float4*)&wv[8] = *(const float4*)&wb[8];
      const float* rowb = &inS[ic * 350 + s * 50];
#pragma unroll
      for (int du = 0; du < 3; ++du) {
        int uu = u + du - 1;
        if ((unsigned)uu >= 7u) continue;
        const float* rr = rowb + uu * 7;
        float r7[7];
#pragma unroll
        for (int q = 0; q < 7; ++q) r7[q] = rr[q];
#pragma unroll
        for (int v = 0; v < 7; ++v) {
          float a = acc[v];
          if (v > 0) a += wv[du * 3 + 0] * r7[v - 1];
          a += wv[du * 3 + 1] * r7[v];
          if (v < 6) a += wv[du * 3 + 2] * r7[v + 1];
          acc[v] = a;
        }
      }
    }
    float g = BNINV * bnp[o], bt = bnp[16 + o];
    long ob = (long)(b * 16 + o) * 2401 + kc * 7 + s;
#pragma unroll
    for (int v = 0; v < 7; ++v)
      out[ob + (u * 7 + v) * 49] = fmaxf(acc[v] * g + bt, 0.f);
  }
}

// ---------------- sep4d #1 conv b. grid (64 b, 7 ir) ----------------
__global__ __launch_bounds__(256) void k_sep1b(
    const float* __restrict__ in, const float* __restrict__ w,
    const float* __restrict__ bnp, float* __restrict__ out) {
  int b = blockIdx.x, ir = blockIdx.y, t = threadIdx.x;
  __shared__ float inS[16 * 345];
  __shared__ __align__(16) float wP[3072];
  for (int i = t; i < 3072; i += 256) {
    int oc = i / 12, d = i % 12;
    wP[i] = (d < 9) ? w[oc * 9 + d] : 0.f;
  }
  for (int i = t; i < 5488; i += 256) {
    int ic = i / 343, r = i - ic * 343;
    inS[ic * 345 + r] = in[(b * 16 + ic) * 2401 + ir * 343 + r];
  }
  __syncthreads();
  for (int rho = t; rho < 784; rho += 256) {
    int o = rho / 49, rem = rho - o * 49, jj = rem / 7, k = rem - jj * 7;
    float acc[7] = {0.f, 0.f, 0.f, 0.f, 0.f, 0.f, 0.f};
    for (int ic = 0; ic < 16; ++ic) {
      float wv[12];
      const float* wb = &wP[(o * 16 + ic) * 12];
      *(float4*)&wv[0] = *(const float4*)&wb[0];
      *(float4*)&wv[4] = *(const float4*)&wb[4];
      *(float4*)&wv[8] = *(const float4*)&wb[8];
      const float* rowb = &inS[ic * 345 + jj * 49];
#pragma unroll
      for (int dh = 0; dh < 3; ++dh) {
        int k2 = k + dh - 1;
        if ((unsigned)k2 >= 7u) continue;
        const float* rr = rowb + k2 * 7;
        float r7[7];
#pragma unroll
        for (int q = 0; q < 7; ++q) r7[q] = rr[q];
#pragma unroll
        for (int l = 0; l < 7; ++l) {
          float a = acc[l];
          if (l > 0) a += wv[dh * 3 + 0] * r7[l - 1];
          a += wv[dh * 3 + 1] * r7[l];
          if (l < 6) a += wv[dh * 3 + 2] * r7[l + 1];
          acc[l] = a;
        }
      }
    }
    float g = BNINV * bnp[o], bt = bnp[16 + o];
    long ob = (long)(b * 16 + o) * 2401 + ir * 343 + jj * 49 + k * 7;
#pragma unroll
    for (int l = 0; l < 7; ++l)
      out[ob + l] = acc[l] * g + bt;
  }
}

// ------- K10: fused sep1p + gauss-softmax attention (dual-phase concurrent) -------
__global__ __launch_bounds__(256) void k_c4attn(
    const float* __restrict__ in, const float* __restrict__ pw,
    const float* __restrict__ pbn, float* __restrict__ attn_s,
    float* __restrict__ attn_q) {
  int b = blockIdx.x, t = threadIdx.x;
  __shared__ float c[2401];
  __shared__ float nA[2401];
  __shared__ float nB[2401];
  __shared__ float plw[16];
  if (t < 16) plw[t] = pw[t];
  __syncthreads();
  float g0 = BNINV * pbn[0], bt0 = pbn[1];
  for (int i = t; i < 2401; i += 256) {
    float a = 0.f;
#pragma unroll
    for (int ic = 0; ic < 16; ++ic) a += plw[ic] * in[(b * 16 + ic) * 2401 + i];
    c[i] = a * g0 + bt0;
  }
  __syncthreads();
  if (t < 49) {
    // phase A: per kl=t, softmax over ij (column)
    float m = 0.f;
    for (int ij = 0; ij < 49; ++ij) m += c[ij * 49 + t];
    m *= (1.f / 49.f);
    float v = 0.f;
    for (int ij = 0; ij < 49; ++ij) { float d = c[ij * 49 + t] - m; v += d * d; }
    v *= (1.f / 48.f);
    float inv = 1.f / sqrtf(v + 1e-5f);
    float mx = -1e30f;
    for (int ij = 0; ij < 49; ++ij) mx = fmaxf(mx, (c[ij * 49 + t] - m) * inv);
    float s = 0.f;
    for (int ij = 0; ij < 49; ++ij) {
      float e = expf((c[ij * 49 + t] - m) * inv - mx);
      nA[ij * 49 + t] = e; s += e;
    }
    float r = 1.f / s;
    for (int ij = 0; ij < 49; ++ij) nA[ij * 49 + t] *= r;
  } else if (t >= 64 && t < 113) {
    // phase B: per ij=t-64, softmax over kl (row)
    int t2 = t - 64;
    float m = 0.f;
    for (int kl = 0; kl < 49; ++kl) m += c[t2 * 49 + kl];
    m *= (1.f / 49.f);
    float v = 0.f;
    for (int kl = 0; kl < 49; ++kl) { float d = c[t2 * 49 + kl] - m; v += d * d; }
    v *= (1.f / 48.f);
    float inv = 1.f / sqrtf(v + 1e-5f);
    float mx = -1e30f;
    for (int kl = 0; kl < 49; ++kl) mx = fmaxf(mx, (c[t2 * 49 + kl] - m) * inv);
    float s = 0.f;
    for (int kl = 0; kl < 49; ++kl) {
      float e = expf((c[t2 * 49 + kl] - m) * inv - mx);
      nB[t2 * 49 + kl] = e; s += e;
    }
    float r = 1.f / s;
    for (int kl = 0; kl < 49; ++kl) nB[t2 * 49 + kl] *= r;
  }
  __syncthreads();
  if (t < 49) {
    float s = 0.f;
    for (int kl = 0; kl < 49; ++kl) s += nA[t * 49 + kl];
    attn_s[b * 49 + t] = s;
  } else if (t >= 64 && t < 113) {
    int t2 = t - 64;
    float s = 0.f;
    for (int ij = 0; ij < 49; ++ij) s += nB[ij * 49 + t2];
    attn_q[b * 49 + t2] = s;
  }
}

// ------- K11: attention-weighted mean/max pooling -------
__global__ __launch_bounds__(256) void k_pool(const float* __restrict__ xpn,
                                              const float* __restrict__ attn,
                                              float* __restrict__ ep) {
  int b = blockIdx.x, br = blockIdx.y, t = threadIdx.x;
  const float* xb = xpn + br * 3010560 + b * 47040;
  const float* a = attn + br * 3136 + b * 49;
  __shared__ float al[49];
  if (t < 49) al[t] = a[t];
  __syncthreads();
  float* eb = ep + br * 122880 + b * 1920;
  for (int c = t; c < 960; c += 256) {
    float s = 0.f, mx = -1e30f;
    for (int hw = 0; hw < 49; ++hw) {
      float v = al[hw] * xb[hw * 960 + c];
      s += v; mx = fmaxf(mx, v);
    }
    eb[c] = s * (1.f / 49.f);
    eb[960 + c] = mx;
  }
}

// ------- M=64 GEMM, split-K with atomicAdd; z selects meta/ene -------
__global__ __launch_bounds__(256) void k_gemm64(
    const float* __restrict__ A0, const float* __restrict__ A1, int asplit,
    int reluA, const float* __restrict__ Wm, const float* __restrict__ We,
    int K, int Kslice, float* __restrict__ Cm, float* __restrict__ Ce,
    int N, int zAoff) {
  int otile = blockIdx.x, ks = blockIdx.y, z = blockIdx.z;
  const float* W = z ? We : Wm;
  float* C = z ? Ce : Cm;
  int zo = z * zAoff;
  int t = threadIdx.x, bt = t >> 4, ot = t & 15;
  __shared__ __align__(16) float eT[48 * 68];
  __shared__ __align__(16) float wT[48 * 68];
  float acc[4][4];
#pragma unroll
  for (int i = 0; i < 4; ++i)
#pragma unroll
    for (int j = 0; j < 4; ++j) acc[i][j] = 0.f;
  int kbeg = ks * Kslice, kend = kbeg + Kslice;
  for (int k0 = kbeg; k0 < kend; k0 += 48) {
    __syncthreads();
    for (int i = t; i < 768; i += 256) {
      int b = i / 12, kg = i % 12;
      int k = k0 + kg * 4;
      float4 v;
      if (asplit) {
        v = (k < asplit) ? *(const float4*)&A0[b * 1920 + zo + k]
                         : *(const float4*)&A1[b * 1920 + zo + k - asplit];
      } else {
        v = *(const float4*)&A0[zo + b * K + k];
      }
      if (reluA) {
        v.x = fmaxf(v.x, 0.f); v.y = fmaxf(v.y, 0.f);
        v.z = fmaxf(v.z, 0.f); v.w = fmaxf(v.w, 0.f);
      }
      eT[(kg * 4 + 0) * 68 + b] = v.x; eT[(kg * 4 + 1) * 68 + b] = v.y;
      eT[(kg * 4 + 2) * 68 + b] = v.z; eT[(kg * 4 + 3) * 68 + b] = v.w;
    }
    for (int i = t; i < 768; i += 256) {
      int o = i / 12, kg = i % 12;
      float4 v = *(const float4*)&W[(otile * 64 + o) * K + k0 + kg * 4];
      wT[(kg * 4 + 0) * 68 + o] = v.x; wT[(kg * 4 + 1) * 68 + o] = v.y;
      wT[(kg * 4 + 2) * 68 + o] = v.z; wT[(kg * 4 + 3) * 68 + o] = v.w;
    }
    __syncthreads();
#pragma unroll 4
    for (int kk = 0; kk < 48; ++kk) {
      float av[4], wv[4];
      *(float4*)av = *(const float4*)&eT[kk * 68 + bt * 4];
      *(float4*)wv = *(const float4*)&wT[kk * 68 + ot * 4];
#pragma unroll
      for (int i = 0; i < 4; ++i)
#pragma unroll
        for (int j = 0; j < 4; ++j) acc[i][j] += av[i] * wv[j];
    }
  }
#pragma unroll
  for (int i = 0; i < 4; ++i)
#pragma unroll
    for (int j = 0; j < 4; ++j)
      atomicAdd(&C[(bt * 4 + i) * N + otile * 64 + ot * 4 + j], acc[i][j]);
}

// ------- classifier layer 1 (with fused group-pooling) -------
__global__ __launch_bounds__(256) void k_cls1(
    const float* __restrict__ em3, const float* __restrict__ b2m,
    const float* __restrict__ b2e, const float* __restrict__ w1mT,
    const float* __restrict__ b1m, const float* __restrict__ w1eT,
    const float* __restrict__ b1e, float* __restrict__ h2) {
  int which = blockIdx.z, g = blockIdx.y, t = threadIdx.x;
  const float* em = em3 + which * 61440 + g * 7680;
  const float* b2 = which ? b2e : b2m;
  const float* WT = which ? w1eT : w1mT;
  const float* b1 = which ? b1e : b1m;
  __shared__ float pl[960];
  for (int d = t; d < 960; d += 256) {
    float s = 0.f;
#pragma unroll
    for (int r = 0; r < 8; ++r) s += em[r * 960 + d];
    pl[d] = s * 0.125f + b2[d];
  }
  __syncthreads();
  int o = blockIdx.x * 256 + t;
  if (o >= 1920) return;
  float acc = 0.f;
#pragma unroll 8
  for (int k = 0; k < 960; ++k) acc += WT[k * 1920 + o] * pl[k];
  float z = acc + b1[o];
  h2[which * 15360 + g * 1920 + o] = z * fminf(fmaxf(z + 3.f, 0.f), 6.f) * (1.f / 6.f);
}

// ------- classifier layer 2 + final concat -------
__global__ __launch_bounds__(128) void k_cls2(
    const float* __restrict__ h2, const float* __restrict__ w2m,
    const float* __restrict__ b2m, const float* __restrict__ w2e,
    const float* __restrict__ b2e, float* __restrict__ out) {
  int g = blockIdx.x, which = blockIdx.y;
  int t = threadIdx.x, j = t >> 6, lane = t & 63;
  const float* h = h2 + which * 15360 + g * 1920;
  const float* W = (which ? w2e : w2m) + j * 1920;
  const float* bb = which ? b2e : b2m;
  float s = 0.f;
  for (int k = lane; k < 1920; k += 64) s += h[k] * W[k];
  for (int off = 32; off >= 1; off >>= 1) s += __shfl_down(s, off);
  if (lane == 0) out[g * 4 + which * 2 + j] = s + bb[j];
}

// =======================================================================
extern "C" void kernel_launch(void* const* d_in, const int* in_sizes, int n_in,
                              void* d_out, int out_size, void* d_ws, size_t ws_size,
                              hipStream_t stream) {
  const float* x_p = (const float*)d_in[0];
  const float* x_i = (const float*)d_in[1];
  const float* scr_w_in = (const float*)d_in[2];
  const float* scr_bn_in = (const float*)d_in[3];
  const float* scr_w1 = (const float*)d_in[4];
  const float* scr_bn1 = (const float*)d_in[5];
  const float* scr_w2 = (const float*)d_in[6];
  const float* scr_bn2 = (const float*)d_in[7];
  const float* scr_w_out = (const float*)d_in[8];
  const float* scr_bn_out = (const float*)d_in[9];
  const float* cca1x1_w = (const float*)d_in[10];
  const float* cca1x1_bn = (const float*)d_in[11];
  const float* cca0_c2_w = (const float*)d_in[12];
  const float* cca0_c2_bn = (const float*)d_in[13];
  const float* cca0_c1_w = (const float*)d_in[14];
  const float* cca0_c1_bn = (const float*)d_in[15];
  const float* cca0_p_w = (const float*)d_in[16];
  const float* cca0_p_bn = (const float*)d_in[17];
  const float* cca1_c2_w = (const float*)d_in[18];
  const float* cca1_c2_bn = (const float*)d_in[19];
  const float* cca1_c1_w = (const float*)d_in[20];
  const float* cca1_c1_bn = (const float*)d_in[21];
  const float* cca1_p_w = (const float*)d_in[22];
  const float* cca1_p_bn = (const float*)d_in[23];
  const float* meta_w1 = (const float*)d_in[24];
  const float* meta_w2 = (const float*)d_in[25];
  const float* meta_b2 = (const float*)d_in[26];
  const float* ene_w1 = (const float*)d_in[27];
  const float* ene_w2 = (const float*)d_in[28];
  const float* ene_b2 = (const float*)d_in[29];
  const float* mcls_w1 = (const float*)d_in[30];
  const float* mcls_b1 = (const float*)d_in[31];
  const float* mcls_w2 = (const float*)d_in[32];
  const float* mcls_b2 = (const float*)d_in[33];
  const float* ecls_w1 = (const float*)d_in[34];
  const float* ecls_b1 = (const float*)d_in[35];
  const float* ecls_w2 = (const float*)d_in[36];
  const float* ecls_b2 = (const float*)d_in[37];

  float* ws = (float*)d_ws;
  float* XN = ws + OFF_XN;
  unsigned short* Y1BF = (unsigned short*)(ws + OFF_Y1BF);
  unsigned* KMTU = (unsigned*)(ws + OFF_KMT);
  unsigned short* W2BF = (unsigned short*)(ws + OFF_W2BF);
  unsigned short* Y2BF = (unsigned short*)(ws + OFF_Y2BF);
  float* T = ws + OFF_T;
  float* XPN = ws + OFF_XPN;
  float* SQ = ws + OFF_SQ;
  float* S0P = ws + OFF_S0P;
  float* S1Y1 = ws + OFF_S1Y1;
  float* S1Y2 = ws + OFF_S1Y2;
  float* ATT = ws + OFF_ATT;
  float* EPI = ws + OFF_EPI;
  float* H1 = ws + OFF_H1;
  float* EM3 = ws + OFF_EM3;
  float* H2 = ws + OFF_H2;
  float* WOUTT = ws + OFF_WOUTT;
  float* CCAT = ws + OFF_CCAT;
  float* MCLST = ws + OFF_MCLST;
  float* ECLST = ws + OFF_ECLST;
  unsigned* WBF = (unsigned*)(ws + OFF_WBF);

  // weight preps
  k_transpose_t<<<dim3(3, 30), 256, 0, stream>>>(scr_w_out, WOUTT, 960, 96);
  k_transpose_t<<<dim3(30, 3), 256, 0, stream>>>(cca1x1_w, CCAT, 96, 960);
  k_transpose_t<<<dim3(30, 60), 256, 0, stream>>>(mcls_w1, MCLST, 1920, 960);
  k_transpose_t<<<dim3(30, 60), 256, 0, stream>>>(ecls_w1, ECLST, 1920, 960);
  k_prepwbf<<<180, 256, 0, stream>>>(scr_w_in, WBF);
  k_kmat<<<4256, 256, 0, stream>>>(scr_w1, KMTU);
  k_w2bf<<<336, 256, 0, stream>>>(scr_w2, W2BF);

  for (int br = 0; br < 2; ++br) {
    const float* x = br ? x_i : x_p;
    k_l2n<<<64, 256, 0, stream>>>(x, XN);
    k_scr_in<<<dim3(64, 7), 512, 0, stream>>>(XN, WBF, scr_bn_in, Y1BF);
    k_conv1g<<<dim3(64, 7), 256, 0, stream>>>((const unsigned*)Y1BF, KMTU,
                                              scr_bn1, Y2BF);
    k_conv2g<<<98, 256, 0, stream>>>((const unsigned*)Y2BF, (const unsigned*)W2BF,
                                     scr_bn2, T);
    k_out_cca<<<dim3(64, 7), 256, 0, stream>>>(T, WOUTT, scr_bn_out, x, CCAT,
                                               cca1x1_bn, XPN + br * 3010560,
                                               SQ + br * 301056);
  }
  k_mid<<<64, 512, 0, stream>>>(SQ, SQ + 301056, cca0_c2_w, cca0_c2_bn,
                                cca0_c1_w, cca0_c1_bn, cca0_p_w, cca0_p_bn, S0P);
  k_sep1a<<<dim3(64, 7), 256, 0, stream>>>(S0P, cca1_c2_w, cca1_c2_bn, S1Y1);
  k_sep1b<<<dim3(64, 7), 256, 0, stream>>>(S1Y1, cca1_c1_w, cca1_c1_bn, S1Y2);
  k_c4attn<<<64, 256, 0, stream>>>(S1Y2, cca1_p_w, cca1_p_bn, ATT, ATT + 3136);
  k_pool<<<dim3(64, 2), 256, 0, stream>>>(XPN, ATT, EPI);

  hipMemsetAsync(H1, 0, (245760u + 122880u) * sizeof(float), stream);
  k_gemm64<<<dim3(30, 8, 2), 256, 0, stream>>>(EPI, EPI + 122880, 960, 0,
                                               meta_w1, ene_w1, 1920, 240,
                                               H1, H1 + 122880, 1920, 960);
  k_gemm64<<<dim3(15, 8, 2), 256, 0, stream>>>(H1, nullptr, 0, 1,
                                               meta_w2, ene_w2, 1920, 240,
                                               EM3, EM3 + 61440, 960, 122880);
  k_cls1<<<dim3(8, 8, 2), 256, 0, stream>>>(EM3, meta_b2, ene_b2, MCLST, mcls_b1,
                                            ECLST, ecls_b1, H2);
  k_cls2<<<dim3(8, 2), 128, 0, stream>>>(H2, mcls_w2, mcls_b2, ecls_w2, ecls_b2,
                                         (float*)d_out);
}